// Round 4
// baseline (2998.281 us; speedup 1.0000x reference)
//
#include <hip/hip_runtime.h>
#include <hip/hip_bf16.h>
#include <cstdint>

#define DEVINL __device__ __forceinline__

// ---------------------------------------------------------------------------
// 2-layer GCN (gcn_norm w/ self-loops) -> per-pair MLP -> per-graph softmax.
// R4: CSR build streamlined (hist carries weight-sum; dinv fused into scan3;
// fill stores w*dinv[row]); k_edge 128 edges/block with register layer-c;
// gathers 4x unrolled; softmax rescales stored exp.
// ---------------------------------------------------------------------------

// ---------- CSR build ----------
// one pass: edge count histogram + weighted degree
__global__ void k_hist2(const int* __restrict__ col, const float* __restrict__ w,
                        int* __restrict__ cnt, float* __restrict__ degF, int E) {
  int e = blockIdx.x * 256 + threadIdx.x;
  if (e < E) {
    int c = col[e];
    atomicAdd(&cnt[c], 1);
    atomicAdd(&degF[c], w[e]);
  }
}

__global__ void k_scan1(const int* __restrict__ cnt, int* __restrict__ start,
                        int* __restrict__ bsum, int N) {
  __shared__ int s[256];
  int t = threadIdx.x;
  int i = blockIdx.x * 256 + t;
  int v = (i < N) ? cnt[i] : 0;
  s[t] = v; __syncthreads();
  int x = v;
#pragma unroll
  for (int off = 1; off < 256; off <<= 1) {
    int y = (t >= off) ? s[t - off] : 0;
    __syncthreads();
    x += y; s[t] = x;
    __syncthreads();
  }
  if (i < N) start[i] = x - v;
  if (t == 255) bsum[blockIdx.x] = x;
}
__global__ void k_scan2(const int* __restrict__ bsum, int* __restrict__ boff, int nb) {
  __shared__ int s[512];
  int t = threadIdx.x;
  int v = (t < nb) ? bsum[t] : 0;
  s[t] = v; __syncthreads();
  int x = v;
#pragma unroll
  for (int off = 1; off < 512; off <<= 1) {
    int y = (t >= off) ? s[t - off] : 0;
    __syncthreads();
    x += y; s[t] = x;
    __syncthreads();
  }
  if (t < nb) boff[t] = x - v;
}
// scan finalize + dinv = rsqrt(1 + weighted_deg)
__global__ void k_scan3dinv(int* __restrict__ start, const int* __restrict__ boff,
                            const float* __restrict__ degF, float* __restrict__ dinv, int N) {
  int i = blockIdx.x * 256 + threadIdx.x;
  if (i < N) {
    start[i] += boff[blockIdx.x];
    dinv[i] = rsqrtf(1.0f + degF[i]);
  }
}

// fill: stores {row, w*dinv[row]}; mutates start[] from exclusive to inclusive-end.
__global__ void k_fill(const int* __restrict__ row, const int* __restrict__ col,
                       const float* __restrict__ w, const float* __restrict__ dinv,
                       int* __restrict__ start, int2* __restrict__ pk, int E) {
  int e = blockIdx.x * 256 + threadIdx.x;
  if (e >= E) return;
  int c = col[e];
  int pos = atomicAdd(&start[c], 1);
  pk[pos] = make_int2(row[e], __float_as_int(w[e] * dinv[row[e]]));
}

// ---------- weight folding (tiny, once per call) ----------
__global__ void k_prep(const float* __restrict__ Wp, const float* __restrict__ bp,
                       const float* __restrict__ W1,
                       const float* __restrict__ W2, const float* __restrict__ Wa,
                       const float* __restrict__ ba, const float* __restrict__ b2,
                       float* __restrict__ Wfuse, float* __restrict__ bfuse,
                       float* __restrict__ Mcat, float* __restrict__ bU) {
  int id = blockIdx.x * 256 + threadIdx.x;
  if (id < 8192) {                      // Wfuse[i,j] = (Wp@W1)[i,j]
    int i = id >> 7, j = id & 127;
    float s = 0.f;
    for (int k = 0; k < 128; k++) s = fmaf(Wp[i * 128 + k], W1[k * 128 + j], s);
    Wfuse[id] = s;
  } else if (id < 8320) {               // bfuse = bp@W1
    int j = id - 8192;
    float s = 0.f;
    for (int k = 0; k < 128; k++) s = fmaf(bp[k], W1[k * 128 + j], s);
    bfuse[j] = s;
  } else if (id < 8320 + 16384) {       // Mcat = [W2@Wa0 | W2@Wa1]
    int m = id - 8320;
    int i = m >> 7, j = m & 127;
    int jj = j & 63, koff = (j < 64) ? 0 : 64;
    float s = 0.f;
    for (int k = 0; k < 64; k++) s = fmaf(W2[i * 64 + k], Wa[(koff + k) * 64 + jj], s);
    Mcat[i * 128 + j] = s;
  } else if (id < 8320 + 16384 + 128) { // bU = [b2@Wa0+ba | b2@Wa1]
    int j = id - 8320 - 16384;
    int jj = j & 63, koff = (j < 64) ? 0 : 64;
    float s = (j < 64) ? ba[j] : 0.f;
    for (int k = 0; k < 64; k++) s = fmaf(b2[k], Wa[(koff + k) * 64 + jj], s);
    bU[j] = s;
  }
}

// ---------- tiled fp32 GEMM: C[N,M] = A[N,K] @ W[K,M] (+bias) ----------
template<int K, int M, bool BIAS>
__global__ __launch_bounds__(256, 2) void k_gemm(const float* __restrict__ A,
                                                 const float* __restrict__ W,
                                                 const float* __restrict__ bias,
                                                 float* __restrict__ C, int N) {
  constexpr int KC = 64;
  constexpr int NB = M / 64;
  __shared__ alignas(16) float sA[128 * 68];
  __shared__ alignas(16) float sW[KC * (M + 4)];
  const int t = threadIdx.x;
  const int rg = t >> 4, cg = t & 15;
  const int r0 = blockIdx.x * 128;
  float acc[NB][8][4] = {};
  for (int kc = 0; kc < K; kc += KC) {
    __syncthreads();
#pragma unroll
    for (int i = 0; i < 8; i++) {
      int idx = t * 4 + i * 1024;
      int r = idx >> 6, k = idx & 63;
      int gr = r0 + r;
      float4 v = make_float4(0.f, 0.f, 0.f, 0.f);
      if (gr < N) v = *(const float4*)&A[(size_t)gr * K + kc + k];
      *(float4*)&sA[r * 68 + k] = v;
    }
#pragma unroll
    for (int i = 0; i < KC * M / 1024; i++) {
      int idx = t * 4 + i * 1024;
      int r = idx / M, c = idx % M;
      *(float4*)&sW[r * (M + 4) + c] = *(const float4*)&W[(size_t)(kc + r) * M + c];
    }
    __syncthreads();
#pragma unroll
    for (int k0 = 0; k0 < KC; k0 += 4) {
      float4 av[8];
#pragma unroll
      for (int ri = 0; ri < 8; ri++) av[ri] = *(const float4*)&sA[(rg + 16 * ri) * 68 + k0];
      float4 wv[4][NB];
#pragma unroll
      for (int kk = 0; kk < 4; kk++)
#pragma unroll
        for (int b = 0; b < NB; b++)
          wv[kk][b] = *(const float4*)&sW[(k0 + kk) * (M + 4) + b * 64 + cg * 4];
#pragma unroll
      for (int kk = 0; kk < 4; kk++)
#pragma unroll
        for (int ri = 0; ri < 8; ri++) {
          float a = ((const float*)&av[ri])[kk];
#pragma unroll
          for (int b = 0; b < NB; b++) {
            acc[b][ri][0] = fmaf(a, wv[kk][b].x, acc[b][ri][0]);
            acc[b][ri][1] = fmaf(a, wv[kk][b].y, acc[b][ri][1]);
            acc[b][ri][2] = fmaf(a, wv[kk][b].z, acc[b][ri][2]);
            acc[b][ri][3] = fmaf(a, wv[kk][b].w, acc[b][ri][3]);
          }
        }
    }
  }
#pragma unroll
  for (int ri = 0; ri < 8; ri++) {
    int rrow = r0 + rg + 16 * ri;
    if (rrow < N) {
#pragma unroll
      for (int b = 0; b < NB; b++) {
        float4 o;
        o.x = acc[b][ri][0]; o.y = acc[b][ri][1]; o.z = acc[b][ri][2]; o.w = acc[b][ri][3];
        if (BIAS) {
          float4 bv = *(const float4*)&bias[b * 64 + cg * 4];
          o.x += bv.x; o.y += bv.y; o.z += bv.z; o.w += bv.w;
        }
        *(float4*)&C[(size_t)rrow * M + b * 64 + cg * 4] = o;
      }
    }
  }
}

// ---------- CSR gather: h[v] = act(dinv*sum + dinv^2*hw[v] + bias) ----------
template<int M, bool RELU>
__global__ void k_gather(const int* __restrict__ start, const int2* __restrict__ pk,
                         const float* __restrict__ hw, const float* __restrict__ dinv,
                         const float* __restrict__ bias, float* __restrict__ hout, int N) {
  constexpr int L = M / 4;
  constexpr int NPB = 256 / L;
  const int t = threadIdx.x;
  const int v = blockIdx.x * NPB + t / L;
  if (v >= N) return;
  const int j = (t % L) * 4;
  const int b = v ? start[v - 1] : 0;
  const int en = start[v];
  float4 a0 = make_float4(0.f, 0.f, 0.f, 0.f);
  float4 a1 = make_float4(0.f, 0.f, 0.f, 0.f);
  int i = b;
  for (; i + 3 < en; i += 4) {
    int2 q0 = pk[i], q1 = pk[i + 1], q2 = pk[i + 2], q3 = pk[i + 3];
    float n0 = __int_as_float(q0.y), n1 = __int_as_float(q1.y);
    float n2 = __int_as_float(q2.y), n3 = __int_as_float(q3.y);
    float4 h0 = *(const float4*)&hw[(size_t)q0.x * M + j];
    float4 h1 = *(const float4*)&hw[(size_t)q1.x * M + j];
    float4 h2 = *(const float4*)&hw[(size_t)q2.x * M + j];
    float4 h3 = *(const float4*)&hw[(size_t)q3.x * M + j];
    a0.x = fmaf(n0, h0.x, a0.x); a0.y = fmaf(n0, h0.y, a0.y);
    a0.z = fmaf(n0, h0.z, a0.z); a0.w = fmaf(n0, h0.w, a0.w);
    a1.x = fmaf(n1, h1.x, a1.x); a1.y = fmaf(n1, h1.y, a1.y);
    a1.z = fmaf(n1, h1.z, a1.z); a1.w = fmaf(n1, h1.w, a1.w);
    a0.x = fmaf(n2, h2.x, a0.x); a0.y = fmaf(n2, h2.y, a0.y);
    a0.z = fmaf(n2, h2.z, a0.z); a0.w = fmaf(n2, h2.w, a0.w);
    a1.x = fmaf(n3, h3.x, a1.x); a1.y = fmaf(n3, h3.y, a1.y);
    a1.z = fmaf(n3, h3.z, a1.z); a1.w = fmaf(n3, h3.w, a1.w);
  }
  for (; i < en; i++) {
    int2 p = pk[i];
    float n = __int_as_float(p.y);
    float4 h = *(const float4*)&hw[(size_t)p.x * M + j];
    a0.x = fmaf(n, h.x, a0.x); a0.y = fmaf(n, h.y, a0.y);
    a0.z = fmaf(n, h.z, a0.z); a0.w = fmaf(n, h.w, a0.w);
  }
  float4 acc;
  acc.x = a0.x + a1.x; acc.y = a0.y + a1.y; acc.z = a0.z + a1.z; acc.w = a0.w + a1.w;
  const float d = dinv[v];
  const float s = d * d;
  float4 hv = *(const float4*)&hw[(size_t)v * M + j];
  float4 bv = *(const float4*)&bias[j];
  float4 o;
  o.x = fmaf(d, acc.x, fmaf(s, hv.x, bv.x));
  o.y = fmaf(d, acc.y, fmaf(s, hv.y, bv.y));
  o.z = fmaf(d, acc.z, fmaf(s, hv.z, bv.z));
  o.w = fmaf(d, acc.w, fmaf(s, hv.w, bv.w));
  if (RELU) {
    o.x = fmaxf(o.x, 0.f); o.y = fmaxf(o.y, 0.f);
    o.z = fmaxf(o.z, 0.f); o.w = fmaxf(o.w, 0.f);
  }
  *(float4*)&hout[(size_t)v * M + j] = o;
}

// ---------- per-edge kernel: logit = relu(U0[p0]+U1[p1]) @ Wb(relu) @ Wc ----------
// 128 edges per block, 256 threads. Layer c fused into registers + 16-lane shuffle.
__global__ __launch_bounds__(256, 3) void k_edge(const float* __restrict__ U,
    const int* __restrict__ p0, const int* __restrict__ p1,
    const float* __restrict__ Wb, const float* __restrict__ bb,
    const float* __restrict__ Wc, const float* __restrict__ bc,
    float* __restrict__ logits, int ES) {
  __shared__ alignas(16) float sWb[64 * 36];    // [k][c] stride 36
  __shared__ alignas(16) float sS1[128 * 68];   // [edge][k] stride 68
  __shared__ float sWc[32], sbb[32], sbc;
  const int t = threadIdx.x;
#pragma unroll
  for (int i = t * 4; i < 64 * 32; i += 1024) {
    int r = i >> 5, c = i & 31;
    *(float4*)&sWb[r * 36 + c] = *(const float4*)&Wb[i];
  }
  if (t < 32) { sWc[t] = Wc[t]; sbb[t] = bb[t]; }
  if (t == 0) sbc = bc[0];
  const int base = blockIdx.x << 7;
  {  // gather + add + relu -> s1 (2 passes of 64 edges; 4 threads/edge)
    int p = t >> 2, q = t & 3;
#pragma unroll
    for (int ee = 0; ee < 2; ee++) {
      int le = ee * 64 + p;
      int e = base + le; if (e >= ES) e = ES - 1;
      const float* r0 = U + (size_t)p0[e] * 128;        // U0 half: cols 0..63
      const float* r1 = U + (size_t)p1[e] * 128 + 64;   // U1 half: cols 64..127
#pragma unroll
      for (int i = 0; i < 4; i++) {
        int c = i * 16 + q * 4;
        float4 a = *(const float4*)&r0[c];
        float4 b = *(const float4*)&r1[c];
        float4 o;
        o.x = fmaxf(a.x + b.x, 0.f); o.y = fmaxf(a.y + b.y, 0.f);
        o.z = fmaxf(a.z + b.z, 0.f); o.w = fmaxf(a.w + b.w, 0.f);
        *(float4*)&sS1[le * 68 + c] = o;
      }
    }
  }
  __syncthreads();
  // layer b: thread (rg=t>>4, cg=t&15) -> rows rg+16*ri (ri<8), cols 2cg..2cg+1
  const int rg = t >> 4, cg = t & 15;
  float accb[8][2] = {};
#pragma unroll
  for (int k0 = 0; k0 < 64; k0 += 4) {
    float4 av[8];
#pragma unroll
    for (int ri = 0; ri < 8; ri++) av[ri] = *(const float4*)&sS1[(rg + 16 * ri) * 68 + k0];
    float2 wv[4];
#pragma unroll
    for (int kk = 0; kk < 4; kk++) wv[kk] = *(const float2*)&sWb[(k0 + kk) * 36 + cg * 2];
#pragma unroll
    for (int kk = 0; kk < 4; kk++)
#pragma unroll
      for (int ri = 0; ri < 8; ri++) {
        float a = ((const float*)&av[ri])[kk];
        accb[ri][0] = fmaf(a, wv[kk].x, accb[ri][0]);
        accb[ri][1] = fmaf(a, wv[kk].y, accb[ri][1]);
      }
  }
  // layer c in registers: partial over this thread's 2 cols, reduce over 16 lanes
  const float wc0 = sWc[cg * 2 + 0], wc1 = sWc[cg * 2 + 1];
  const float bb0 = sbb[cg * 2 + 0], bb1 = sbb[cg * 2 + 1];
  float part[8];
#pragma unroll
  for (int ri = 0; ri < 8; ri++) {
    float s0 = fmaxf(accb[ri][0] + bb0, 0.f);
    float s1 = fmaxf(accb[ri][1] + bb1, 0.f);
    part[ri] = fmaf(s0, wc0, s1 * wc1);
  }
#pragma unroll
  for (int ri = 0; ri < 8; ri++) {
    float s = part[ri];
    s += __shfl_down(s, 8);
    s += __shfl_down(s, 4);
    s += __shfl_down(s, 2);
    s += __shfl_down(s, 1);
    if (cg == 0) {
      int e = base + rg + 16 * ri;
      if (e < ES) logits[e] = s + sbc;
    }
  }
}

// ---------- fused per-graph softmax: one block per graph (eg sorted) ----------
DEVINL int lbound(const int* __restrict__ a, int n, int key) {
  int lo = 0, hi = n;
  while (lo < hi) { int mid = (lo + hi) >> 1; if (a[mid] < key) lo = mid + 1; else hi = mid; }
  return lo;
}
__global__ __launch_bounds__(512) void k_softmax(const float* __restrict__ logits,
                          const int* __restrict__ eg,
                          float* __restrict__ out, int ES) {
  const int g = blockIdx.x;
  const int t = threadIdx.x;
  const int lo = lbound(eg, ES, g);
  const int hi = lbound(eg, ES, g + 1);
  if (lo >= hi) return;
  __shared__ float red[512];
  __shared__ float s_m, s_z;
  float m = -3.4e38f;
  for (int i = lo + t; i < hi; i += 512) m = fmaxf(m, logits[i]);
  red[t] = m; __syncthreads();
#pragma unroll
  for (int off = 256; off >= 1; off >>= 1) {
    if (t < off) red[t] = fmaxf(red[t], red[t + off]);
    __syncthreads();
  }
  if (t == 0) s_m = red[0];
  __syncthreads();
  const float gm = s_m;
  float z = 0.f;
  for (int i = lo + t; i < hi; i += 512) {
    float e = expf(logits[i] - gm);
    out[i] = e;                    // store exp; rescale in pass 3
    z += e;
  }
  red[t] = z; __syncthreads();
#pragma unroll
  for (int off = 256; off >= 1; off >>= 1) {
    if (t < off) red[t] += red[t + off];
    __syncthreads();
  }
  if (t == 0) s_z = red[0];
  __syncthreads();
  const float inv = 1.0f / s_z;
  for (int i = lo + t; i < hi; i += 512) out[i] *= inv;
}

// ---------------------------------------------------------------------------
extern "C" void kernel_launch(void* const* d_in, const int* in_sizes, int n_in,
                              void* d_out, int out_size, void* d_ws, size_t ws_size,
                              hipStream_t stream) {
  const float* x  = (const float*)d_in[0];
  const int* ei   = (const int*)d_in[1];
  const float* ew = (const float*)d_in[2];
  const int* pi   = (const int*)d_in[3];
  const int* eg   = (const int*)d_in[4];
  const float* Wp = (const float*)d_in[6];
  const float* bp = (const float*)d_in[7];
  const float* W1 = (const float*)d_in[8];
  const float* b1 = (const float*)d_in[9];
  const float* W2 = (const float*)d_in[10];
  const float* b2 = (const float*)d_in[11];
  const float* Wa = (const float*)d_in[12];
  const float* ba = (const float*)d_in[13];
  const float* Wb = (const float*)d_in[14];
  const float* bb = (const float*)d_in[15];
  const float* Wc = (const float*)d_in[16];
  const float* bc = (const float*)d_in[17];

  const int N  = in_sizes[0] / 64;
  const int E  = in_sizes[2];
  const int ES = in_sizes[4];
  const int G  = 128;

  float* ws = (float*)d_ws;
  size_t o = 0;
  const size_t Npad = ((size_t)N + 31) & ~(size_t)31;
  int* cnt = (int*)(ws + o);    o += Npad;   // dead after scan1 -> reused as dinv
  float* dinv = (float*)cnt;
  float* degF = (float*)(ws + o); o += Npad;
  int* start = (int*)(ws + o);  o += Npad;
  int* bsum = (int*)(ws + o);   o += 512;
  int* boff = (int*)(ws + o);   o += 512;
  int2* pk = (int2*)(ws + o);   o += (size_t)E * 2;
  float* A = ws + o;            o += (size_t)N * 128;   // h1 -> U
  float* B = ws + o;            o += (size_t)N * 128;   // hw1 -> V -> logits
  float* Wfuse = ws + o;        o += 8192;
  float* bfuse = ws + o;        o += 128;
  float* Mcat = ws + o;         o += 16384;
  float* bU = ws + o;           o += 128;

  const int* row = ei;
  const int* col = ei + E;
  const int* p0 = pi;
  const int* p1 = pi + ES;
  float* out = (float*)d_out;

  const int gN = (N + 255) / 256;
  const int gE = (E + 255) / 256;
  const int nb = gN;

  // ---- weight folding + CSR build ----
  hipMemsetAsync(cnt, 0, 2 * Npad * sizeof(int), stream);   // cnt + degF (adjacent)
  k_prep<<<98, 256, 0, stream>>>(Wp, bp, W1, W2, Wa, ba, b2, Wfuse, bfuse, Mcat, bU);
  k_hist2<<<gE, 256, 0, stream>>>(col, ew, cnt, degF, E);
  k_scan1<<<nb, 256, 0, stream>>>(cnt, start, bsum, N);
  k_scan2<<<1, 512, 0, stream>>>(bsum, boff, nb);
  k_scan3dinv<<<nb, 256, 0, stream>>>(start, boff, degF, dinv, N);
  k_fill<<<gE, 256, 0, stream>>>(row, col, ew, dinv, start, pk, E);

  // ---- node pipeline: 2 GEMMs + 2 gathers ----
  const int gRows = (N + 127) / 128;
  k_gemm<64, 128, true><<<gRows, 256, 0, stream>>>(x, Wfuse, bfuse, B, N);              // hw1
  k_gather<128, true><<<(N + 7) / 8, 256, 0, stream>>>(start, pk, B, dinv, b1, A, N);   // h1
  k_gemm<128, 128, false><<<gRows, 256, 0, stream>>>(A, Mcat, nullptr, B, N);           // V
  k_gather<128, false><<<(N + 7) / 8, 256, 0, stream>>>(start, pk, B, dinv, bU, A, N);  // U

  // ---- per-edge MLP ----
  k_edge<<<(ES + 127) / 128, 256, 0, stream>>>(A, p0, p1, Wb, bb, Wc, bc, B, ES);

  // ---- per-graph softmax ----
  k_softmax<<<G, 512, 0, stream>>>(B, eg, out, ES);
}

// Round 5
// 1345.739 us; speedup vs baseline: 2.2280x; 2.2280x over previous
//
#include <hip/hip_runtime.h>
#include <hip/hip_bf16.h>
#include <cstdint>

#define DEVINL __device__ __forceinline__

// ---------------------------------------------------------------------------
// 2-layer GCN (gcn_norm w/ self-loops) -> per-pair MLP -> per-graph softmax.
// R5: bisect — k_edge reverted verbatim to the R3 version (R4's 128-edge/block
// restructure showed 1709us profiled vs <780us in R3; mechanism unidentified).
// Keeps R4's CSR streamlining, 4x-unrolled gather, softmax exp-store+rescale.
// ---------------------------------------------------------------------------

// ---------- CSR build ----------
// one pass: edge count histogram + weighted degree
__global__ void k_hist2(const int* __restrict__ col, const float* __restrict__ w,
                        int* __restrict__ cnt, float* __restrict__ degF, int E) {
  int e = blockIdx.x * 256 + threadIdx.x;
  if (e < E) {
    int c = col[e];
    atomicAdd(&cnt[c], 1);
    atomicAdd(&degF[c], w[e]);
  }
}

__global__ void k_scan1(const int* __restrict__ cnt, int* __restrict__ start,
                        int* __restrict__ bsum, int N) {
  __shared__ int s[256];
  int t = threadIdx.x;
  int i = blockIdx.x * 256 + t;
  int v = (i < N) ? cnt[i] : 0;
  s[t] = v; __syncthreads();
  int x = v;
#pragma unroll
  for (int off = 1; off < 256; off <<= 1) {
    int y = (t >= off) ? s[t - off] : 0;
    __syncthreads();
    x += y; s[t] = x;
    __syncthreads();
  }
  if (i < N) start[i] = x - v;
  if (t == 255) bsum[blockIdx.x] = x;
}
__global__ void k_scan2(const int* __restrict__ bsum, int* __restrict__ boff, int nb) {
  __shared__ int s[512];
  int t = threadIdx.x;
  int v = (t < nb) ? bsum[t] : 0;
  s[t] = v; __syncthreads();
  int x = v;
#pragma unroll
  for (int off = 1; off < 512; off <<= 1) {
    int y = (t >= off) ? s[t - off] : 0;
    __syncthreads();
    x += y; s[t] = x;
    __syncthreads();
  }
  if (t < nb) boff[t] = x - v;
}
// scan finalize + dinv = rsqrt(1 + weighted_deg)
__global__ void k_scan3dinv(int* __restrict__ start, const int* __restrict__ boff,
                            const float* __restrict__ degF, float* __restrict__ dinv, int N) {
  int i = blockIdx.x * 256 + threadIdx.x;
  if (i < N) {
    start[i] += boff[blockIdx.x];
    dinv[i] = rsqrtf(1.0f + degF[i]);
  }
}

// fill: stores {row, w*dinv[row]}; mutates start[] from exclusive to inclusive-end.
__global__ void k_fill(const int* __restrict__ row, const int* __restrict__ col,
                       const float* __restrict__ w, const float* __restrict__ dinv,
                       int* __restrict__ start, int2* __restrict__ pk, int E) {
  int e = blockIdx.x * 256 + threadIdx.x;
  if (e >= E) return;
  int c = col[e];
  int pos = atomicAdd(&start[c], 1);
  pk[pos] = make_int2(row[e], __float_as_int(w[e] * dinv[row[e]]));
}

// ---------- weight folding (tiny, once per call) ----------
__global__ void k_prep(const float* __restrict__ Wp, const float* __restrict__ bp,
                       const float* __restrict__ W1,
                       const float* __restrict__ W2, const float* __restrict__ Wa,
                       const float* __restrict__ ba, const float* __restrict__ b2,
                       float* __restrict__ Wfuse, float* __restrict__ bfuse,
                       float* __restrict__ Mcat, float* __restrict__ bU) {
  int id = blockIdx.x * 256 + threadIdx.x;
  if (id < 8192) {                      // Wfuse[i,j] = (Wp@W1)[i,j]
    int i = id >> 7, j = id & 127;
    float s = 0.f;
    for (int k = 0; k < 128; k++) s = fmaf(Wp[i * 128 + k], W1[k * 128 + j], s);
    Wfuse[id] = s;
  } else if (id < 8320) {               // bfuse = bp@W1
    int j = id - 8192;
    float s = 0.f;
    for (int k = 0; k < 128; k++) s = fmaf(bp[k], W1[k * 128 + j], s);
    bfuse[j] = s;
  } else if (id < 8320 + 16384) {       // Mcat = [W2@Wa0 | W2@Wa1]
    int m = id - 8320;
    int i = m >> 7, j = m & 127;
    int jj = j & 63, koff = (j < 64) ? 0 : 64;
    float s = 0.f;
    for (int k = 0; k < 64; k++) s = fmaf(W2[i * 64 + k], Wa[(koff + k) * 64 + jj], s);
    Mcat[i * 128 + j] = s;
  } else if (id < 8320 + 16384 + 128) { // bU = [b2@Wa0+ba | b2@Wa1]
    int j = id - 8320 - 16384;
    int jj = j & 63, koff = (j < 64) ? 0 : 64;
    float s = (j < 64) ? ba[j] : 0.f;
    for (int k = 0; k < 64; k++) s = fmaf(b2[k], Wa[(koff + k) * 64 + jj], s);
    bU[j] = s;
  }
}

// ---------- tiled fp32 GEMM: C[N,M] = A[N,K] @ W[K,M] (+bias) ----------
template<int K, int M, bool BIAS>
__global__ __launch_bounds__(256, 2) void k_gemm(const float* __restrict__ A,
                                                 const float* __restrict__ W,
                                                 const float* __restrict__ bias,
                                                 float* __restrict__ C, int N) {
  constexpr int KC = 64;
  constexpr int NB = M / 64;
  __shared__ alignas(16) float sA[128 * 68];
  __shared__ alignas(16) float sW[KC * (M + 4)];
  const int t = threadIdx.x;
  const int rg = t >> 4, cg = t & 15;
  const int r0 = blockIdx.x * 128;
  float acc[NB][8][4] = {};
  for (int kc = 0; kc < K; kc += KC) {
    __syncthreads();
#pragma unroll
    for (int i = 0; i < 8; i++) {
      int idx = t * 4 + i * 1024;
      int r = idx >> 6, k = idx & 63;
      int gr = r0 + r;
      float4 v = make_float4(0.f, 0.f, 0.f, 0.f);
      if (gr < N) v = *(const float4*)&A[(size_t)gr * K + kc + k];
      *(float4*)&sA[r * 68 + k] = v;
    }
#pragma unroll
    for (int i = 0; i < KC * M / 1024; i++) {
      int idx = t * 4 + i * 1024;
      int r = idx / M, c = idx % M;
      *(float4*)&sW[r * (M + 4) + c] = *(const float4*)&W[(size_t)(kc + r) * M + c];
    }
    __syncthreads();
#pragma unroll
    for (int k0 = 0; k0 < KC; k0 += 4) {
      float4 av[8];
#pragma unroll
      for (int ri = 0; ri < 8; ri++) av[ri] = *(const float4*)&sA[(rg + 16 * ri) * 68 + k0];
      float4 wv[4][NB];
#pragma unroll
      for (int kk = 0; kk < 4; kk++)
#pragma unroll
        for (int b = 0; b < NB; b++)
          wv[kk][b] = *(const float4*)&sW[(k0 + kk) * (M + 4) + b * 64 + cg * 4];
#pragma unroll
      for (int kk = 0; kk < 4; kk++)
#pragma unroll
        for (int ri = 0; ri < 8; ri++) {
          float a = ((const float*)&av[ri])[kk];
#pragma unroll
          for (int b = 0; b < NB; b++) {
            acc[b][ri][0] = fmaf(a, wv[kk][b].x, acc[b][ri][0]);
            acc[b][ri][1] = fmaf(a, wv[kk][b].y, acc[b][ri][1]);
            acc[b][ri][2] = fmaf(a, wv[kk][b].z, acc[b][ri][2]);
            acc[b][ri][3] = fmaf(a, wv[kk][b].w, acc[b][ri][3]);
          }
        }
    }
  }
#pragma unroll
  for (int ri = 0; ri < 8; ri++) {
    int rrow = r0 + rg + 16 * ri;
    if (rrow < N) {
#pragma unroll
      for (int b = 0; b < NB; b++) {
        float4 o;
        o.x = acc[b][ri][0]; o.y = acc[b][ri][1]; o.z = acc[b][ri][2]; o.w = acc[b][ri][3];
        if (BIAS) {
          float4 bv = *(const float4*)&bias[b * 64 + cg * 4];
          o.x += bv.x; o.y += bv.y; o.z += bv.z; o.w += bv.w;
        }
        *(float4*)&C[(size_t)rrow * M + b * 64 + cg * 4] = o;
      }
    }
  }
}

// ---------- CSR gather: h[v] = act(dinv*sum + dinv^2*hw[v] + bias) ----------
template<int M, bool RELU>
__global__ void k_gather(const int* __restrict__ start, const int2* __restrict__ pk,
                         const float* __restrict__ hw, const float* __restrict__ dinv,
                         const float* __restrict__ bias, float* __restrict__ hout, int N) {
  constexpr int L = M / 4;
  constexpr int NPB = 256 / L;
  const int t = threadIdx.x;
  const int v = blockIdx.x * NPB + t / L;
  if (v >= N) return;
  const int j = (t % L) * 4;
  const int b = v ? start[v - 1] : 0;
  const int en = start[v];
  float4 a0 = make_float4(0.f, 0.f, 0.f, 0.f);
  float4 a1 = make_float4(0.f, 0.f, 0.f, 0.f);
  int i = b;
  for (; i + 3 < en; i += 4) {
    int2 q0 = pk[i], q1 = pk[i + 1], q2 = pk[i + 2], q3 = pk[i + 3];
    float n0 = __int_as_float(q0.y), n1 = __int_as_float(q1.y);
    float n2 = __int_as_float(q2.y), n3 = __int_as_float(q3.y);
    float4 h0 = *(const float4*)&hw[(size_t)q0.x * M + j];
    float4 h1 = *(const float4*)&hw[(size_t)q1.x * M + j];
    float4 h2 = *(const float4*)&hw[(size_t)q2.x * M + j];
    float4 h3 = *(const float4*)&hw[(size_t)q3.x * M + j];
    a0.x = fmaf(n0, h0.x, a0.x); a0.y = fmaf(n0, h0.y, a0.y);
    a0.z = fmaf(n0, h0.z, a0.z); a0.w = fmaf(n0, h0.w, a0.w);
    a1.x = fmaf(n1, h1.x, a1.x); a1.y = fmaf(n1, h1.y, a1.y);
    a1.z = fmaf(n1, h1.z, a1.z); a1.w = fmaf(n1, h1.w, a1.w);
    a0.x = fmaf(n2, h2.x, a0.x); a0.y = fmaf(n2, h2.y, a0.y);
    a0.z = fmaf(n2, h2.z, a0.z); a0.w = fmaf(n2, h2.w, a0.w);
    a1.x = fmaf(n3, h3.x, a1.x); a1.y = fmaf(n3, h3.y, a1.y);
    a1.z = fmaf(n3, h3.z, a1.z); a1.w = fmaf(n3, h3.w, a1.w);
  }
  for (; i < en; i++) {
    int2 p = pk[i];
    float n = __int_as_float(p.y);
    float4 h = *(const float4*)&hw[(size_t)p.x * M + j];
    a0.x = fmaf(n, h.x, a0.x); a0.y = fmaf(n, h.y, a0.y);
    a0.z = fmaf(n, h.z, a0.z); a0.w = fmaf(n, h.w, a0.w);
  }
  float4 acc;
  acc.x = a0.x + a1.x; acc.y = a0.y + a1.y; acc.z = a0.z + a1.z; acc.w = a0.w + a1.w;
  const float d = dinv[v];
  const float s = d * d;
  float4 hv = *(const float4*)&hw[(size_t)v * M + j];
  float4 bv = *(const float4*)&bias[j];
  float4 o;
  o.x = fmaf(d, acc.x, fmaf(s, hv.x, bv.x));
  o.y = fmaf(d, acc.y, fmaf(s, hv.y, bv.y));
  o.z = fmaf(d, acc.z, fmaf(s, hv.z, bv.z));
  o.w = fmaf(d, acc.w, fmaf(s, hv.w, bv.w));
  if (RELU) {
    o.x = fmaxf(o.x, 0.f); o.y = fmaxf(o.y, 0.f);
    o.z = fmaxf(o.z, 0.f); o.w = fmaxf(o.w, 0.f);
  }
  *(float4*)&hout[(size_t)v * M + j] = o;
}

// ---------- per-edge kernel: logit = relu(U0[p0]+U1[p1]) @ Wb(relu) @ Wc ----------
// 64 edges per block, 256 threads.  (R3 version, verbatim — known-good ~300us.)
__global__ __launch_bounds__(256) void k_edge(const float* __restrict__ U,
    const int* __restrict__ p0, const int* __restrict__ p1,
    const float* __restrict__ Wb, const float* __restrict__ bb,
    const float* __restrict__ Wc, const float* __restrict__ bc,
    float* __restrict__ logits, int ES) {
  __shared__ alignas(16) float sWb[64 * 36];   // [k][c] stride 36
  __shared__ alignas(16) float sS1[64 * 68];   // [p][k] stride 68
  __shared__ alignas(16) float sS2[64 * 36];   // [p][j] stride 36
  __shared__ float sWc[32], sbb[32], sbc;
  const int t = threadIdx.x;
#pragma unroll
  for (int i = t * 4; i < 64 * 32; i += 1024) {
    int r = i >> 5, c = i & 31;
    *(float4*)&sWb[r * 36 + c] = *(const float4*)&Wb[i];
  }
  if (t < 32) { sWc[t] = Wc[t]; sbb[t] = bb[t]; }
  if (t == 0) sbc = bc[0];
  const int base = blockIdx.x << 6;
  {  // gather + add + relu -> s1
    int p = t >> 2, q = t & 3;
    int e = base + p; if (e >= ES) e = ES - 1;
    const float* r0 = U + (size_t)p0[e] * 128;        // U0 half: cols 0..63
    const float* r1 = U + (size_t)p1[e] * 128 + 64;   // U1 half: cols 64..127
#pragma unroll
    for (int i = 0; i < 4; i++) {
      int c = i * 16 + q * 4;
      float4 a = *(const float4*)&r0[c];
      float4 b = *(const float4*)&r1[c];
      float4 o;
      o.x = fmaxf(a.x + b.x, 0.f); o.y = fmaxf(a.y + b.y, 0.f);
      o.z = fmaxf(a.z + b.z, 0.f); o.w = fmaxf(a.w + b.w, 0.f);
      *(float4*)&sS1[p * 68 + c] = o;
    }
  }
  __syncthreads();
  // layer b: rows rg*4+ri, cols cg*2..+1
  const int rg = t >> 4, cg = t & 15;
  float accb[4][2] = {};
#pragma unroll
  for (int k0 = 0; k0 < 64; k0 += 4) {
    float4 av[4];
#pragma unroll
    for (int ri = 0; ri < 4; ri++) av[ri] = *(const float4*)&sS1[(rg * 4 + ri) * 68 + k0];
    float2 wv[4];
#pragma unroll
    for (int kk = 0; kk < 4; kk++) wv[kk] = *(const float2*)&sWb[(k0 + kk) * 36 + cg * 2];
#pragma unroll
    for (int kk = 0; kk < 4; kk++)
#pragma unroll
      for (int ri = 0; ri < 4; ri++) {
        float a = ((const float*)&av[ri])[kk];
        accb[ri][0] = fmaf(a, wv[kk].x, accb[ri][0]);
        accb[ri][1] = fmaf(a, wv[kk].y, accb[ri][1]);
      }
  }
#pragma unroll
  for (int ri = 0; ri < 4; ri++) {
    float2 o;
    o.x = fmaxf(accb[ri][0] + sbb[cg * 2 + 0], 0.f);
    o.y = fmaxf(accb[ri][1] + sbb[cg * 2 + 1], 0.f);
    *(float2*)&sS2[(rg * 4 + ri) * 36 + cg * 2] = o;
  }
  __syncthreads();
  {  // layer c
    int p = t >> 2, q = t & 3;
    float s = 0.f;
#pragma unroll
    for (int jj = 0; jj < 8; jj++) {
      int j = q + jj * 4;
      s = fmaf(sS2[p * 36 + j], sWc[j], s);
    }
    s += __shfl_down(s, 2);
    s += __shfl_down(s, 1);
    if (q == 0 && base + p < ES) logits[base + p] = s + sbc;
  }
}

// ---------- fused per-graph softmax: one block per graph (eg sorted) ----------
DEVINL int lbound(const int* __restrict__ a, int n, int key) {
  int lo = 0, hi = n;
  while (lo < hi) { int mid = (lo + hi) >> 1; if (a[mid] < key) lo = mid + 1; else hi = mid; }
  return lo;
}
__global__ __launch_bounds__(512) void k_softmax(const float* __restrict__ logits,
                          const int* __restrict__ eg,
                          float* __restrict__ out, int ES) {
  const int g = blockIdx.x;
  const int t = threadIdx.x;
  const int lo = lbound(eg, ES, g);
  const int hi = lbound(eg, ES, g + 1);
  if (lo >= hi) return;
  __shared__ float red[512];
  __shared__ float s_m, s_z;
  float m = -3.4e38f;
  for (int i = lo + t; i < hi; i += 512) m = fmaxf(m, logits[i]);
  red[t] = m; __syncthreads();
#pragma unroll
  for (int off = 256; off >= 1; off >>= 1) {
    if (t < off) red[t] = fmaxf(red[t], red[t + off]);
    __syncthreads();
  }
  if (t == 0) s_m = red[0];
  __syncthreads();
  const float gm = s_m;
  float z = 0.f;
  for (int i = lo + t; i < hi; i += 512) {
    float e = expf(logits[i] - gm);
    out[i] = e;                    // store exp; rescale in pass 3
    z += e;
  }
  red[t] = z; __syncthreads();
#pragma unroll
  for (int off = 256; off >= 1; off >>= 1) {
    if (t < off) red[t] += red[t + off];
    __syncthreads();
  }
  if (t == 0) s_z = red[0];
  __syncthreads();
  const float inv = 1.0f / s_z;
  for (int i = lo + t; i < hi; i += 512) out[i] *= inv;
}

// ---------------------------------------------------------------------------
extern "C" void kernel_launch(void* const* d_in, const int* in_sizes, int n_in,
                              void* d_out, int out_size, void* d_ws, size_t ws_size,
                              hipStream_t stream) {
  const float* x  = (const float*)d_in[0];
  const int* ei   = (const int*)d_in[1];
  const float* ew = (const float*)d_in[2];
  const int* pi   = (const int*)d_in[3];
  const int* eg   = (const int*)d_in[4];
  const float* Wp = (const float*)d_in[6];
  const float* bp = (const float*)d_in[7];
  const float* W1 = (const float*)d_in[8];
  const float* b1 = (const float*)d_in[9];
  const float* W2 = (const float*)d_in[10];
  const float* b2 = (const float*)d_in[11];
  const float* Wa = (const float*)d_in[12];
  const float* ba = (const float*)d_in[13];
  const float* Wb = (const float*)d_in[14];
  const float* bb = (const float*)d_in[15];
  const float* Wc = (const float*)d_in[16];
  const float* bc = (const float*)d_in[17];

  const int N  = in_sizes[0] / 64;
  const int E  = in_sizes[2];
  const int ES = in_sizes[4];
  const int G  = 128;

  float* ws = (float*)d_ws;
  size_t o = 0;
  const size_t Npad = ((size_t)N + 31) & ~(size_t)31;
  int* cnt = (int*)(ws + o);    o += Npad;   // dead after scan1 -> reused as dinv
  float* dinv = (float*)cnt;
  float* degF = (float*)(ws + o); o += Npad;
  int* start = (int*)(ws + o);  o += Npad;
  int* bsum = (int*)(ws + o);   o += 512;
  int* boff = (int*)(ws + o);   o += 512;
  int2* pk = (int2*)(ws + o);   o += (size_t)E * 2;
  float* A = ws + o;            o += (size_t)N * 128;   // h1 -> U
  float* B = ws + o;            o += (size_t)N * 128;   // hw1 -> V -> logits
  float* Wfuse = ws + o;        o += 8192;
  float* bfuse = ws + o;        o += 128;
  float* Mcat = ws + o;         o += 16384;
  float* bU = ws + o;           o += 128;

  const int* row = ei;
  const int* col = ei + E;
  const int* p0 = pi;
  const int* p1 = pi + ES;
  float* out = (float*)d_out;

  const int gN = (N + 255) / 256;
  const int gE = (E + 255) / 256;
  const int nb = gN;

  // ---- weight folding + CSR build ----
  hipMemsetAsync(cnt, 0, 2 * Npad * sizeof(int), stream);   // cnt + degF (adjacent)
  k_prep<<<98, 256, 0, stream>>>(Wp, bp, W1, W2, Wa, ba, b2, Wfuse, bfuse, Mcat, bU);
  k_hist2<<<gE, 256, 0, stream>>>(col, ew, cnt, degF, E);
  k_scan1<<<nb, 256, 0, stream>>>(cnt, start, bsum, N);
  k_scan2<<<1, 512, 0, stream>>>(bsum, boff, nb);
  k_scan3dinv<<<nb, 256, 0, stream>>>(start, boff, degF, dinv, N);
  k_fill<<<gE, 256, 0, stream>>>(row, col, ew, dinv, start, pk, E);

  // ---- node pipeline: 2 GEMMs + 2 gathers ----
  const int gRows = (N + 127) / 128;
  k_gemm<64, 128, true><<<gRows, 256, 0, stream>>>(x, Wfuse, bfuse, B, N);              // hw1
  k_gather<128, true><<<(N + 7) / 8, 256, 0, stream>>>(start, pk, B, dinv, b1, A, N);   // h1
  k_gemm<128, 128, false><<<gRows, 256, 0, stream>>>(A, Mcat, nullptr, B, N);           // V
  k_gather<128, false><<<(N + 7) / 8, 256, 0, stream>>>(start, pk, B, dinv, bU, A, N);  // U

  // ---- per-edge MLP ----
  k_edge<<<(ES + 63) / 64, 256, 0, stream>>>(A, p0, p1, Wb, bb, Wc, bc, B, ES);

  // ---- per-graph softmax ----
  k_softmax<<<G, 512, 0, stream>>>(B, eg, out, ES);
}

// Round 6
// 646.755 us; speedup vs baseline: 4.6359x; 2.0808x over previous
//
#include <hip/hip_runtime.h>
#include <hip/hip_bf16.h>
#include <cstdint>

#define DEVINL __device__ __forceinline__

// ---------------------------------------------------------------------------
// 2-layer GCN (gcn_norm w/ self-loops) -> per-pair MLP -> per-graph softmax.
// R6: k_gemm de-spilled. R5 evidence: VGPR_Count=128 (cap) with ~155 live regs
// -> ~11KB/thread scratch traffic -> 2.2GB HBM @2.9TB/s -> 770us, VALUBusy 1.6%.
// Fix: wv loaded per-kk (8 live regs not 32), KC 64->32 (LDS 35KB, 4 blocks/CU),
// __launch_bounds__(256,4). Everything else identical to R5.
// ---------------------------------------------------------------------------

// ---------- CSR build ----------
__global__ void k_hist2(const int* __restrict__ col, const float* __restrict__ w,
                        int* __restrict__ cnt, float* __restrict__ degF, int E) {
  int e = blockIdx.x * 256 + threadIdx.x;
  if (e < E) {
    int c = col[e];
    atomicAdd(&cnt[c], 1);
    atomicAdd(&degF[c], w[e]);
  }
}

__global__ void k_scan1(const int* __restrict__ cnt, int* __restrict__ start,
                        int* __restrict__ bsum, int N) {
  __shared__ int s[256];
  int t = threadIdx.x;
  int i = blockIdx.x * 256 + t;
  int v = (i < N) ? cnt[i] : 0;
  s[t] = v; __syncthreads();
  int x = v;
#pragma unroll
  for (int off = 1; off < 256; off <<= 1) {
    int y = (t >= off) ? s[t - off] : 0;
    __syncthreads();
    x += y; s[t] = x;
    __syncthreads();
  }
  if (i < N) start[i] = x - v;
  if (t == 255) bsum[blockIdx.x] = x;
}
__global__ void k_scan2(const int* __restrict__ bsum, int* __restrict__ boff, int nb) {
  __shared__ int s[512];
  int t = threadIdx.x;
  int v = (t < nb) ? bsum[t] : 0;
  s[t] = v; __syncthreads();
  int x = v;
#pragma unroll
  for (int off = 1; off < 512; off <<= 1) {
    int y = (t >= off) ? s[t - off] : 0;
    __syncthreads();
    x += y; s[t] = x;
    __syncthreads();
  }
  if (t < nb) boff[t] = x - v;
}
__global__ void k_scan3dinv(int* __restrict__ start, const int* __restrict__ boff,
                            const float* __restrict__ degF, float* __restrict__ dinv, int N) {
  int i = blockIdx.x * 256 + threadIdx.x;
  if (i < N) {
    start[i] += boff[blockIdx.x];
    dinv[i] = rsqrtf(1.0f + degF[i]);
  }
}

__global__ void k_fill(const int* __restrict__ row, const int* __restrict__ col,
                       const float* __restrict__ w, const float* __restrict__ dinv,
                       int* __restrict__ start, int2* __restrict__ pk, int E) {
  int e = blockIdx.x * 256 + threadIdx.x;
  if (e >= E) return;
  int c = col[e];
  int pos = atomicAdd(&start[c], 1);
  pk[pos] = make_int2(row[e], __float_as_int(w[e] * dinv[row[e]]));
}

// ---------- weight folding (tiny, once per call) ----------
__global__ void k_prep(const float* __restrict__ Wp, const float* __restrict__ bp,
                       const float* __restrict__ W1,
                       const float* __restrict__ W2, const float* __restrict__ Wa,
                       const float* __restrict__ ba, const float* __restrict__ b2,
                       float* __restrict__ Wfuse, float* __restrict__ bfuse,
                       float* __restrict__ Mcat, float* __restrict__ bU) {
  int id = blockIdx.x * 256 + threadIdx.x;
  if (id < 8192) {                      // Wfuse[i,j] = (Wp@W1)[i,j]
    int i = id >> 7, j = id & 127;
    float s = 0.f;
    for (int k = 0; k < 128; k++) s = fmaf(Wp[i * 128 + k], W1[k * 128 + j], s);
    Wfuse[id] = s;
  } else if (id < 8320) {               // bfuse = bp@W1
    int j = id - 8192;
    float s = 0.f;
    for (int k = 0; k < 128; k++) s = fmaf(bp[k], W1[k * 128 + j], s);
    bfuse[j] = s;
  } else if (id < 8320 + 16384) {       // Mcat = [W2@Wa0 | W2@Wa1]
    int m = id - 8320;
    int i = m >> 7, j = m & 127;
    int jj = j & 63, koff = (j < 64) ? 0 : 64;
    float s = 0.f;
    for (int k = 0; k < 64; k++) s = fmaf(W2[i * 64 + k], Wa[(koff + k) * 64 + jj], s);
    Mcat[i * 128 + j] = s;
  } else if (id < 8320 + 16384 + 128) { // bU = [b2@Wa0+ba | b2@Wa1]
    int j = id - 8320 - 16384;
    int jj = j & 63, koff = (j < 64) ? 0 : 64;
    float s = (j < 64) ? ba[j] : 0.f;
    for (int k = 0; k < 64; k++) s = fmaf(b2[k], Wa[(koff + k) * 64 + jj], s);
    bU[j] = s;
  }
}

// ---------- tiled fp32 GEMM: C[N,M] = A[N,K] @ W[K,M] (+bias) ----------
// 128-row x M-col tile, 256 threads, microtile 8x(4*NB). KC=32 -> 35KB LDS,
// 4 blocks/CU. wv loaded per-kk: live regs ~ acc64 + av32 + wv8 + addr < 128.
template<int K, int M, bool BIAS>
__global__ __launch_bounds__(256, 4) void k_gemm(const float* __restrict__ A,
                                                 const float* __restrict__ W,
                                                 const float* __restrict__ bias,
                                                 float* __restrict__ C, int N) {
  constexpr int KC = 32;
  constexpr int NB = M / 64;
  __shared__ alignas(16) float sA[128 * 36];       // [r][k], stride 36
  __shared__ alignas(16) float sW[KC * (M + 4)];   // [k][c], stride M+4
  const int t = threadIdx.x;
  const int rg = t >> 4, cg = t & 15;
  const int r0 = blockIdx.x * 128;
  float acc[NB][8][4] = {};
  for (int kc = 0; kc < K; kc += KC) {
    __syncthreads();
#pragma unroll
    for (int i = 0; i < 4; i++) {            // stage A: 128x32 floats
      int idx = (t + i * 256) * 4;
      int r = idx >> 5, k = idx & 31;
      int gr = r0 + r;
      float4 v = make_float4(0.f, 0.f, 0.f, 0.f);
      if (gr < N) v = *(const float4*)&A[(size_t)gr * K + kc + k];
      *(float4*)&sA[r * 36 + k] = v;
    }
#pragma unroll
    for (int i = 0; i < KC * M / 1024; i++) {  // stage W chunk: KCxM floats
      int idx = (t + i * 256) * 4;
      int r = idx / M, c = idx % M;
      *(float4*)&sW[r * (M + 4) + c] = *(const float4*)&W[(size_t)(kc + r) * M + c];
    }
    __syncthreads();
    for (int k0 = 0; k0 < KC; k0 += 4) {
      float4 av[8];
#pragma unroll
      for (int ri = 0; ri < 8; ri++) av[ri] = *(const float4*)&sA[(rg + 16 * ri) * 36 + k0];
#pragma unroll
      for (int kk = 0; kk < 4; kk++) {
        float4 wv[NB];
#pragma unroll
        for (int b = 0; b < NB; b++)
          wv[b] = *(const float4*)&sW[(k0 + kk) * (M + 4) + b * 64 + cg * 4];
#pragma unroll
        for (int ri = 0; ri < 8; ri++) {
          float a = ((const float*)&av[ri])[kk];
#pragma unroll
          for (int b = 0; b < NB; b++) {
            acc[b][ri][0] = fmaf(a, wv[b].x, acc[b][ri][0]);
            acc[b][ri][1] = fmaf(a, wv[b].y, acc[b][ri][1]);
            acc[b][ri][2] = fmaf(a, wv[b].z, acc[b][ri][2]);
            acc[b][ri][3] = fmaf(a, wv[b].w, acc[b][ri][3]);
          }
        }
      }
    }
  }
#pragma unroll
  for (int ri = 0; ri < 8; ri++) {
    int rrow = r0 + rg + 16 * ri;
    if (rrow < N) {
#pragma unroll
      for (int b = 0; b < NB; b++) {
        float4 o;
        o.x = acc[b][ri][0]; o.y = acc[b][ri][1]; o.z = acc[b][ri][2]; o.w = acc[b][ri][3];
        if (BIAS) {
          float4 bv = *(const float4*)&bias[b * 64 + cg * 4];
          o.x += bv.x; o.y += bv.y; o.z += bv.z; o.w += bv.w;
        }
        *(float4*)&C[(size_t)rrow * M + b * 64 + cg * 4] = o;
      }
    }
  }
}

// ---------- CSR gather: h[v] = act(dinv*sum + dinv^2*hw[v] + bias) ----------
template<int M, bool RELU>
__global__ void k_gather(const int* __restrict__ start, const int2* __restrict__ pk,
                         const float* __restrict__ hw, const float* __restrict__ dinv,
                         const float* __restrict__ bias, float* __restrict__ hout, int N) {
  constexpr int L = M / 4;
  constexpr int NPB = 256 / L;
  const int t = threadIdx.x;
  const int v = blockIdx.x * NPB + t / L;
  if (v >= N) return;
  const int j = (t % L) * 4;
  const int b = v ? start[v - 1] : 0;
  const int en = start[v];
  float4 a0 = make_float4(0.f, 0.f, 0.f, 0.f);
  float4 a1 = make_float4(0.f, 0.f, 0.f, 0.f);
  int i = b;
  for (; i + 3 < en; i += 4) {
    int2 q0 = pk[i], q1 = pk[i + 1], q2 = pk[i + 2], q3 = pk[i + 3];
    float n0 = __int_as_float(q0.y), n1 = __int_as_float(q1.y);
    float n2 = __int_as_float(q2.y), n3 = __int_as_float(q3.y);
    float4 h0 = *(const float4*)&hw[(size_t)q0.x * M + j];
    float4 h1 = *(const float4*)&hw[(size_t)q1.x * M + j];
    float4 h2 = *(const float4*)&hw[(size_t)q2.x * M + j];
    float4 h3 = *(const float4*)&hw[(size_t)q3.x * M + j];
    a0.x = fmaf(n0, h0.x, a0.x); a0.y = fmaf(n0, h0.y, a0.y);
    a0.z = fmaf(n0, h0.z, a0.z); a0.w = fmaf(n0, h0.w, a0.w);
    a1.x = fmaf(n1, h1.x, a1.x); a1.y = fmaf(n1, h1.y, a1.y);
    a1.z = fmaf(n1, h1.z, a1.z); a1.w = fmaf(n1, h1.w, a1.w);
    a0.x = fmaf(n2, h2.x, a0.x); a0.y = fmaf(n2, h2.y, a0.y);
    a0.z = fmaf(n2, h2.z, a0.z); a0.w = fmaf(n2, h2.w, a0.w);
    a1.x = fmaf(n3, h3.x, a1.x); a1.y = fmaf(n3, h3.y, a1.y);
    a1.z = fmaf(n3, h3.z, a1.z); a1.w = fmaf(n3, h3.w, a1.w);
  }
  for (; i < en; i++) {
    int2 p = pk[i];
    float n = __int_as_float(p.y);
    float4 h = *(const float4*)&hw[(size_t)p.x * M + j];
    a0.x = fmaf(n, h.x, a0.x); a0.y = fmaf(n, h.y, a0.y);
    a0.z = fmaf(n, h.z, a0.z); a0.w = fmaf(n, h.w, a0.w);
  }
  float4 acc;
  acc.x = a0.x + a1.x; acc.y = a0.y + a1.y; acc.z = a0.z + a1.z; acc.w = a0.w + a1.w;
  const float d = dinv[v];
  const float s = d * d;
  float4 hv = *(const float4*)&hw[(size_t)v * M + j];
  float4 bv = *(const float4*)&bias[j];
  float4 o;
  o.x = fmaf(d, acc.x, fmaf(s, hv.x, bv.x));
  o.y = fmaf(d, acc.y, fmaf(s, hv.y, bv.y));
  o.z = fmaf(d, acc.z, fmaf(s, hv.z, bv.z));
  o.w = fmaf(d, acc.w, fmaf(s, hv.w, bv.w));
  if (RELU) {
    o.x = fmaxf(o.x, 0.f); o.y = fmaxf(o.y, 0.f);
    o.z = fmaxf(o.z, 0.f); o.w = fmaxf(o.w, 0.f);
  }
  *(float4*)&hout[(size_t)v * M + j] = o;
}

// ---------- per-edge kernel: logit = relu(U0[p0]+U1[p1]) @ Wb(relu) @ Wc ----------
// 64 edges per block, 256 threads.  (R3 version, verbatim — known-good.)
__global__ __launch_bounds__(256) void k_edge(const float* __restrict__ U,
    const int* __restrict__ p0, const int* __restrict__ p1,
    const float* __restrict__ Wb, const float* __restrict__ bb,
    const float* __restrict__ Wc, const float* __restrict__ bc,
    float* __restrict__ logits, int ES) {
  __shared__ alignas(16) float sWb[64 * 36];   // [k][c] stride 36
  __shared__ alignas(16) float sS1[64 * 68];   // [p][k] stride 68
  __shared__ alignas(16) float sS2[64 * 36];   // [p][j] stride 36
  __shared__ float sWc[32], sbb[32], sbc;
  const int t = threadIdx.x;
#pragma unroll
  for (int i = t * 4; i < 64 * 32; i += 1024) {
    int r = i >> 5, c = i & 31;
    *(float4*)&sWb[r * 36 + c] = *(const float4*)&Wb[i];
  }
  if (t < 32) { sWc[t] = Wc[t]; sbb[t] = bb[t]; }
  if (t == 0) sbc = bc[0];
  const int base = blockIdx.x << 6;
  {  // gather + add + relu -> s1
    int p = t >> 2, q = t & 3;
    int e = base + p; if (e >= ES) e = ES - 1;
    const float* r0 = U + (size_t)p0[e] * 128;        // U0 half: cols 0..63
    const float* r1 = U + (size_t)p1[e] * 128 + 64;   // U1 half: cols 64..127
#pragma unroll
    for (int i = 0; i < 4; i++) {
      int c = i * 16 + q * 4;
      float4 a = *(const float4*)&r0[c];
      float4 b = *(const float4*)&r1[c];
      float4 o;
      o.x = fmaxf(a.x + b.x, 0.f); o.y = fmaxf(a.y + b.y, 0.f);
      o.z = fmaxf(a.z + b.z, 0.f); o.w = fmaxf(a.w + b.w, 0.f);
      *(float4*)&sS1[p * 68 + c] = o;
    }
  }
  __syncthreads();
  // layer b: rows rg*4+ri, cols cg*2..+1
  const int rg = t >> 4, cg = t & 15;
  float accb[4][2] = {};
#pragma unroll
  for (int k0 = 0; k0 < 64; k0 += 4) {
    float4 av[4];
#pragma unroll
    for (int ri = 0; ri < 4; ri++) av[ri] = *(const float4*)&sS1[(rg * 4 + ri) * 68 + k0];
    float2 wv[4];
#pragma unroll
    for (int kk = 0; kk < 4; kk++) wv[kk] = *(const float2*)&sWb[(k0 + kk) * 36 + cg * 2];
#pragma unroll
    for (int kk = 0; kk < 4; kk++)
#pragma unroll
      for (int ri = 0; ri < 4; ri++) {
        float a = ((const float*)&av[ri])[kk];
        accb[ri][0] = fmaf(a, wv[kk].x, accb[ri][0]);
        accb[ri][1] = fmaf(a, wv[kk].y, accb[ri][1]);
      }
  }
#pragma unroll
  for (int ri = 0; ri < 4; ri++) {
    float2 o;
    o.x = fmaxf(accb[ri][0] + sbb[cg * 2 + 0], 0.f);
    o.y = fmaxf(accb[ri][1] + sbb[cg * 2 + 1], 0.f);
    *(float2*)&sS2[(rg * 4 + ri) * 36 + cg * 2] = o;
  }
  __syncthreads();
  {  // layer c
    int p = t >> 2, q = t & 3;
    float s = 0.f;
#pragma unroll
    for (int jj = 0; jj < 8; jj++) {
      int j = q + jj * 4;
      s = fmaf(sS2[p * 36 + j], sWc[j], s);
    }
    s += __shfl_down(s, 2);
    s += __shfl_down(s, 1);
    if (q == 0 && base + p < ES) logits[base + p] = s + sbc;
  }
}

// ---------- fused per-graph softmax: one block per graph (eg sorted) ----------
DEVINL int lbound(const int* __restrict__ a, int n, int key) {
  int lo = 0, hi = n;
  while (lo < hi) { int mid = (lo + hi) >> 1; if (a[mid] < key) lo = mid + 1; else hi = mid; }
  return lo;
}
__global__ __launch_bounds__(512) void k_softmax(const float* __restrict__ logits,
                          const int* __restrict__ eg,
                          float* __restrict__ out, int ES) {
  const int g = blockIdx.x;
  const int t = threadIdx.x;
  const int lo = lbound(eg, ES, g);
  const int hi = lbound(eg, ES, g + 1);
  if (lo >= hi) return;
  __shared__ float red[512];
  __shared__ float s_m, s_z;
  float m = -3.4e38f;
  for (int i = lo + t; i < hi; i += 512) m = fmaxf(m, logits[i]);
  red[t] = m; __syncthreads();
#pragma unroll
  for (int off = 256; off >= 1; off >>= 1) {
    if (t < off) red[t] = fmaxf(red[t], red[t + off]);
    __syncthreads();
  }
  if (t == 0) s_m = red[0];
  __syncthreads();
  const float gm = s_m;
  float z = 0.f;
  for (int i = lo + t; i < hi; i += 512) {
    float e = expf(logits[i] - gm);
    out[i] = e;                    // store exp; rescale in pass 3
    z += e;
  }
  red[t] = z; __syncthreads();
#pragma unroll
  for (int off = 256; off >= 1; off >>= 1) {
    if (t < off) red[t] += red[t + off];
    __syncthreads();
  }
  if (t == 0) s_z = red[0];
  __syncthreads();
  const float inv = 1.0f / s_z;
  for (int i = lo + t; i < hi; i += 512) out[i] *= inv;
}

// ---------------------------------------------------------------------------
extern "C" void kernel_launch(void* const* d_in, const int* in_sizes, int n_in,
                              void* d_out, int out_size, void* d_ws, size_t ws_size,
                              hipStream_t stream) {
  const float* x  = (const float*)d_in[0];
  const int* ei   = (const int*)d_in[1];
  const float* ew = (const float*)d_in[2];
  const int* pi   = (const int*)d_in[3];
  const int* eg   = (const int*)d_in[4];
  const float* Wp = (const float*)d_in[6];
  const float* bp = (const float*)d_in[7];
  const float* W1 = (const float*)d_in[8];
  const float* b1 = (const float*)d_in[9];
  const float* W2 = (const float*)d_in[10];
  const float* b2 = (const float*)d_in[11];
  const float* Wa = (const float*)d_in[12];
  const float* ba = (const float*)d_in[13];
  const float* Wb = (const float*)d_in[14];
  const float* bb = (const float*)d_in[15];
  const float* Wc = (const float*)d_in[16];
  const float* bc = (const float*)d_in[17];

  const int N  = in_sizes[0] / 64;
  const int E  = in_sizes[2];
  const int ES = in_sizes[4];
  const int G  = 128;

  float* ws = (float*)d_ws;
  size_t o = 0;
  const size_t Npad = ((size_t)N + 31) & ~(size_t)31;
  int* cnt = (int*)(ws + o);    o += Npad;   // dead after scan1 -> reused as dinv
  float* dinv = (float*)cnt;
  float* degF = (float*)(ws + o); o += Npad;
  int* start = (int*)(ws + o);  o += Npad;
  int* bsum = (int*)(ws + o);   o += 512;
  int* boff = (int*)(ws + o);   o += 512;
  int2* pk = (int2*)(ws + o);   o += (size_t)E * 2;
  float* A = ws + o;            o += (size_t)N * 128;   // h1 -> U
  float* B = ws + o;            o += (size_t)N * 128;   // hw1 -> V -> logits
  float* Wfuse = ws + o;        o += 8192;
  float* bfuse = ws + o;        o += 128;
  float* Mcat = ws + o;         o += 16384;
  float* bU = ws + o;           o += 128;

  const int* row = ei;
  const int* col = ei + E;
  const int* p0 = pi;
  const int* p1 = pi + ES;
  float* out = (float*)d_out;

  const int gN = (N + 255) / 256;
  const int gE = (E + 255) / 256;
  const int nb = gN;

  // ---- weight folding + CSR build ----
  hipMemsetAsync(cnt, 0, 2 * Npad * sizeof(int), stream);   // cnt + degF (adjacent)
  k_prep<<<98, 256, 0, stream>>>(Wp, bp, W1, W2, Wa, ba, b2, Wfuse, bfuse, Mcat, bU);
  k_hist2<<<gE, 256, 0, stream>>>(col, ew, cnt, degF, E);
  k_scan1<<<nb, 256, 0, stream>>>(cnt, start, bsum, N);
  k_scan2<<<1, 512, 0, stream>>>(bsum, boff, nb);
  k_scan3dinv<<<nb, 256, 0, stream>>>(start, boff, degF, dinv, N);
  k_fill<<<gE, 256, 0, stream>>>(row, col, ew, dinv, start, pk, E);

  // ---- node pipeline: 2 GEMMs + 2 gathers ----
  const int gRows = (N + 127) / 128;
  k_gemm<64, 128, true><<<gRows, 256, 0, stream>>>(x, Wfuse, bfuse, B, N);              // hw1
  k_gather<128, true><<<(N + 7) / 8, 256, 0, stream>>>(start, pk, B, dinv, b1, A, N);   // h1
  k_gemm<128, 128, false><<<gRows, 256, 0, stream>>>(A, Mcat, nullptr, B, N);           // V
  k_gather<128, false><<<(N + 7) / 8, 256, 0, stream>>>(start, pk, B, dinv, bU, A, N);  // U

  // ---- per-edge MLP ----
  k_edge<<<(ES + 63) / 64, 256, 0, stream>>>(A, p0, p1, Wb, bb, Wc, bc, B, ES);

  // ---- per-graph softmax ----
  k_softmax<<<G, 512, 0, stream>>>(B, eg, out, ES);
}

// Round 7
// 573.711 us; speedup vs baseline: 5.2261x; 1.1273x over previous
//
#include <hip/hip_runtime.h>
#include <hip/hip_bf16.h>
#include <cstdint>

#define DEVINL __device__ __forceinline__

// ---------------------------------------------------------------------------
// 2-layer GCN (gcn_norm w/ self-loops) -> per-pair MLP -> per-graph softmax.
// R7: bf16 storage for the three randomly-gathered feature tables (hw1, V, U)
// to halve gather traffic (R6: k_edge 103us @234MB FETCH; gathers similar).
// fp32 accumulation everywhere; h1 stays fp32 (streamed once, linearly).
// Error math: bf16 tables add ~1e-3 rel on logits -> ~2e-7 abs on softmax
// outputs (p~1.3e-4); threshold is 2.67e-6. Structure otherwise = R6.
// ---------------------------------------------------------------------------

DEVINL float bflo(unsigned u) { return __uint_as_float(u << 16); }
DEVINL float bfhi(unsigned u) { return __uint_as_float(u & 0xffff0000u); }
DEVINL unsigned packbf2(float a, float b) {   // RNE pack of 2 fp32 -> 2 bf16
  unsigned ua = __float_as_uint(a); ua = (ua + 0x7fff + ((ua >> 16) & 1)) >> 16;
  unsigned ub = __float_as_uint(b); ub = (ub + 0x7fff + ((ub >> 16) & 1)) >> 16;
  return ua | (ub << 16);
}

// ---------- CSR build ----------
__global__ void k_hist2(const int* __restrict__ col, const float* __restrict__ w,
                        int* __restrict__ cnt, float* __restrict__ degF, int E) {
  int e = blockIdx.x * 256 + threadIdx.x;
  if (e < E) {
    int c = col[e];
    atomicAdd(&cnt[c], 1);
    atomicAdd(&degF[c], w[e]);
  }
}

__global__ void k_scan1(const int* __restrict__ cnt, int* __restrict__ start,
                        int* __restrict__ bsum, int N) {
  __shared__ int s[256];
  int t = threadIdx.x;
  int i = blockIdx.x * 256 + t;
  int v = (i < N) ? cnt[i] : 0;
  s[t] = v; __syncthreads();
  int x = v;
#pragma unroll
  for (int off = 1; off < 256; off <<= 1) {
    int y = (t >= off) ? s[t - off] : 0;
    __syncthreads();
    x += y; s[t] = x;
    __syncthreads();
  }
  if (i < N) start[i] = x - v;
  if (t == 255) bsum[blockIdx.x] = x;
}
__global__ void k_scan2(const int* __restrict__ bsum, int* __restrict__ boff, int nb) {
  __shared__ int s[512];
  int t = threadIdx.x;
  int v = (t < nb) ? bsum[t] : 0;
  s[t] = v; __syncthreads();
  int x = v;
#pragma unroll
  for (int off = 1; off < 512; off <<= 1) {
    int y = (t >= off) ? s[t - off] : 0;
    __syncthreads();
    x += y; s[t] = x;
    __syncthreads();
  }
  if (t < nb) boff[t] = x - v;
}
__global__ void k_scan3dinv(int* __restrict__ start, const int* __restrict__ boff,
                            const float* __restrict__ degF, float* __restrict__ dinv, int N) {
  int i = blockIdx.x * 256 + threadIdx.x;
  if (i < N) {
    start[i] += boff[blockIdx.x];
    dinv[i] = rsqrtf(1.0f + degF[i]);
  }
}

__global__ void k_fill(const int* __restrict__ row, const int* __restrict__ col,
                       const float* __restrict__ w, const float* __restrict__ dinv,
                       int* __restrict__ start, int2* __restrict__ pk, int E) {
  int e = blockIdx.x * 256 + threadIdx.x;
  if (e >= E) return;
  int c = col[e];
  int pos = atomicAdd(&start[c], 1);
  pk[pos] = make_int2(row[e], __float_as_int(w[e] * dinv[row[e]]));
}

// ---------- weight folding (tiny, once per call) ----------
__global__ void k_prep(const float* __restrict__ Wp, const float* __restrict__ bp,
                       const float* __restrict__ W1,
                       const float* __restrict__ W2, const float* __restrict__ Wa,
                       const float* __restrict__ ba, const float* __restrict__ b2,
                       float* __restrict__ Wfuse, float* __restrict__ bfuse,
                       float* __restrict__ Mcat, float* __restrict__ bU) {
  int id = blockIdx.x * 256 + threadIdx.x;
  if (id < 8192) {                      // Wfuse[i,j] = (Wp@W1)[i,j]
    int i = id >> 7, j = id & 127;
    float s = 0.f;
    for (int k = 0; k < 128; k++) s = fmaf(Wp[i * 128 + k], W1[k * 128 + j], s);
    Wfuse[id] = s;
  } else if (id < 8320) {               // bfuse = bp@W1
    int j = id - 8192;
    float s = 0.f;
    for (int k = 0; k < 128; k++) s = fmaf(bp[k], W1[k * 128 + j], s);
    bfuse[j] = s;
  } else if (id < 8320 + 16384) {       // Mcat = [W2@Wa0 | W2@Wa1]
    int m = id - 8320;
    int i = m >> 7, j = m & 127;
    int jj = j & 63, koff = (j < 64) ? 0 : 64;
    float s = 0.f;
    for (int k = 0; k < 64; k++) s = fmaf(W2[i * 64 + k], Wa[(koff + k) * 64 + jj], s);
    Mcat[i * 128 + j] = s;
  } else if (id < 8320 + 16384 + 128) { // bU = [b2@Wa0+ba | b2@Wa1]
    int j = id - 8320 - 16384;
    int jj = j & 63, koff = (j < 64) ? 0 : 64;
    float s = (j < 64) ? ba[j] : 0.f;
    for (int k = 0; k < 64; k++) s = fmaf(b2[k], Wa[(koff + k) * 64 + jj], s);
    bU[j] = s;
  }
}

// ---------- tiled fp32 GEMM: C[N,M] = A[N,K] @ W[K,M] (+bias), C fp32|bf16 ----------
// KC=32, 4 blocks/CU, wv per-kk (no spill: R6 fix).
template<int K, int M, bool BIAS, bool CBF>
__global__ __launch_bounds__(256, 4) void k_gemm(const float* __restrict__ A,
                                                 const float* __restrict__ W,
                                                 const float* __restrict__ bias,
                                                 void* __restrict__ Cv, int N) {
  constexpr int KC = 32;
  constexpr int NB = M / 64;
  __shared__ alignas(16) float sA[128 * 36];       // [r][k], stride 36
  __shared__ alignas(16) float sW[KC * (M + 4)];   // [k][c], stride M+4
  const int t = threadIdx.x;
  const int rg = t >> 4, cg = t & 15;
  const int r0 = blockIdx.x * 128;
  float acc[NB][8][4] = {};
  for (int kc = 0; kc < K; kc += KC) {
    __syncthreads();
#pragma unroll
    for (int i = 0; i < 4; i++) {            // stage A: 128x32 floats
      int idx = (t + i * 256) * 4;
      int r = idx >> 5, k = idx & 31;
      int gr = r0 + r;
      float4 v = make_float4(0.f, 0.f, 0.f, 0.f);
      if (gr < N) v = *(const float4*)&A[(size_t)gr * K + kc + k];
      *(float4*)&sA[r * 36 + k] = v;
    }
#pragma unroll
    for (int i = 0; i < KC * M / 1024; i++) {  // stage W chunk: KCxM floats
      int idx = (t + i * 256) * 4;
      int r = idx / M, c = idx % M;
      *(float4*)&sW[r * (M + 4) + c] = *(const float4*)&W[(size_t)(kc + r) * M + c];
    }
    __syncthreads();
    for (int k0 = 0; k0 < KC; k0 += 4) {
      float4 av[8];
#pragma unroll
      for (int ri = 0; ri < 8; ri++) av[ri] = *(const float4*)&sA[(rg + 16 * ri) * 36 + k0];
#pragma unroll
      for (int kk = 0; kk < 4; kk++) {
        float4 wv[NB];
#pragma unroll
        for (int b = 0; b < NB; b++)
          wv[b] = *(const float4*)&sW[(k0 + kk) * (M + 4) + b * 64 + cg * 4];
#pragma unroll
        for (int ri = 0; ri < 8; ri++) {
          float a = ((const float*)&av[ri])[kk];
#pragma unroll
          for (int b = 0; b < NB; b++) {
            acc[b][ri][0] = fmaf(a, wv[b].x, acc[b][ri][0]);
            acc[b][ri][1] = fmaf(a, wv[b].y, acc[b][ri][1]);
            acc[b][ri][2] = fmaf(a, wv[b].z, acc[b][ri][2]);
            acc[b][ri][3] = fmaf(a, wv[b].w, acc[b][ri][3]);
          }
        }
      }
    }
  }
#pragma unroll
  for (int ri = 0; ri < 8; ri++) {
    int rrow = r0 + rg + 16 * ri;
    if (rrow < N) {
#pragma unroll
      for (int b = 0; b < NB; b++) {
        float4 o;
        o.x = acc[b][ri][0]; o.y = acc[b][ri][1]; o.z = acc[b][ri][2]; o.w = acc[b][ri][3];
        if (BIAS) {
          float4 bv = *(const float4*)&bias[b * 64 + cg * 4];
          o.x += bv.x; o.y += bv.y; o.z += bv.z; o.w += bv.w;
        }
        if (CBF) {
          uint2 pv;
          pv.x = packbf2(o.x, o.y);
          pv.y = packbf2(o.z, o.w);
          *(uint2*)&((unsigned short*)Cv)[(size_t)rrow * M + b * 64 + cg * 4] = pv;
        } else {
          *(float4*)&((float*)Cv)[(size_t)rrow * M + b * 64 + cg * 4] = o;
        }
      }
    }
  }
}

// ---------- CSR gather (bf16 table): h[v] = act(dinv*sum + dinv^2*hw[v] + bias) ----
// 16 lanes/node, each lane owns 8 bf16 cols (one uint4 load per neighbor).
template<bool RELU, bool OUTBF>
__global__ void k_gather(const int* __restrict__ start, const int2* __restrict__ pk,
                         const unsigned short* __restrict__ hw, const float* __restrict__ dinv,
                         const float* __restrict__ bias, void* __restrict__ hout, int N) {
  const int t = threadIdx.x;
  const int v = blockIdx.x * 16 + (t >> 4);
  if (v >= N) return;
  const int j8 = (t & 15) * 8;
  const int b = v ? start[v - 1] : 0;
  const int en = start[v];
  float accA[8] = {}, accB[8] = {};
  int i = b;
  for (; i + 1 < en; i += 2) {
    int2 q0 = pk[i], q1 = pk[i + 1];
    float n0 = __int_as_float(q0.y), n1 = __int_as_float(q1.y);
    uint4 w0 = *(const uint4*)&hw[(size_t)q0.x * 128 + j8];
    uint4 w1 = *(const uint4*)&hw[(size_t)q1.x * 128 + j8];
    accA[0] = fmaf(n0, bflo(w0.x), accA[0]); accA[1] = fmaf(n0, bfhi(w0.x), accA[1]);
    accA[2] = fmaf(n0, bflo(w0.y), accA[2]); accA[3] = fmaf(n0, bfhi(w0.y), accA[3]);
    accA[4] = fmaf(n0, bflo(w0.z), accA[4]); accA[5] = fmaf(n0, bfhi(w0.z), accA[5]);
    accA[6] = fmaf(n0, bflo(w0.w), accA[6]); accA[7] = fmaf(n0, bfhi(w0.w), accA[7]);
    accB[0] = fmaf(n1, bflo(w1.x), accB[0]); accB[1] = fmaf(n1, bfhi(w1.x), accB[1]);
    accB[2] = fmaf(n1, bflo(w1.y), accB[2]); accB[3] = fmaf(n1, bfhi(w1.y), accB[3]);
    accB[4] = fmaf(n1, bflo(w1.z), accB[4]); accB[5] = fmaf(n1, bfhi(w1.z), accB[5]);
    accB[6] = fmaf(n1, bflo(w1.w), accB[6]); accB[7] = fmaf(n1, bfhi(w1.w), accB[7]);
  }
  if (i < en) {
    int2 q = pk[i];
    float n = __int_as_float(q.y);
    uint4 w0 = *(const uint4*)&hw[(size_t)q.x * 128 + j8];
    accA[0] = fmaf(n, bflo(w0.x), accA[0]); accA[1] = fmaf(n, bfhi(w0.x), accA[1]);
    accA[2] = fmaf(n, bflo(w0.y), accA[2]); accA[3] = fmaf(n, bfhi(w0.y), accA[3]);
    accA[4] = fmaf(n, bflo(w0.z), accA[4]); accA[5] = fmaf(n, bfhi(w0.z), accA[5]);
    accA[6] = fmaf(n, bflo(w0.w), accA[6]); accA[7] = fmaf(n, bfhi(w0.w), accA[7]);
  }
  const float d = dinv[v];
  const float s = d * d;
  uint4 wv = *(const uint4*)&hw[(size_t)v * 128 + j8];
  float hv[8] = { bflo(wv.x), bfhi(wv.x), bflo(wv.y), bfhi(wv.y),
                  bflo(wv.z), bfhi(wv.z), bflo(wv.w), bfhi(wv.w) };
  float4 bv0 = *(const float4*)&bias[j8];
  float4 bv1 = *(const float4*)&bias[j8 + 4];
  float bvv[8] = { bv0.x, bv0.y, bv0.z, bv0.w, bv1.x, bv1.y, bv1.z, bv1.w };
  float o[8];
#pragma unroll
  for (int k = 0; k < 8; k++) {
    float a = accA[k] + accB[k];
    o[k] = fmaf(d, a, fmaf(s, hv[k], bvv[k]));
    if (RELU) o[k] = fmaxf(o[k], 0.f);
  }
  if (OUTBF) {
    uint4 pv;
    pv.x = packbf2(o[0], o[1]); pv.y = packbf2(o[2], o[3]);
    pv.z = packbf2(o[4], o[5]); pv.w = packbf2(o[6], o[7]);
    *(uint4*)&((unsigned short*)hout)[(size_t)v * 128 + j8] = pv;
  } else {
    float* hf = (float*)hout;
    *(float4*)&hf[(size_t)v * 128 + j8]     = make_float4(o[0], o[1], o[2], o[3]);
    *(float4*)&hf[(size_t)v * 128 + j8 + 4] = make_float4(o[4], o[5], o[6], o[7]);
  }
}

// ---------- per-edge kernel: logit = relu(U0[p0]+U1[p1]) @ Wb(relu) @ Wc ----------
// 64 edges per block, 256 threads. U is bf16 [N,128].
__global__ __launch_bounds__(256) void k_edge(const unsigned short* __restrict__ U,
    const int* __restrict__ p0, const int* __restrict__ p1,
    const float* __restrict__ Wb, const float* __restrict__ bb,
    const float* __restrict__ Wc, const float* __restrict__ bc,
    float* __restrict__ logits, int ES) {
  __shared__ alignas(16) float sWb[64 * 36];   // [k][c] stride 36
  __shared__ alignas(16) float sS1[64 * 68];   // [p][k] stride 68
  __shared__ alignas(16) float sS2[64 * 36];   // [p][j] stride 36
  __shared__ float sWc[32], sbb[32], sbc;
  const int t = threadIdx.x;
#pragma unroll
  for (int i = t * 4; i < 64 * 32; i += 1024) {
    int r = i >> 5, c = i & 31;
    *(float4*)&sWb[r * 36 + c] = *(const float4*)&Wb[i];
  }
  if (t < 32) { sWc[t] = Wc[t]; sbb[t] = bb[t]; }
  if (t == 0) sbc = bc[0];
  const int base = blockIdx.x << 6;
  {  // gather + add + relu -> s1 (bf16 reads)
    int p = t >> 2, q = t & 3;
    int e = base + p; if (e >= ES) e = ES - 1;
    const unsigned short* r0 = U + (size_t)p0[e] * 128;        // U0: cols 0..63
    const unsigned short* r1 = U + (size_t)p1[e] * 128 + 64;   // U1: cols 64..127
#pragma unroll
    for (int i = 0; i < 4; i++) {
      int c = i * 16 + q * 4;
      uint2 av = *(const uint2*)&r0[c];
      uint2 bv = *(const uint2*)&r1[c];
      float4 o;
      o.x = fmaxf(bflo(av.x) + bflo(bv.x), 0.f);
      o.y = fmaxf(bfhi(av.x) + bfhi(bv.x), 0.f);
      o.z = fmaxf(bflo(av.y) + bflo(bv.y), 0.f);
      o.w = fmaxf(bfhi(av.y) + bfhi(bv.y), 0.f);
      *(float4*)&sS1[p * 68 + c] = o;
    }
  }
  __syncthreads();
  // layer b: rows rg*4+ri, cols cg*2..+1
  const int rg = t >> 4, cg = t & 15;
  float accb[4][2] = {};
#pragma unroll
  for (int k0 = 0; k0 < 64; k0 += 4) {
    float4 av[4];
#pragma unroll
    for (int ri = 0; ri < 4; ri++) av[ri] = *(const float4*)&sS1[(rg * 4 + ri) * 68 + k0];
    float2 wv[4];
#pragma unroll
    for (int kk = 0; kk < 4; kk++) wv[kk] = *(const float2*)&sWb[(k0 + kk) * 36 + cg * 2];
#pragma unroll
    for (int kk = 0; kk < 4; kk++)
#pragma unroll
      for (int ri = 0; ri < 4; ri++) {
        float a = ((const float*)&av[ri])[kk];
        accb[ri][0] = fmaf(a, wv[kk].x, accb[ri][0]);
        accb[ri][1] = fmaf(a, wv[kk].y, accb[ri][1]);
      }
  }
#pragma unroll
  for (int ri = 0; ri < 4; ri++) {
    float2 o;
    o.x = fmaxf(accb[ri][0] + sbb[cg * 2 + 0], 0.f);
    o.y = fmaxf(accb[ri][1] + sbb[cg * 2 + 1], 0.f);
    *(float2*)&sS2[(rg * 4 + ri) * 36 + cg * 2] = o;
  }
  __syncthreads();
  {  // layer c
    int p = t >> 2, q = t & 3;
    float s = 0.f;
#pragma unroll
    for (int jj = 0; jj < 8; jj++) {
      int j = q + jj * 4;
      s = fmaf(sS2[p * 36 + j], sWc[j], s);
    }
    s += __shfl_down(s, 2);
    s += __shfl_down(s, 1);
    if (q == 0 && base + p < ES) logits[base + p] = s + sbc;
  }
}

// ---------- fused per-graph softmax: one block per graph (eg sorted) ----------
DEVINL int lbound(const int* __restrict__ a, int n, int key) {
  int lo = 0, hi = n;
  while (lo < hi) { int mid = (lo + hi) >> 1; if (a[mid] < key) lo = mid + 1; else hi = mid; }
  return lo;
}
__global__ __launch_bounds__(512) void k_softmax(const float* __restrict__ logits,
                          const int* __restrict__ eg,
                          float* __restrict__ out, int ES) {
  const int g = blockIdx.x;
  const int t = threadIdx.x;
  const int lo = lbound(eg, ES, g);
  const int hi = lbound(eg, ES, g + 1);
  if (lo >= hi) return;
  __shared__ float red[512];
  __shared__ float s_m, s_z;
  float m = -3.4e38f;
  for (int i = lo + t; i < hi; i += 512) m = fmaxf(m, logits[i]);
  red[t] = m; __syncthreads();
#pragma unroll
  for (int off = 256; off >= 1; off >>= 1) {
    if (t < off) red[t] = fmaxf(red[t], red[t + off]);
    __syncthreads();
  }
  if (t == 0) s_m = red[0];
  __syncthreads();
  const float gm = s_m;
  float z = 0.f;
  for (int i = lo + t; i < hi; i += 512) {
    float e = expf(logits[i] - gm);
    out[i] = e;
    z += e;
  }
  red[t] = z; __syncthreads();
#pragma unroll
  for (int off = 256; off >= 1; off >>= 1) {
    if (t < off) red[t] += red[t + off];
    __syncthreads();
  }
  if (t == 0) s_z = red[0];
  __syncthreads();
  const float inv = 1.0f / s_z;
  for (int i = lo + t; i < hi; i += 512) out[i] *= inv;
}

// ---------------------------------------------------------------------------
extern "C" void kernel_launch(void* const* d_in, const int* in_sizes, int n_in,
                              void* d_out, int out_size, void* d_ws, size_t ws_size,
                              hipStream_t stream) {
  const float* x  = (const float*)d_in[0];
  const int* ei   = (const int*)d_in[1];
  const float* ew = (const float*)d_in[2];
  const int* pi   = (const int*)d_in[3];
  const int* eg   = (const int*)d_in[4];
  const float* Wp = (const float*)d_in[6];
  const float* bp = (const float*)d_in[7];
  const float* W1 = (const float*)d_in[8];
  const float* b1 = (const float*)d_in[9];
  const float* W2 = (const float*)d_in[10];
  const float* b2 = (const float*)d_in[11];
  const float* Wa = (const float*)d_in[12];
  const float* ba = (const float*)d_in[13];
  const float* Wb = (const float*)d_in[14];
  const float* bb = (const float*)d_in[15];
  const float* Wc = (const float*)d_in[16];
  const float* bc = (const float*)d_in[17];

  const int N  = in_sizes[0] / 64;
  const int E  = in_sizes[2];
  const int ES = in_sizes[4];
  const int G  = 128;

  float* ws = (float*)d_ws;
  size_t o = 0;
  const size_t Npad = ((size_t)N + 31) & ~(size_t)31;
  int* cnt = (int*)(ws + o);    o += Npad;   // dead after scan1 -> reused as dinv
  float* dinv = (float*)cnt;
  float* degF = (float*)(ws + o); o += Npad;
  int* start = (int*)(ws + o);  o += Npad;
  int* bsum = (int*)(ws + o);   o += 512;
  int* boff = (int*)(ws + o);   o += 512;
  int2* pk = (int2*)(ws + o);   o += (size_t)E * 2;
  float* A = ws + o;            o += (size_t)N * 128;   // h1 fp32 -> U bf16
  float* B = ws + o;            o += (size_t)N * 128;   // hw1 bf16 -> V bf16 -> logits fp32
  float* Wfuse = ws + o;        o += 8192;
  float* bfuse = ws + o;        o += 128;
  float* Mcat = ws + o;         o += 16384;
  float* bU = ws + o;           o += 128;

  unsigned short* hw1 = (unsigned short*)B;
  float* h1 = A;
  unsigned short* V = (unsigned short*)B;   // overwrites hw1 (dead after gather1)
  unsigned short* U = (unsigned short*)A;   // overwrites h1 (dead after gemm2)
  float* logits = B;                        // overwrites V (dead after gather2)

  const int* row = ei;
  const int* col = ei + E;
  const int* p0 = pi;
  const int* p1 = pi + ES;
  float* out = (float*)d_out;

  const int gN = (N + 255) / 256;
  const int gE = (E + 255) / 256;
  const int nb = gN;

  // ---- weight folding + CSR build ----
  hipMemsetAsync(cnt, 0, 2 * Npad * sizeof(int), stream);   // cnt + degF (adjacent)
  k_prep<<<98, 256, 0, stream>>>(Wp, bp, W1, W2, Wa, ba, b2, Wfuse, bfuse, Mcat, bU);
  k_hist2<<<gE, 256, 0, stream>>>(col, ew, cnt, degF, E);
  k_scan1<<<nb, 256, 0, stream>>>(cnt, start, bsum, N);
  k_scan2<<<1, 512, 0, stream>>>(bsum, boff, nb);
  k_scan3dinv<<<nb, 256, 0, stream>>>(start, boff, degF, dinv, N);
  k_fill<<<gE, 256, 0, stream>>>(row, col, ew, dinv, start, pk, E);

  // ---- node pipeline: 2 GEMMs + 2 gathers ----
  const int gRows = (N + 127) / 128;
  const int gGat = (N + 15) / 16;
  k_gemm<64, 128, true, true><<<gRows, 256, 0, stream>>>(x, Wfuse, bfuse, (void*)hw1, N);
  k_gather<true, false><<<gGat, 256, 0, stream>>>(start, pk, hw1, dinv, b1, (void*)h1, N);
  k_gemm<128, 128, false, true><<<gRows, 256, 0, stream>>>(h1, Mcat, nullptr, (void*)V, N);
  k_gather<false, true><<<gGat, 256, 0, stream>>>(start, pk, V, dinv, bU, (void*)U, N);

  // ---- per-edge MLP ----
  k_edge<<<(ES + 63) / 64, 256, 0, stream>>>(U, p0, p1, Wb, bb, Wc, bc, logits, ES);

  // ---- per-graph softmax ----
  k_softmax<<<G, 512, 0, stream>>>(logits, eg, out, ES);
}

// Round 8
// 531.702 us; speedup vs baseline: 5.6390x; 1.0790x over previous
//
#include <hip/hip_runtime.h>
#include <hip/hip_bf16.h>
#include <cstdint>

#define DEVINL __device__ __forceinline__

// ---------------------------------------------------------------------------
// 2-layer GCN (gcn_norm w/ self-loops) -> per-pair MLP -> per-graph softmax.
// R8: k_edge layer-b moved to MFMA (bf16). R7 evidence: k_edge VALUBusy 70%,
// FETCH already halved -> compute-bound on scalar-FMA layer b. Now: gather
// packs s1 to bf16 LDS; 4x mfma_f32_16x16x32_bf16 per wave (16 edges);
// Wb pre-packed into B-fragment layout by k_prep; layer c via shuffle-xor
// from C-layout (col=lane&15,row=quad*4+reg). Rest identical to R7.
// ---------------------------------------------------------------------------

typedef __attribute__((ext_vector_type(8))) short bf16x8;
typedef __attribute__((ext_vector_type(4))) float f32x4;

DEVINL float bflo(unsigned u) { return __uint_as_float(u << 16); }
DEVINL float bfhi(unsigned u) { return __uint_as_float(u & 0xffff0000u); }
DEVINL unsigned packbf2(float a, float b) {   // RNE pack of 2 fp32 -> 2 bf16
  unsigned ua = __float_as_uint(a); ua = (ua + 0x7fff + ((ua >> 16) & 1)) >> 16;
  unsigned ub = __float_as_uint(b); ub = (ub + 0x7fff + ((ub >> 16) & 1)) >> 16;
  return ua | (ub << 16);
}
DEVINL unsigned short packbf1(float a) {
  unsigned ua = __float_as_uint(a);
  return (unsigned short)((ua + 0x7fff + ((ua >> 16) & 1)) >> 16);
}

// ---------- CSR build ----------
__global__ void k_hist2(const int* __restrict__ col, const float* __restrict__ w,
                        int* __restrict__ cnt, float* __restrict__ degF, int E) {
  int e = blockIdx.x * 256 + threadIdx.x;
  if (e < E) {
    int c = col[e];
    atomicAdd(&cnt[c], 1);
    atomicAdd(&degF[c], w[e]);
  }
}

__global__ void k_scan1(const int* __restrict__ cnt, int* __restrict__ start,
                        int* __restrict__ bsum, int N) {
  __shared__ int s[256];
  int t = threadIdx.x;
  int i = blockIdx.x * 256 + t;
  int v = (i < N) ? cnt[i] : 0;
  s[t] = v; __syncthreads();
  int x = v;
#pragma unroll
  for (int off = 1; off < 256; off <<= 1) {
    int y = (t >= off) ? s[t - off] : 0;
    __syncthreads();
    x += y; s[t] = x;
    __syncthreads();
  }
  if (i < N) start[i] = x - v;
  if (t == 255) bsum[blockIdx.x] = x;
}
__global__ void k_scan2(const int* __restrict__ bsum, int* __restrict__ boff, int nb) {
  __shared__ int s[512];
  int t = threadIdx.x;
  int v = (t < nb) ? bsum[t] : 0;
  s[t] = v; __syncthreads();
  int x = v;
#pragma unroll
  for (int off = 1; off < 512; off <<= 1) {
    int y = (t >= off) ? s[t - off] : 0;
    __syncthreads();
    x += y; s[t] = x;
    __syncthreads();
  }
  if (t < nb) boff[t] = x - v;
}
__global__ void k_scan3dinv(int* __restrict__ start, const int* __restrict__ boff,
                            const float* __restrict__ degF, float* __restrict__ dinv, int N) {
  int i = blockIdx.x * 256 + threadIdx.x;
  if (i < N) {
    start[i] += boff[blockIdx.x];
    dinv[i] = rsqrtf(1.0f + degF[i]);
  }
}

__global__ void k_fill(const int* __restrict__ row, const int* __restrict__ col,
                       const float* __restrict__ w, const float* __restrict__ dinv,
                       int* __restrict__ start, int2* __restrict__ pk, int E) {
  int e = blockIdx.x * 256 + threadIdx.x;
  if (e >= E) return;
  int c = col[e];
  int pos = atomicAdd(&start[c], 1);
  pk[pos] = make_int2(row[e], __float_as_int(w[e] * dinv[row[e]]));
}

// ---------- weight folding (tiny, once per call) ----------
// Adds WbF: Wb[64,32] pre-packed bf16 in MFMA B-fragment order:
// WbF[((lane*4)+(kt*2)+nt)*8 + j] = Wb[kt*32 + (lane>>4)*8 + j][nt*16 + (lane&15)]
__global__ void k_prep(const float* __restrict__ Wp, const float* __restrict__ bp,
                       const float* __restrict__ W1,
                       const float* __restrict__ W2, const float* __restrict__ Wa,
                       const float* __restrict__ ba, const float* __restrict__ b2,
                       const float* __restrict__ Wb,
                       float* __restrict__ Wfuse, float* __restrict__ bfuse,
                       float* __restrict__ Mcat, float* __restrict__ bU,
                       unsigned short* __restrict__ WbF) {
  int id = blockIdx.x * 256 + threadIdx.x;
  if (id < 8192) {                      // Wfuse[i,j] = (Wp@W1)[i,j]
    int i = id >> 7, j = id & 127;
    float s = 0.f;
    for (int k = 0; k < 128; k++) s = fmaf(Wp[i * 128 + k], W1[k * 128 + j], s);
    Wfuse[id] = s;
  } else if (id < 8320) {               // bfuse = bp@W1
    int j = id - 8192;
    float s = 0.f;
    for (int k = 0; k < 128; k++) s = fmaf(bp[k], W1[k * 128 + j], s);
    bfuse[j] = s;
  } else if (id < 8320 + 16384) {       // Mcat = [W2@Wa0 | W2@Wa1]
    int m = id - 8320;
    int i = m >> 7, j = m & 127;
    int jj = j & 63, koff = (j < 64) ? 0 : 64;
    float s = 0.f;
    for (int k = 0; k < 64; k++) s = fmaf(W2[i * 64 + k], Wa[(koff + k) * 64 + jj], s);
    Mcat[i * 128 + j] = s;
  } else if (id < 8320 + 16384 + 128) { // bU = [b2@Wa0+ba | b2@Wa1]
    int j = id - 8320 - 16384;
    int jj = j & 63, koff = (j < 64) ? 0 : 64;
    float s = (j < 64) ? ba[j] : 0.f;
    for (int k = 0; k < 64; k++) s = fmaf(b2[k], Wa[(koff + k) * 64 + jj], s);
    bU[j] = s;
  } else if (id < 24832 + 2048) {       // WbF bf16 fragment pack
    int m = id - 24832;
    int j = m & 7;
    int idx = m >> 3;
    int nt = idx & 1, kt = (idx >> 1) & 1, l = idx >> 2;
    int kr = kt * 32 + ((l >> 4) << 3) + j;
    int nc = nt * 16 + (l & 15);
    WbF[m] = packbf1(Wb[kr * 32 + nc]);
  }
}

// ---------- tiled fp32 GEMM: C[N,M] = A[N,K] @ W[K,M] (+bias), C fp32|bf16 ----------
template<int K, int M, bool BIAS, bool CBF>
__global__ __launch_bounds__(256, 4) void k_gemm(const float* __restrict__ A,
                                                 const float* __restrict__ W,
                                                 const float* __restrict__ bias,
                                                 void* __restrict__ Cv, int N) {
  constexpr int KC = 32;
  constexpr int NB = M / 64;
  __shared__ alignas(16) float sA[128 * 36];       // [r][k], stride 36
  __shared__ alignas(16) float sW[KC * (M + 4)];   // [k][c], stride M+4
  const int t = threadIdx.x;
  const int rg = t >> 4, cg = t & 15;
  const int r0 = blockIdx.x * 128;
  float acc[NB][8][4] = {};
  for (int kc = 0; kc < K; kc += KC) {
    __syncthreads();
#pragma unroll
    for (int i = 0; i < 4; i++) {            // stage A: 128x32 floats
      int idx = (t + i * 256) * 4;
      int r = idx >> 5, k = idx & 31;
      int gr = r0 + r;
      float4 v = make_float4(0.f, 0.f, 0.f, 0.f);
      if (gr < N) v = *(const float4*)&A[(size_t)gr * K + kc + k];
      *(float4*)&sA[r * 36 + k] = v;
    }
#pragma unroll
    for (int i = 0; i < KC * M / 1024; i++) {  // stage W chunk: KCxM floats
      int idx = (t + i * 256) * 4;
      int r = idx / M, c = idx % M;
      *(float4*)&sW[r * (M + 4) + c] = *(const float4*)&W[(size_t)(kc + r) * M + c];
    }
    __syncthreads();
    for (int k0 = 0; k0 < KC; k0 += 4) {
      float4 av[8];
#pragma unroll
      for (int ri = 0; ri < 8; ri++) av[ri] = *(const float4*)&sA[(rg + 16 * ri) * 36 + k0];
#pragma unroll
      for (int kk = 0; kk < 4; kk++) {
        float4 wv[NB];
#pragma unroll
        for (int b = 0; b < NB; b++)
          wv[b] = *(const float4*)&sW[(k0 + kk) * (M + 4) + b * 64 + cg * 4];
#pragma unroll
        for (int ri = 0; ri < 8; ri++) {
          float a = ((const float*)&av[ri])[kk];
#pragma unroll
          for (int b = 0; b < NB; b++) {
            acc[b][ri][0] = fmaf(a, wv[b].x, acc[b][ri][0]);
            acc[b][ri][1] = fmaf(a, wv[b].y, acc[b][ri][1]);
            acc[b][ri][2] = fmaf(a, wv[b].z, acc[b][ri][2]);
            acc[b][ri][3] = fmaf(a, wv[b].w, acc[b][ri][3]);
          }
        }
      }
    }
  }
#pragma unroll
  for (int ri = 0; ri < 8; ri++) {
    int rrow = r0 + rg + 16 * ri;
    if (rrow < N) {
#pragma unroll
      for (int b = 0; b < NB; b++) {
        float4 o;
        o.x = acc[b][ri][0]; o.y = acc[b][ri][1]; o.z = acc[b][ri][2]; o.w = acc[b][ri][3];
        if (BIAS) {
          float4 bv = *(const float4*)&bias[b * 64 + cg * 4];
          o.x += bv.x; o.y += bv.y; o.z += bv.z; o.w += bv.w;
        }
        if (CBF) {
          uint2 pv;
          pv.x = packbf2(o.x, o.y);
          pv.y = packbf2(o.z, o.w);
          *(uint2*)&((unsigned short*)Cv)[(size_t)rrow * M + b * 64 + cg * 4] = pv;
        } else {
          *(float4*)&((float*)Cv)[(size_t)rrow * M + b * 64 + cg * 4] = o;
        }
      }
    }
  }
}

// ---------- CSR gather (bf16 table): h[v] = act(dinv*sum + dinv^2*hw[v] + bias) ----
template<bool RELU, bool OUTBF>
__global__ void k_gather(const int* __restrict__ start, const int2* __restrict__ pk,
                         const unsigned short* __restrict__ hw, const float* __restrict__ dinv,
                         const float* __restrict__ bias, void* __restrict__ hout, int N) {
  const int t = threadIdx.x;
  const int v = blockIdx.x * 16 + (t >> 4);
  if (v >= N) return;
  const int j8 = (t & 15) * 8;
  const int b = v ? start[v - 1] : 0;
  const int en = start[v];
  float accA[8] = {}, accB[8] = {};
  int i = b;
  for (; i + 1 < en; i += 2) {
    int2 q0 = pk[i], q1 = pk[i + 1];
    float n0 = __int_as_float(q0.y), n1 = __int_as_float(q1.y);
    uint4 w0 = *(const uint4*)&hw[(size_t)q0.x * 128 + j8];
    uint4 w1 = *(const uint4*)&hw[(size_t)q1.x * 128 + j8];
    accA[0] = fmaf(n0, bflo(w0.x), accA[0]); accA[1] = fmaf(n0, bfhi(w0.x), accA[1]);
    accA[2] = fmaf(n0, bflo(w0.y), accA[2]); accA[3] = fmaf(n0, bfhi(w0.y), accA[3]);
    accA[4] = fmaf(n0, bflo(w0.z), accA[4]); accA[5] = fmaf(n0, bfhi(w0.z), accA[5]);
    accA[6] = fmaf(n0, bflo(w0.w), accA[6]); accA[7] = fmaf(n0, bfhi(w0.w), accA[7]);
    accB[0] = fmaf(n1, bflo(w1.x), accB[0]); accB[1] = fmaf(n1, bfhi(w1.x), accB[1]);
    accB[2] = fmaf(n1, bflo(w1.y), accB[2]); accB[3] = fmaf(n1, bfhi(w1.y), accB[3]);
    accB[4] = fmaf(n1, bflo(w1.z), accB[4]); accB[5] = fmaf(n1, bfhi(w1.z), accB[5]);
    accB[6] = fmaf(n1, bflo(w1.w), accB[6]); accB[7] = fmaf(n1, bfhi(w1.w), accB[7]);
  }
  if (i < en) {
    int2 q = pk[i];
    float n = __int_as_float(q.y);
    uint4 w0 = *(const uint4*)&hw[(size_t)q.x * 128 + j8];
    accA[0] = fmaf(n, bflo(w0.x), accA[0]); accA[1] = fmaf(n, bfhi(w0.x), accA[1]);
    accA[2] = fmaf(n, bflo(w0.y), accA[2]); accA[3] = fmaf(n, bfhi(w0.y), accA[3]);
    accA[4] = fmaf(n, bflo(w0.z), accA[4]); accA[5] = fmaf(n, bfhi(w0.z), accA[5]);
    accA[6] = fmaf(n, bflo(w0.w), accA[6]); accA[7] = fmaf(n, bfhi(w0.w), accA[7]);
  }
  const float d = dinv[v];
  const float s = d * d;
  uint4 wv = *(const uint4*)&hw[(size_t)v * 128 + j8];
  float hv[8] = { bflo(wv.x), bfhi(wv.x), bflo(wv.y), bfhi(wv.y),
                  bflo(wv.z), bfhi(wv.z), bflo(wv.w), bfhi(wv.w) };
  float4 bv0 = *(const float4*)&bias[j8];
  float4 bv1 = *(const float4*)&bias[j8 + 4];
  float bvv[8] = { bv0.x, bv0.y, bv0.z, bv0.w, bv1.x, bv1.y, bv1.z, bv1.w };
  float o[8];
#pragma unroll
  for (int k = 0; k < 8; k++) {
    float a = accA[k] + accB[k];
    o[k] = fmaf(d, a, fmaf(s, hv[k], bvv[k]));
    if (RELU) o[k] = fmaxf(o[k], 0.f);
  }
  if (OUTBF) {
    uint4 pv;
    pv.x = packbf2(o[0], o[1]); pv.y = packbf2(o[2], o[3]);
    pv.z = packbf2(o[4], o[5]); pv.w = packbf2(o[6], o[7]);
    *(uint4*)&((unsigned short*)hout)[(size_t)v * 128 + j8] = pv;
  } else {
    float* hf = (float*)hout;
    *(float4*)&hf[(size_t)v * 128 + j8]     = make_float4(o[0], o[1], o[2], o[3]);
    *(float4*)&hf[(size_t)v * 128 + j8 + 4] = make_float4(o[4], o[5], o[6], o[7]);
  }
}

// ---------- per-edge kernel (MFMA layer b) ----------
// 64 edges/block, 256 threads (4 waves x 16 edges). s1 packed bf16 in LDS
// (stride 72 shorts = uniform 8-way banking for b128). Layer b:
// 4x mfma_f32_16x16x32_bf16 per wave; layer c from C-layout + shuffle-xor.
__global__ __launch_bounds__(256) void k_edge(const unsigned short* __restrict__ U,
    const int* __restrict__ p0, const int* __restrict__ p1,
    const unsigned short* __restrict__ WbF, const float* __restrict__ bb,
    const float* __restrict__ Wc, const float* __restrict__ bc,
    float* __restrict__ logits, int ES) {
  __shared__ alignas(16) unsigned short sS1[64 * 72];   // bf16 [edge][k], stride 72
  const int t = threadIdx.x;
  const int base = blockIdx.x << 6;
  {  // gather + add + relu + bf16-pack -> sS1
    int p = t >> 2, q = t & 3;
    int e = base + p; if (e >= ES) e = ES - 1;
    const unsigned short* r0 = U + (size_t)p0[e] * 128;        // U0: cols 0..63
    const unsigned short* r1 = U + (size_t)p1[e] * 128 + 64;   // U1: cols 64..127
#pragma unroll
    for (int i = 0; i < 4; i++) {
      int c = i * 16 + q * 4;
      uint2 av = *(const uint2*)&r0[c];
      uint2 bv = *(const uint2*)&r1[c];
      float ox = fmaxf(bflo(av.x) + bflo(bv.x), 0.f);
      float oy = fmaxf(bfhi(av.x) + bfhi(bv.x), 0.f);
      float oz = fmaxf(bflo(av.y) + bflo(bv.y), 0.f);
      float ow = fmaxf(bfhi(av.y) + bfhi(bv.y), 0.f);
      uint2 pv;
      pv.x = packbf2(ox, oy);
      pv.y = packbf2(oz, ow);
      *(uint2*)&sS1[p * 72 + c] = pv;
    }
  }
  __syncthreads();
  const int lane = t & 63;
  const int wave = t >> 6;
  const int quad = lane >> 4, n0 = lane & 15;
  const int edge0 = wave * 16;
  // A-fragments: A[m=lane&15][k=quad*8+j]  (two K-tiles: k0..31, k32..63)
  bf16x8 a0 = *(const bf16x8*)&sS1[(edge0 + n0) * 72 + quad * 8];
  bf16x8 a1 = *(const bf16x8*)&sS1[(edge0 + n0) * 72 + 32 + quad * 8];
  // B-fragments from pre-packed WbF (block-invariant -> L2 broadcast)
  const bf16x8* wf = (const bf16x8*)WbF;
  bf16x8 b00 = wf[lane * 4 + 0];   // kt0 nt0
  bf16x8 b01 = wf[lane * 4 + 1];   // kt0 nt1
  bf16x8 b10 = wf[lane * 4 + 2];   // kt1 nt0
  bf16x8 b11 = wf[lane * 4 + 3];   // kt1 nt1
  f32x4 acc0 = {0.f, 0.f, 0.f, 0.f};
  f32x4 acc1 = {0.f, 0.f, 0.f, 0.f};
  acc0 = __builtin_amdgcn_mfma_f32_16x16x32_bf16(a0, b00, acc0, 0, 0, 0);
  acc0 = __builtin_amdgcn_mfma_f32_16x16x32_bf16(a1, b10, acc0, 0, 0, 0);
  acc1 = __builtin_amdgcn_mfma_f32_16x16x32_bf16(a0, b01, acc1, 0, 0, 0);
  acc1 = __builtin_amdgcn_mfma_f32_16x16x32_bf16(a1, b11, acc1, 0, 0, 0);
  // layer c: D[row=m=quad*4+reg][col=n=lane&15]; reduce over n (16 lanes)
  const float bb0 = bb[n0], bb1 = bb[n0 + 16];
  const float wc0 = Wc[n0], wc1 = Wc[n0 + 16];
  const float bcv = bc[0];
#pragma unroll
  for (int reg = 0; reg < 4; reg++) {
    float s = fmaf(fmaxf(acc0[reg] + bb0, 0.f), wc0,
                   fmaxf(acc1[reg] + bb1, 0.f) * wc1);
    s += __shfl_xor(s, 1);
    s += __shfl_xor(s, 2);
    s += __shfl_xor(s, 4);
    s += __shfl_xor(s, 8);
    if (n0 == 0) {
      int e = base + edge0 + quad * 4 + reg;
      if (e < ES) logits[e] = s + bcv;
    }
  }
}

// ---------- fused per-graph softmax: one block per graph (eg sorted) ----------
DEVINL int lbound(const int* __restrict__ a, int n, int key) {
  int lo = 0, hi = n;
  while (lo < hi) { int mid = (lo + hi) >> 1; if (a[mid] < key) lo = mid + 1; else hi = mid; }
  return lo;
}
__global__ __launch_bounds__(512) void k_softmax(const float* __restrict__ logits,
                          const int* __restrict__ eg,
                          float* __restrict__ out, int ES) {
  const int g = blockIdx.x;
  const int t = threadIdx.x;
  const int lo = lbound(eg, ES, g);
  const int hi = lbound(eg, ES, g + 1);
  if (lo >= hi) return;
  __shared__ float red[512];
  __shared__ float s_m, s_z;
  float m = -3.4e38f;
  for (int i = lo + t; i < hi; i += 512) m = fmaxf(m, logits[i]);
  red[t] = m; __syncthreads();
#pragma unroll
  for (int off = 256; off >= 1; off >>= 1) {
    if (t < off) red[t] = fmaxf(red[t], red[t + off]);
    __syncthreads();
  }
  if (t == 0) s_m = red[0];
  __syncthreads();
  const float gm = s_m;
  float z = 0.f;
  for (int i = lo + t; i < hi; i += 512) {
    float e = expf(logits[i] - gm);
    out[i] = e;
    z += e;
  }
  red[t] = z; __syncthreads();
#pragma unroll
  for (int off = 256; off >= 1; off >>= 1) {
    if (t < off) red[t] += red[t + off];
    __syncthreads();
  }
  if (t == 0) s_z = red[0];
  __syncthreads();
  const float inv = 1.0f / s_z;
  for (int i = lo + t; i < hi; i += 512) out[i] *= inv;
}

// ---------------------------------------------------------------------------
extern "C" void kernel_launch(void* const* d_in, const int* in_sizes, int n_in,
                              void* d_out, int out_size, void* d_ws, size_t ws_size,
                              hipStream_t stream) {
  const float* x  = (const float*)d_in[0];
  const int* ei   = (const int*)d_in[1];
  const float* ew = (const float*)d_in[2];
  const int* pi   = (const int*)d_in[3];
  const int* eg   = (const int*)d_in[4];
  const float* Wp = (const float*)d_in[6];
  const float* bp = (const float*)d_in[7];
  const float* W1 = (const float*)d_in[8];
  const float* b1 = (const float*)d_in[9];
  const float* W2 = (const float*)d_in[10];
  const float* b2 = (const float*)d_in[11];
  const float* Wa = (const float*)d_in[12];
  const float* ba = (const float*)d_in[13];
  const float* Wb = (const float*)d_in[14];
  const float* bb = (const float*)d_in[15];
  const float* Wc = (const float*)d_in[16];
  const float* bc = (const float*)d_in[17];

  const int N  = in_sizes[0] / 64;
  const int E  = in_sizes[2];
  const int ES = in_sizes[4];
  const int G  = 128;

  float* ws = (float*)d_ws;
  size_t o = 0;
  const size_t Npad = ((size_t)N + 31) & ~(size_t)31;
  int* cnt = (int*)(ws + o);    o += Npad;   // dead after scan1 -> reused as dinv
  float* dinv = (float*)cnt;
  float* degF = (float*)(ws + o); o += Npad;
  int* start = (int*)(ws + o);  o += Npad;
  int* bsum = (int*)(ws + o);   o += 512;
  int* boff = (int*)(ws + o);   o += 512;
  int2* pk = (int2*)(ws + o);   o += (size_t)E * 2;
  float* A = ws + o;            o += (size_t)N * 128;   // h1 fp32 -> U bf16
  float* B = ws + o;            o += (size_t)N * 128;   // hw1 bf16 -> V bf16 -> logits fp32
  float* Wfuse = ws + o;        o += 8192;
  float* bfuse = ws + o;        o += 128;
  float* Mcat = ws + o;         o += 16384;
  float* bU = ws + o;           o += 128;
  unsigned short* WbF = (unsigned short*)(ws + o); o += 1024;  // 2048 bf16

  unsigned short* hw1 = (unsigned short*)B;
  float* h1 = A;
  unsigned short* V = (unsigned short*)B;   // overwrites hw1 (dead after gather1)
  unsigned short* U = (unsigned short*)A;   // overwrites h1 (dead after gemm2)
  float* logits = B;                        // overwrites V (dead after gather2)

  const int* row = ei;
  const int* col = ei + E;
  const int* p0 = pi;
  const int* p1 = pi + ES;
  float* out = (float*)d_out;

  const int gN = (N + 255) / 256;
  const int gE = (E + 255) / 256;
  const int nb = gN;

  // ---- weight folding + CSR build ----
  hipMemsetAsync(cnt, 0, 2 * Npad * sizeof(int), stream);   // cnt + degF (adjacent)
  k_prep<<<105, 256, 0, stream>>>(Wp, bp, W1, W2, Wa, ba, b2, Wb,
                                  Wfuse, bfuse, Mcat, bU, WbF);
  k_hist2<<<gE, 256, 0, stream>>>(col, ew, cnt, degF, E);
  k_scan1<<<nb, 256, 0, stream>>>(cnt, start, bsum, N);
  k_scan2<<<1, 512, 0, stream>>>(bsum, boff, nb);
  k_scan3dinv<<<nb, 256, 0, stream>>>(start, boff, degF, dinv, N);
  k_fill<<<gE, 256, 0, stream>>>(row, col, ew, dinv, start, pk, E);

  // ---- node pipeline: 2 GEMMs + 2 gathers ----
  const int gRows = (N + 127) / 128;
  const int gGat = (N + 15) / 16;
  k_gemm<64, 128, true, true><<<gRows, 256, 0, stream>>>(x, Wfuse, bfuse, (void*)hw1, N);
  k_gather<true, false><<<gGat, 256, 0, stream>>>(start, pk, hw1, dinv, b1, (void*)h1, N);
  k_gemm<128, 128, false, true><<<gRows, 256, 0, stream>>>(h1, Mcat, nullptr, (void*)V, N);
  k_gather<false, true><<<gGat, 256, 0, stream>>>(start, pk, V, dinv, bU, (void*)U, N);

  // ---- per-edge MLP (MFMA) ----
  k_edge<<<(ES + 63) / 64, 256, 0, stream>>>(U, p0, p1, WbF, bb, Wc, bc, logits, ES);

  // ---- per-graph softmax ----
  k_softmax<<<G, 512, 0, stream>>>(logits, eg, out, ES);
}

// Round 9
// 452.199 us; speedup vs baseline: 6.6304x; 1.1758x over previous
//
#include <hip/hip_runtime.h>
#include <hip/hip_bf16.h>
#include <cstdint>

#define DEVINL __device__ __forceinline__
typedef unsigned long long ull;

// ---------------------------------------------------------------------------
// 2-layer GCN (gcn_norm w/ self-loops) -> per-pair MLP -> per-graph softmax.
// R9: CSR-build atomics halved then removed. R8 evidence: k_hist2 90us,
// VALUBusy 0.3%, 22G atomics/s (op-rate bound). Now: one 64-bit packed
// atomicAdd per edge (count<<36 | fix28(w)); returned old value = bucket
// position -> k_fill is atomic-free. start[] is pristine exclusive (N+1).
// Rest identical to R8 (MFMA k_edge, bf16 tables, de-spilled gemm).
// ---------------------------------------------------------------------------

typedef __attribute__((ext_vector_type(8))) short bf16x8;
typedef __attribute__((ext_vector_type(4))) float f32x4;

DEVINL float bflo(unsigned u) { return __uint_as_float(u << 16); }
DEVINL float bfhi(unsigned u) { return __uint_as_float(u & 0xffff0000u); }
DEVINL unsigned packbf2(float a, float b) {   // RNE pack of 2 fp32 -> 2 bf16
  unsigned ua = __float_as_uint(a); ua = (ua + 0x7fff + ((ua >> 16) & 1)) >> 16;
  unsigned ub = __float_as_uint(b); ub = (ub + 0x7fff + ((ub >> 16) & 1)) >> 16;
  return ua | (ub << 16);
}
DEVINL unsigned short packbf1(float a) {
  unsigned ua = __float_as_uint(a);
  return (unsigned short)((ua + 0x7fff + ((ua >> 16) & 1)) >> 16);
}

// ---------- CSR build ----------
// one 64-bit atomic per edge: high 28 bits = count, low 36 bits = sum(w) in
// 8.28 fixed point (w in [0,1), degree << 2^8 -> no overflow).
__global__ void k_hist64(const int* __restrict__ col, const float* __restrict__ w,
                         ull* __restrict__ cnt64, int* __restrict__ pos, int E) {
  int e = blockIdx.x * 256 + threadIdx.x;
  if (e < E) {
    ull inc = (1ULL << 36) | (ull)(unsigned)(w[e] * 268435456.0f + 0.5f);
    ull old = atomicAdd(&cnt64[col[e]], inc);
    pos[e] = (int)(old >> 36);
  }
}

__global__ void k_scan1(const ull* __restrict__ cnt64, int* __restrict__ start,
                        int* __restrict__ bsum, int N) {
  __shared__ int s[256];
  int t = threadIdx.x;
  int i = blockIdx.x * 256 + t;
  int v = (i < N) ? (int)(cnt64[i] >> 36) : 0;
  s[t] = v; __syncthreads();
  int x = v;
#pragma unroll
  for (int off = 1; off < 256; off <<= 1) {
    int y = (t >= off) ? s[t - off] : 0;
    __syncthreads();
    x += y; s[t] = x;
    __syncthreads();
  }
  if (i < N) start[i] = x - v;   // block-local exclusive
  if (t == 255) bsum[blockIdx.x] = x;
}
// also writes start[N] = E (total)
__global__ void k_scan2(const int* __restrict__ bsum, int* __restrict__ boff,
                        int nb, int* __restrict__ startN) {
  __shared__ int s[512];
  int t = threadIdx.x;
  int v = (t < nb) ? bsum[t] : 0;
  s[t] = v; __syncthreads();
  int x = v;
#pragma unroll
  for (int off = 1; off < 512; off <<= 1) {
    int y = (t >= off) ? s[t - off] : 0;
    __syncthreads();
    x += y; s[t] = x;
    __syncthreads();
  }
  if (t < nb) boff[t] = x - v;
  if (t == nb - 1) *startN = x;  // = E
}
// scan finalize + dinv = rsqrt(1 + weighted_deg)   (fixed-point decode)
__global__ void k_scan3dinv(int* __restrict__ start, const int* __restrict__ boff,
                            const ull* __restrict__ cnt64, float* __restrict__ dinv, int N) {
  int i = blockIdx.x * 256 + threadIdx.x;
  if (i < N) {
    start[i] += boff[blockIdx.x];
    float sw = (float)(cnt64[i] & 0xFFFFFFFFFULL) * 3.7252903e-09f;  // *2^-28
    dinv[i] = rsqrtf(1.0f + sw);
  }
}

// atomic-free fill: slot = start[c] + pos[e]; start stays pristine exclusive.
__global__ void k_fill(const int* __restrict__ row, const int* __restrict__ col,
                       const float* __restrict__ w, const float* __restrict__ dinv,
                       const int* __restrict__ start, const int* __restrict__ pos,
                       int2* __restrict__ pk, int E) {
  int e = blockIdx.x * 256 + threadIdx.x;
  if (e >= E) return;
  int r = row[e];
  int p = start[col[e]] + pos[e];
  pk[p] = make_int2(r, __float_as_int(w[e] * dinv[r]));
}

// ---------- weight folding (tiny, once per call) ----------
__global__ void k_prep(const float* __restrict__ Wp, const float* __restrict__ bp,
                       const float* __restrict__ W1,
                       const float* __restrict__ W2, const float* __restrict__ Wa,
                       const float* __restrict__ ba, const float* __restrict__ b2,
                       const float* __restrict__ Wb,
                       float* __restrict__ Wfuse, float* __restrict__ bfuse,
                       float* __restrict__ Mcat, float* __restrict__ bU,
                       unsigned short* __restrict__ WbF) {
  int id = blockIdx.x * 256 + threadIdx.x;
  if (id < 8192) {                      // Wfuse[i,j] = (Wp@W1)[i,j]
    int i = id >> 7, j = id & 127;
    float s = 0.f;
    for (int k = 0; k < 128; k++) s = fmaf(Wp[i * 128 + k], W1[k * 128 + j], s);
    Wfuse[id] = s;
  } else if (id < 8320) {               // bfuse = bp@W1
    int j = id - 8192;
    float s = 0.f;
    for (int k = 0; k < 128; k++) s = fmaf(bp[k], W1[k * 128 + j], s);
    bfuse[j] = s;
  } else if (id < 8320 + 16384) {       // Mcat = [W2@Wa0 | W2@Wa1]
    int m = id - 8320;
    int i = m >> 7, j = m & 127;
    int jj = j & 63, koff = (j < 64) ? 0 : 64;
    float s = 0.f;
    for (int k = 0; k < 64; k++) s = fmaf(W2[i * 64 + k], Wa[(koff + k) * 64 + jj], s);
    Mcat[i * 128 + j] = s;
  } else if (id < 8320 + 16384 + 128) { // bU = [b2@Wa0+ba | b2@Wa1]
    int j = id - 8320 - 16384;
    int jj = j & 63, koff = (j < 64) ? 0 : 64;
    float s = (j < 64) ? ba[j] : 0.f;
    for (int k = 0; k < 64; k++) s = fmaf(b2[k], Wa[(koff + k) * 64 + jj], s);
    bU[j] = s;
  } else if (id < 24832 + 2048) {       // WbF bf16 B-fragment pack
    int m = id - 24832;
    int j = m & 7;
    int idx = m >> 3;
    int nt = idx & 1, kt = (idx >> 1) & 1, l = idx >> 2;
    int kr = kt * 32 + ((l >> 4) << 3) + j;
    int nc = nt * 16 + (l & 15);
    WbF[m] = packbf1(Wb[kr * 32 + nc]);
  }
}

// ---------- tiled fp32 GEMM: C[N,M] = A[N,K] @ W[K,M] (+bias), C fp32|bf16 ----------
template<int K, int M, bool BIAS, bool CBF>
__global__ __launch_bounds__(256, 4) void k_gemm(const float* __restrict__ A,
                                                 const float* __restrict__ W,
                                                 const float* __restrict__ bias,
                                                 void* __restrict__ Cv, int N) {
  constexpr int KC = 32;
  constexpr int NB = M / 64;
  __shared__ alignas(16) float sA[128 * 36];       // [r][k], stride 36
  __shared__ alignas(16) float sW[KC * (M + 4)];   // [k][c], stride M+4
  const int t = threadIdx.x;
  const int rg = t >> 4, cg = t & 15;
  const int r0 = blockIdx.x * 128;
  float acc[NB][8][4] = {};
  for (int kc = 0; kc < K; kc += KC) {
    __syncthreads();
#pragma unroll
    for (int i = 0; i < 4; i++) {            // stage A: 128x32 floats
      int idx = (t + i * 256) * 4;
      int r = idx >> 5, k = idx & 31;
      int gr = r0 + r;
      float4 v = make_float4(0.f, 0.f, 0.f, 0.f);
      if (gr < N) v = *(const float4*)&A[(size_t)gr * K + kc + k];
      *(float4*)&sA[r * 36 + k] = v;
    }
#pragma unroll
    for (int i = 0; i < KC * M / 1024; i++) {  // stage W chunk: KCxM floats
      int idx = (t + i * 256) * 4;
      int r = idx / M, c = idx % M;
      *(float4*)&sW[r * (M + 4) + c] = *(const float4*)&W[(size_t)(kc + r) * M + c];
    }
    __syncthreads();
    for (int k0 = 0; k0 < KC; k0 += 4) {
      float4 av[8];
#pragma unroll
      for (int ri = 0; ri < 8; ri++) av[ri] = *(const float4*)&sA[(rg + 16 * ri) * 36 + k0];
#pragma unroll
      for (int kk = 0; kk < 4; kk++) {
        float4 wv[NB];
#pragma unroll
        for (int b = 0; b < NB; b++)
          wv[b] = *(const float4*)&sW[(k0 + kk) * (M + 4) + b * 64 + cg * 4];
#pragma unroll
        for (int ri = 0; ri < 8; ri++) {
          float a = ((const float*)&av[ri])[kk];
#pragma unroll
          for (int b = 0; b < NB; b++) {
            acc[b][ri][0] = fmaf(a, wv[b].x, acc[b][ri][0]);
            acc[b][ri][1] = fmaf(a, wv[b].y, acc[b][ri][1]);
            acc[b][ri][2] = fmaf(a, wv[b].z, acc[b][ri][2]);
            acc[b][ri][3] = fmaf(a, wv[b].w, acc[b][ri][3]);
          }
        }
      }
    }
  }
#pragma unroll
  for (int ri = 0; ri < 8; ri++) {
    int rrow = r0 + rg + 16 * ri;
    if (rrow < N) {
#pragma unroll
      for (int b = 0; b < NB; b++) {
        float4 o;
        o.x = acc[b][ri][0]; o.y = acc[b][ri][1]; o.z = acc[b][ri][2]; o.w = acc[b][ri][3];
        if (BIAS) {
          float4 bv = *(const float4*)&bias[b * 64 + cg * 4];
          o.x += bv.x; o.y += bv.y; o.z += bv.z; o.w += bv.w;
        }
        if (CBF) {
          uint2 pv;
          pv.x = packbf2(o.x, o.y);
          pv.y = packbf2(o.z, o.w);
          *(uint2*)&((unsigned short*)Cv)[(size_t)rrow * M + b * 64 + cg * 4] = pv;
        } else {
          *(float4*)&((float*)Cv)[(size_t)rrow * M + b * 64 + cg * 4] = o;
        }
      }
    }
  }
}

// ---------- CSR gather (bf16 table): h[v] = act(dinv*sum + dinv^2*hw[v] + bias) ----
// start is exclusive prefix with N+1 entries: b = start[v], en = start[v+1].
template<bool RELU, bool OUTBF>
__global__ void k_gather(const int* __restrict__ start, const int2* __restrict__ pk,
                         const unsigned short* __restrict__ hw, const float* __restrict__ dinv,
                         const float* __restrict__ bias, void* __restrict__ hout, int N) {
  const int t = threadIdx.x;
  const int v = blockIdx.x * 16 + (t >> 4);
  if (v >= N) return;
  const int j8 = (t & 15) * 8;
  const int b = start[v];
  const int en = start[v + 1];
  float accA[8] = {}, accB[8] = {};
  int i = b;
  for (; i + 1 < en; i += 2) {
    int2 q0 = pk[i], q1 = pk[i + 1];
    float n0 = __int_as_float(q0.y), n1 = __int_as_float(q1.y);
    uint4 w0 = *(const uint4*)&hw[(size_t)q0.x * 128 + j8];
    uint4 w1 = *(const uint4*)&hw[(size_t)q1.x * 128 + j8];
    accA[0] = fmaf(n0, bflo(w0.x), accA[0]); accA[1] = fmaf(n0, bfhi(w0.x), accA[1]);
    accA[2] = fmaf(n0, bflo(w0.y), accA[2]); accA[3] = fmaf(n0, bfhi(w0.y), accA[3]);
    accA[4] = fmaf(n0, bflo(w0.z), accA[4]); accA[5] = fmaf(n0, bfhi(w0.z), accA[5]);
    accA[6] = fmaf(n0, bflo(w0.w), accA[6]); accA[7] = fmaf(n0, bfhi(w0.w), accA[7]);
    accB[0] = fmaf(n1, bflo(w1.x), accB[0]); accB[1] = fmaf(n1, bfhi(w1.x), accB[1]);
    accB[2] = fmaf(n1, bflo(w1.y), accB[2]); accB[3] = fmaf(n1, bfhi(w1.y), accB[3]);
    accB[4] = fmaf(n1, bflo(w1.z), accB[4]); accB[5] = fmaf(n1, bfhi(w1.z), accB[5]);
    accB[6] = fmaf(n1, bflo(w1.w), accB[6]); accB[7] = fmaf(n1, bfhi(w1.w), accB[7]);
  }
  if (i < en) {
    int2 q = pk[i];
    float n = __int_as_float(q.y);
    uint4 w0 = *(const uint4*)&hw[(size_t)q.x * 128 + j8];
    accA[0] = fmaf(n, bflo(w0.x), accA[0]); accA[1] = fmaf(n, bfhi(w0.x), accA[1]);
    accA[2] = fmaf(n, bflo(w0.y), accA[2]); accA[3] = fmaf(n, bfhi(w0.y), accA[3]);
    accA[4] = fmaf(n, bflo(w0.z), accA[4]); accA[5] = fmaf(n, bfhi(w0.z), accA[5]);
    accA[6] = fmaf(n, bflo(w0.w), accA[6]); accA[7] = fmaf(n, bfhi(w0.w), accA[7]);
  }
  const float d = dinv[v];
  const float s = d * d;
  uint4 wv = *(const uint4*)&hw[(size_t)v * 128 + j8];
  float hv[8] = { bflo(wv.x), bfhi(wv.x), bflo(wv.y), bfhi(wv.y),
                  bflo(wv.z), bfhi(wv.z), bflo(wv.w), bfhi(wv.w) };
  float4 bv0 = *(const float4*)&bias[j8];
  float4 bv1 = *(const float4*)&bias[j8 + 4];
  float bvv[8] = { bv0.x, bv0.y, bv0.z, bv0.w, bv1.x, bv1.y, bv1.z, bv1.w };
  float o[8];
#pragma unroll
  for (int k = 0; k < 8; k++) {
    float a = accA[k] + accB[k];
    o[k] = fmaf(d, a, fmaf(s, hv[k], bvv[k]));
    if (RELU) o[k] = fmaxf(o[k], 0.f);
  }
  if (OUTBF) {
    uint4 pv;
    pv.x = packbf2(o[0], o[1]); pv.y = packbf2(o[2], o[3]);
    pv.z = packbf2(o[4], o[5]); pv.w = packbf2(o[6], o[7]);
    *(uint4*)&((unsigned short*)hout)[(size_t)v * 128 + j8] = pv;
  } else {
    float* hf = (float*)hout;
    *(float4*)&hf[(size_t)v * 128 + j8]     = make_float4(o[0], o[1], o[2], o[3]);
    *(float4*)&hf[(size_t)v * 128 + j8 + 4] = make_float4(o[4], o[5], o[6], o[7]);
  }
}

// ---------- per-edge kernel (MFMA layer b) ----------
__global__ __launch_bounds__(256) void k_edge(const unsigned short* __restrict__ U,
    const int* __restrict__ p0, const int* __restrict__ p1,
    const unsigned short* __restrict__ WbF, const float* __restrict__ bb,
    const float* __restrict__ Wc, const float* __restrict__ bc,
    float* __restrict__ logits, int ES) {
  __shared__ alignas(16) unsigned short sS1[64 * 72];   // bf16 [edge][k], stride 72
  const int t = threadIdx.x;
  const int base = blockIdx.x << 6;
  {  // gather + add + relu + bf16-pack -> sS1
    int p = t >> 2, q = t & 3;
    int e = base + p; if (e >= ES) e = ES - 1;
    const unsigned short* r0 = U + (size_t)p0[e] * 128;        // U0: cols 0..63
    const unsigned short* r1 = U + (size_t)p1[e] * 128 + 64;   // U1: cols 64..127
#pragma unroll
    for (int i = 0; i < 4; i++) {
      int c = i * 16 + q * 4;
      uint2 av = *(const uint2*)&r0[c];
      uint2 bv = *(const uint2*)&r1[c];
      float ox = fmaxf(bflo(av.x) + bflo(bv.x), 0.f);
      float oy = fmaxf(bfhi(av.x) + bfhi(bv.x), 0.f);
      float oz = fmaxf(bflo(av.y) + bflo(bv.y), 0.f);
      float ow = fmaxf(bfhi(av.y) + bfhi(bv.y), 0.f);
      uint2 pv;
      pv.x = packbf2(ox, oy);
      pv.y = packbf2(oz, ow);
      *(uint2*)&sS1[p * 72 + c] = pv;
    }
  }
  __syncthreads();
  const int lane = t & 63;
  const int wave = t >> 6;
  const int quad = lane >> 4, n0 = lane & 15;
  const int edge0 = wave * 16;
  bf16x8 a0 = *(const bf16x8*)&sS1[(edge0 + n0) * 72 + quad * 8];
  bf16x8 a1 = *(const bf16x8*)&sS1[(edge0 + n0) * 72 + 32 + quad * 8];
  const bf16x8* wf = (const bf16x8*)WbF;
  bf16x8 b00 = wf[lane * 4 + 0];
  bf16x8 b01 = wf[lane * 4 + 1];
  bf16x8 b10 = wf[lane * 4 + 2];
  bf16x8 b11 = wf[lane * 4 + 3];
  f32x4 acc0 = {0.f, 0.f, 0.f, 0.f};
  f32x4 acc1 = {0.f, 0.f, 0.f, 0.f};
  acc0 = __builtin_amdgcn_mfma_f32_16x16x32_bf16(a0, b00, acc0, 0, 0, 0);
  acc0 = __builtin_amdgcn_mfma_f32_16x16x32_bf16(a1, b10, acc0, 0, 0, 0);
  acc1 = __builtin_amdgcn_mfma_f32_16x16x32_bf16(a0, b01, acc1, 0, 0, 0);
  acc1 = __builtin_amdgcn_mfma_f32_16x16x32_bf16(a1, b11, acc1, 0, 0, 0);
  const float bb0 = bb[n0], bb1 = bb[n0 + 16];
  const float wc0 = Wc[n0], wc1 = Wc[n0 + 16];
  const float bcv = bc[0];
#pragma unroll
  for (int reg = 0; reg < 4; reg++) {
    float s = fmaf(fmaxf(acc0[reg] + bb0, 0.f), wc0,
                   fmaxf(acc1[reg] + bb1, 0.f) * wc1);
    s += __shfl_xor(s, 1);
    s += __shfl_xor(s, 2);
    s += __shfl_xor(s, 4);
    s += __shfl_xor(s, 8);
    if (n0 == 0) {
      int e = base + edge0 + quad * 4 + reg;
      if (e < ES) logits[e] = s + bcv;
    }
  }
}

// ---------- fused per-graph softmax: one block per graph (eg sorted) ----------
DEVINL int lbound(const int* __restrict__ a, int n, int key) {
  int lo = 0, hi = n;
  while (lo < hi) { int mid = (lo + hi) >> 1; if (a[mid] < key) lo = mid + 1; else hi = mid; }
  return lo;
}
__global__ __launch_bounds__(512) void k_softmax(const float* __restrict__ logits,
                          const int* __restrict__ eg,
                          float* __restrict__ out, int ES) {
  const int g = blockIdx.x;
  const int t = threadIdx.x;
  const int lo = lbound(eg, ES, g);
  const int hi = lbound(eg, ES, g + 1);
  if (lo >= hi) return;
  __shared__ float red[512];
  __shared__ float s_m, s_z;
  float m = -3.4e38f;
  for (int i = lo + t; i < hi; i += 512) m = fmaxf(m, logits[i]);
  red[t] = m; __syncthreads();
#pragma unroll
  for (int off = 256; off >= 1; off >>= 1) {
    if (t < off) red[t] = fmaxf(red[t], red[t + off]);
    __syncthreads();
  }
  if (t == 0) s_m = red[0];
  __syncthreads();
  const float gm = s_m;
  float z = 0.f;
  for (int i = lo + t; i < hi; i += 512) {
    float e = expf(logits[i] - gm);
    out[i] = e;
    z += e;
  }
  red[t] = z; __syncthreads();
#pragma unroll
  for (int off = 256; off >= 1; off >>= 1) {
    if (t < off) red[t] += red[t + off];
    __syncthreads();
  }
  if (t == 0) s_z = red[0];
  __syncthreads();
  const float inv = 1.0f / s_z;
  for (int i = lo + t; i < hi; i += 512) out[i] *= inv;
}

// ---------------------------------------------------------------------------
extern "C" void kernel_launch(void* const* d_in, const int* in_sizes, int n_in,
                              void* d_out, int out_size, void* d_ws, size_t ws_size,
                              hipStream_t stream) {
  const float* x  = (const float*)d_in[0];
  const int* ei   = (const int*)d_in[1];
  const float* ew = (const float*)d_in[2];
  const int* pi   = (const int*)d_in[3];
  const int* eg   = (const int*)d_in[4];
  const float* Wp = (const float*)d_in[6];
  const float* bp = (const float*)d_in[7];
  const float* W1 = (const float*)d_in[8];
  const float* b1 = (const float*)d_in[9];
  const float* W2 = (const float*)d_in[10];
  const float* b2 = (const float*)d_in[11];
  const float* Wa = (const float*)d_in[12];
  const float* ba = (const float*)d_in[13];
  const float* Wb = (const float*)d_in[14];
  const float* bb = (const float*)d_in[15];
  const float* Wc = (const float*)d_in[16];
  const float* bc = (const float*)d_in[17];

  const int N  = in_sizes[0] / 64;
  const int E  = in_sizes[2];
  const int ES = in_sizes[4];
  const int G  = 128;

  float* ws = (float*)d_ws;
  size_t o = 0;
  const size_t Npad = ((size_t)N + 31) & ~(size_t)31;
  ull* cnt64 = (ull*)(ws + o);  o += 2 * Npad;          // packed count|weightsum
  float* dinv = (float*)(ws + o); o += Npad;
  int* start = (int*)(ws + o);  o += Npad + 32;         // exclusive prefix, N+1 entries
  int* bsum = (int*)(ws + o);   o += 512;
  int* boff = (int*)(ws + o);   o += 512;
  int2* pk = (int2*)(ws + o);   o += (size_t)E * 2;
  float* A = ws + o;            o += (size_t)N * 128;   // h1 fp32 -> U bf16
  float* B = ws + o;            o += (size_t)N * 128;   // pos -> hw1 bf16 -> V bf16 -> logits
  float* Wfuse = ws + o;        o += 8192;
  float* bfuse = ws + o;        o += 128;
  float* Mcat = ws + o;         o += 16384;
  float* bU = ws + o;           o += 128;
  unsigned short* WbF = (unsigned short*)(ws + o); o += 1024;  // 2048 bf16

  int* pos = (int*)B;                       // dead before gemm1 writes hw1
  unsigned short* hw1 = (unsigned short*)B;
  float* h1 = A;
  unsigned short* V = (unsigned short*)B;   // overwrites hw1 (dead after gather1)
  unsigned short* U = (unsigned short*)A;   // overwrites h1 (dead after gemm2)
  float* logits = B;                        // overwrites V (dead after gather2)

  const int* row = ei;
  const int* col = ei + E;
  const int* p0 = pi;
  const int* p1 = pi + ES;
  float* out = (float*)d_out;

  const int gN = (N + 255) / 256;
  const int gE = (E + 255) / 256;
  const int nb = gN;

  // ---- weight folding + CSR build ----
  hipMemsetAsync(cnt64, 0, Npad * sizeof(ull), stream);
  k_prep<<<105, 256, 0, stream>>>(Wp, bp, W1, W2, Wa, ba, b2, Wb,
                                  Wfuse, bfuse, Mcat, bU, WbF);
  k_hist64<<<gE, 256, 0, stream>>>(col, ew, cnt64, pos, E);
  k_scan1<<<nb, 256, 0, stream>>>(cnt64, start, bsum, N);
  k_scan2<<<1, 512, 0, stream>>>(bsum, boff, nb, &start[N]);
  k_scan3dinv<<<nb, 256, 0, stream>>>(start, boff, cnt64, dinv, N);
  k_fill<<<gE, 256, 0, stream>>>(row, col, ew, dinv, start, pos, pk, E);

  // ---- node pipeline: 2 GEMMs + 2 gathers ----
  const int gRows = (N + 127) / 128;
  const int gGat = (N + 15) / 16;
  k_gemm<64, 128, true, true><<<gRows, 256, 0, stream>>>(x, Wfuse, bfuse, (void*)hw1, N);
  k_gather<true, false><<<gGat, 256, 0, stream>>>(start, pk, hw1, dinv, b1, (void*)h1, N);
  k_gemm<128, 128, false, true><<<gRows, 256, 0, stream>>>(h1, Mcat, nullptr, (void*)V, N);
  k_gather<false, true><<<gGat, 256, 0, stream>>>(start, pk, V, dinv, bU, (void*)U, N);

  // ---- per-edge MLP (MFMA) ----
  k_edge<<<(ES + 63) / 64, 256, 0, stream>>>(U, p0, p1, WbF, bb, Wc, bc, logits, ES);

  // ---- per-graph softmax ----
  k_softmax<<<G, 512, 0, stream>>>(logits, eg, out, ES);
}

// Round 10
// 364.433 us; speedup vs baseline: 8.2272x; 1.2408x over previous
//
#include <hip/hip_runtime.h>
#include <hip/hip_bf16.h>
#include <cstdint>

#define DEVINL __device__ __forceinline__
typedef unsigned long long ull;

// ---------------------------------------------------------------------------
// 2-layer GCN (gcn_norm w/ self-loops) -> per-pair MLP -> per-graph softmax.
// R10: node GEMMs moved to bf16 MFMA (fp32 accumulate). R9 evidence: k_gemm
// 72us at 29% of fp32 vector peak, VALUBusy 40% — vector-ALU GEMM is the
// bottleneck; MFMA layouts already verified on this workload by R8's k_edge.
// h1 stored bf16 (same numerics as fp32-store + stage-convert). k_prep packs
// Wfuse/Mcat directly into B-fragment bf16 layout. Rest identical to R9.
// ---------------------------------------------------------------------------

typedef __attribute__((ext_vector_type(8))) short bf16x8;
typedef __attribute__((ext_vector_type(4))) float f32x4;

DEVINL float bflo(unsigned u) { return __uint_as_float(u << 16); }
DEVINL float bfhi(unsigned u) { return __uint_as_float(u & 0xffff0000u); }
DEVINL unsigned packbf2(float a, float b) {   // RNE pack of 2 fp32 -> 2 bf16
  unsigned ua = __float_as_uint(a); ua = (ua + 0x7fff + ((ua >> 16) & 1)) >> 16;
  unsigned ub = __float_as_uint(b); ub = (ub + 0x7fff + ((ub >> 16) & 1)) >> 16;
  return ua | (ub << 16);
}
DEVINL unsigned short packbf1(float a) {
  unsigned ua = __float_as_uint(a);
  return (unsigned short)((ua + 0x7fff + ((ua >> 16) & 1)) >> 16);
}

// ---------- CSR build ----------
// one 64-bit atomic per edge: high 28 bits = count, low 36 bits = sum(w) in
// 8.28 fixed point. Returned old value = in-bucket position (atomic-free fill).
__global__ void k_hist64(const int* __restrict__ col, const float* __restrict__ w,
                         ull* __restrict__ cnt64, int* __restrict__ pos, int E) {
  int e = blockIdx.x * 256 + threadIdx.x;
  if (e < E) {
    ull inc = (1ULL << 36) | (ull)(unsigned)(w[e] * 268435456.0f + 0.5f);
    ull old = atomicAdd(&cnt64[col[e]], inc);
    pos[e] = (int)(old >> 36);
  }
}

__global__ void k_scan1(const ull* __restrict__ cnt64, int* __restrict__ start,
                        int* __restrict__ bsum, int N) {
  __shared__ int s[256];
  int t = threadIdx.x;
  int i = blockIdx.x * 256 + t;
  int v = (i < N) ? (int)(cnt64[i] >> 36) : 0;
  s[t] = v; __syncthreads();
  int x = v;
#pragma unroll
  for (int off = 1; off < 256; off <<= 1) {
    int y = (t >= off) ? s[t - off] : 0;
    __syncthreads();
    x += y; s[t] = x;
    __syncthreads();
  }
  if (i < N) start[i] = x - v;   // block-local exclusive
  if (t == 255) bsum[blockIdx.x] = x;
}
__global__ void k_scan2(const int* __restrict__ bsum, int* __restrict__ boff,
                        int nb, int* __restrict__ startN) {
  __shared__ int s[512];
  int t = threadIdx.x;
  int v = (t < nb) ? bsum[t] : 0;
  s[t] = v; __syncthreads();
  int x = v;
#pragma unroll
  for (int off = 1; off < 512; off <<= 1) {
    int y = (t >= off) ? s[t - off] : 0;
    __syncthreads();
    x += y; s[t] = x;
    __syncthreads();
  }
  if (t < nb) boff[t] = x - v;
  if (t == nb - 1) *startN = x;  // = E
}
__global__ void k_scan3dinv(int* __restrict__ start, const int* __restrict__ boff,
                            const ull* __restrict__ cnt64, float* __restrict__ dinv, int N) {
  int i = blockIdx.x * 256 + threadIdx.x;
  if (i < N) {
    start[i] += boff[blockIdx.x];
    float sw = (float)(cnt64[i] & 0xFFFFFFFFFULL) * 3.7252903e-09f;  // *2^-28
    dinv[i] = rsqrtf(1.0f + sw);
  }
}

__global__ void k_fill(const int* __restrict__ row, const int* __restrict__ col,
                       const float* __restrict__ w, const float* __restrict__ dinv,
                       const int* __restrict__ start, const int* __restrict__ pos,
                       int2* __restrict__ pk, int E) {
  int e = blockIdx.x * 256 + threadIdx.x;
  if (e >= E) return;
  int r = row[e];
  int p = start[col[e]] + pos[e];
  pk[p] = make_int2(r, __float_as_int(w[e] * dinv[r]));
}

// ---------- weight folding (tiny, once per call) ----------
// WfuseF [64x128] and McatF [128x128] are emitted DIRECTLY in bf16 MFMA
// B-fragment order: frag elem j at lane l for (kci,nt) =
//   W[kci*32 + (l>>4)*8 + j][nt*16 + (l&15)]
// linear index m = ((kci*8 + nt)*64 + l)*8 + j.
__global__ void k_prep(const float* __restrict__ Wp, const float* __restrict__ bp,
                       const float* __restrict__ W1,
                       const float* __restrict__ W2, const float* __restrict__ Wa,
                       const float* __restrict__ ba, const float* __restrict__ b2,
                       const float* __restrict__ Wb,
                       unsigned short* __restrict__ WfuseF, float* __restrict__ bfuse,
                       unsigned short* __restrict__ McatF, float* __restrict__ bU,
                       unsigned short* __restrict__ WbF) {
  int id = blockIdx.x * 256 + threadIdx.x;
  if (id < 8192) {                      // WfuseF = pack(Wp@W1), K=64, N=128
    int j = id & 7, q = id >> 3;
    int l = q & 63, p = q >> 6;
    int nt = p & 7, kci = p >> 3;       // kci in {0,1}
    int kr = kci * 32 + ((l >> 4) << 3) + j;   // k-index in [0,64)
    int nc = nt * 16 + (l & 15);               // col in [0,128)
    float s = 0.f;
    for (int c = 0; c < 128; c++) s = fmaf(Wp[kr * 128 + c], W1[c * 128 + nc], s);
    WfuseF[id] = packbf1(s);
  } else if (id < 8320) {               // bfuse = bp@W1
    int j = id - 8192;
    float s = 0.f;
    for (int c = 0; c < 128; c++) s = fmaf(bp[c], W1[c * 128 + j], s);
    bfuse[j] = s;
  } else if (id < 24704) {              // McatF = pack([W2@Wa0 | W2@Wa1]), K=128
    int m = id - 8320;
    int j8 = m & 7, q = m >> 3;
    int l = q & 63, p = q >> 6;
    int nt = p & 7, kci = p >> 3;       // kci in {0..3}
    int kr = kci * 32 + ((l >> 4) << 3) + j8;  // k-index in [0,128)
    int nc = nt * 16 + (l & 15);
    int jj = nc & 63, koff = (nc < 64) ? 0 : 64;
    float s = 0.f;
    for (int k = 0; k < 64; k++) s = fmaf(W2[kr * 64 + k], Wa[(koff + k) * 64 + jj], s);
    McatF[m] = packbf1(s);
  } else if (id < 24832) {              // bU = [b2@Wa0+ba | b2@Wa1]
    int j = id - 24704;
    int jj = j & 63, koff = (j < 64) ? 0 : 64;
    float s = (j < 64) ? ba[j] : 0.f;
    for (int k = 0; k < 64; k++) s = fmaf(b2[k], Wa[(koff + k) * 64 + jj], s);
    bU[j] = s;
  } else if (id < 24832 + 2048) {       // WbF bf16 B-fragment pack (k_edge)
    int m = id - 24832;
    int j = m & 7;
    int idx = m >> 3;
    int nt = idx & 1, kt = (idx >> 1) & 1, l = idx >> 2;
    int kr = kt * 32 + ((l >> 4) << 3) + j;
    int nc = nt * 16 + (l & 15);
    WbF[m] = packbf1(Wb[kr * 32 + nc]);
  }
}

// ---------- MFMA bf16 GEMM: C[N,128] = A[N,K] @ W[K,128] (+bias), C bf16 ----------
// 128x128 tile, 4 waves; wave w owns col-tiles {2w, 2w+1}; 8 row-tiles each.
// A staged to LDS bf16, stride 40 shorts (80B rows: 16B-aligned frags, 2-way
// banking = free). ABF: A already bf16; else fp32 -> pack during staging.
template<int K, bool ABF, bool BIAS>
__global__ __launch_bounds__(256) void k_gemm_mfma(const void* __restrict__ Av,
    const unsigned short* __restrict__ WF, const float* __restrict__ bias,
    unsigned short* __restrict__ C, int N) {
  __shared__ alignas(16) unsigned short sA[128 * 40];
  const int t = threadIdx.x;
  const int lane = t & 63, wave = t >> 6;
  const int quad = lane >> 4, n0 = lane & 15;
  const int r0 = blockIdx.x * 128;
  f32x4 acc[8][2] = {};
  for (int kc = 0; kc < K; kc += 32) {
    __syncthreads();
    if (ABF) {
      const unsigned short* Ab = (const unsigned short*)Av;
#pragma unroll
      for (int i = 0; i < 2; i++) {
        int idx = (t + i * 256) * 8;
        int r = idx >> 5, k = idx & 31;
        int gr = r0 + r;
        uint4 v = make_uint4(0u, 0u, 0u, 0u);
        if (gr < N) v = *(const uint4*)&Ab[(size_t)gr * K + kc + k];
        *(uint4*)&sA[r * 40 + k] = v;
      }
    } else {
      const float* Af = (const float*)Av;
#pragma unroll
      for (int i = 0; i < 4; i++) {
        int idx = (t + i * 256) * 4;
        int r = idx >> 5, k = idx & 31;
        int gr = r0 + r;
        float4 v = make_float4(0.f, 0.f, 0.f, 0.f);
        if (gr < N) v = *(const float4*)&Af[(size_t)gr * K + kc + k];
        uint2 pv;
        pv.x = packbf2(v.x, v.y);
        pv.y = packbf2(v.z, v.w);
        *(uint2*)&sA[r * 40 + k] = pv;
      }
    }
    __syncthreads();
    const int kci = kc >> 5;
    const bf16x8* wf = (const bf16x8*)WF;
    bf16x8 b0 = wf[(kci * 8 + wave * 2 + 0) * 64 + lane];
    bf16x8 b1 = wf[(kci * 8 + wave * 2 + 1) * 64 + lane];
#pragma unroll
    for (int rt = 0; rt < 8; rt++) {
      bf16x8 af = *(const bf16x8*)&sA[(rt * 16 + n0) * 40 + quad * 8];
      acc[rt][0] = __builtin_amdgcn_mfma_f32_16x16x32_bf16(af, b0, acc[rt][0], 0, 0, 0);
      acc[rt][1] = __builtin_amdgcn_mfma_f32_16x16x32_bf16(af, b1, acc[rt][1], 0, 0, 0);
    }
  }
  // epilogue: C-layout col=n0, row=quad*4+reg per 16x16 tile
  const int colbase = wave * 32;
  const float bc0 = BIAS ? bias[colbase + n0] : 0.f;
  const float bc1 = BIAS ? bias[colbase + 16 + n0] : 0.f;
#pragma unroll
  for (int rt = 0; rt < 8; rt++) {
#pragma unroll
    for (int reg = 0; reg < 4; reg++) {
      int row = r0 + rt * 16 + quad * 4 + reg;
      if (row < N) {
        unsigned short* cp = C + (size_t)row * 128 + colbase;
        cp[n0] = packbf1(acc[rt][0][reg] + bc0);
        cp[n0 + 16] = packbf1(acc[rt][1][reg] + bc1);
      }
    }
  }
}

// ---------- CSR gather (bf16 table): h[v] = act(dinv*sum + dinv^2*hw[v] + bias) ----
// start is exclusive prefix with N+1 entries: b = start[v], en = start[v+1].
template<bool RELU, bool OUTBF>
__global__ void k_gather(const int* __restrict__ start, const int2* __restrict__ pk,
                         const unsigned short* __restrict__ hw, const float* __restrict__ dinv,
                         const float* __restrict__ bias, void* __restrict__ hout, int N) {
  const int t = threadIdx.x;
  const int v = blockIdx.x * 16 + (t >> 4);
  if (v >= N) return;
  const int j8 = (t & 15) * 8;
  const int b = start[v];
  const int en = start[v + 1];
  float accA[8] = {}, accB[8] = {};
  int i = b;
  for (; i + 1 < en; i += 2) {
    int2 q0 = pk[i], q1 = pk[i + 1];
    float n0 = __int_as_float(q0.y), n1 = __int_as_float(q1.y);
    uint4 w0 = *(const uint4*)&hw[(size_t)q0.x * 128 + j8];
    uint4 w1 = *(const uint4*)&hw[(size_t)q1.x * 128 + j8];
    accA[0] = fmaf(n0, bflo(w0.x), accA[0]); accA[1] = fmaf(n0, bfhi(w0.x), accA[1]);
    accA[2] = fmaf(n0, bflo(w0.y), accA[2]); accA[3] = fmaf(n0, bfhi(w0.y), accA[3]);
    accA[4] = fmaf(n0, bflo(w0.z), accA[4]); accA[5] = fmaf(n0, bfhi(w0.z), accA[5]);
    accA[6] = fmaf(n0, bflo(w0.w), accA[6]); accA[7] = fmaf(n0, bfhi(w0.w), accA[7]);
    accB[0] = fmaf(n1, bflo(w1.x), accB[0]); accB[1] = fmaf(n1, bfhi(w1.x), accB[1]);
    accB[2] = fmaf(n1, bflo(w1.y), accB[2]); accB[3] = fmaf(n1, bfhi(w1.y), accB[3]);
    accB[4] = fmaf(n1, bflo(w1.z), accB[4]); accB[5] = fmaf(n1, bfhi(w1.z), accB[5]);
    accB[6] = fmaf(n1, bflo(w1.w), accB[6]); accB[7] = fmaf(n1, bfhi(w1.w), accB[7]);
  }
  if (i < en) {
    int2 q = pk[i];
    float n = __int_as_float(q.y);
    uint4 w0 = *(const uint4*)&hw[(size_t)q.x * 128 + j8];
    accA[0] = fmaf(n, bflo(w0.x), accA[0]); accA[1] = fmaf(n, bfhi(w0.x), accA[1]);
    accA[2] = fmaf(n, bflo(w0.y), accA[2]); accA[3] = fmaf(n, bfhi(w0.y), accA[3]);
    accA[4] = fmaf(n, bflo(w0.z), accA[4]); accA[5] = fmaf(n, bfhi(w0.z), accA[5]);
    accA[6] = fmaf(n, bflo(w0.w), accA[6]); accA[7] = fmaf(n, bfhi(w0.w), accA[7]);
  }
  const float d = dinv[v];
  const float s = d * d;
  uint4 wv = *(const uint4*)&hw[(size_t)v * 128 + j8];
  float hv[8] = { bflo(wv.x), bfhi(wv.x), bflo(wv.y), bfhi(wv.y),
                  bflo(wv.z), bfhi(wv.z), bflo(wv.w), bfhi(wv.w) };
  float4 bv0 = *(const float4*)&bias[j8];
  float4 bv1 = *(const float4*)&bias[j8 + 4];
  float bvv[8] = { bv0.x, bv0.y, bv0.z, bv0.w, bv1.x, bv1.y, bv1.z, bv1.w };
  float o[8];
#pragma unroll
  for (int k = 0; k < 8; k++) {
    float a = accA[k] + accB[k];
    o[k] = fmaf(d, a, fmaf(s, hv[k], bvv[k]));
    if (RELU) o[k] = fmaxf(o[k], 0.f);
  }
  if (OUTBF) {
    uint4 pv;
    pv.x = packbf2(o[0], o[1]); pv.y = packbf2(o[2], o[3]);
    pv.z = packbf2(o[4], o[5]); pv.w = packbf2(o[6], o[7]);
    *(uint4*)&((unsigned short*)hout)[(size_t)v * 128 + j8] = pv;
  } else {
    float* hf = (float*)hout;
    *(float4*)&hf[(size_t)v * 128 + j8]     = make_float4(o[0], o[1], o[2], o[3]);
    *(float4*)&hf[(size_t)v * 128 + j8 + 4] = make_float4(o[4], o[5], o[6], o[7]);
  }
}

// ---------- per-edge kernel (MFMA layer b) ----------
__global__ __launch_bounds__(256) void k_edge(const unsigned short* __restrict__ U,
    const int* __restrict__ p0, const int* __restrict__ p1,
    const unsigned short* __restrict__ WbF, const float* __restrict__ bb,
    const float* __restrict__ Wc, const float* __restrict__ bc,
    float* __restrict__ logits, int ES) {
  __shared__ alignas(16) unsigned short sS1[64 * 72];   // bf16 [edge][k], stride 72
  const int t = threadIdx.x;
  const int base = blockIdx.x << 6;
  {  // gather + add + relu + bf16-pack -> sS1
    int p = t >> 2, q = t & 3;
    int e = base + p; if (e >= ES) e = ES - 1;
    const unsigned short* r0 = U + (size_t)p0[e] * 128;        // U0: cols 0..63
    const unsigned short* r1 = U + (size_t)p1[e] * 128 + 64;   // U1: cols 64..127
#pragma unroll
    for (int i = 0; i < 4; i++) {
      int c = i * 16 + q * 4;
      uint2 av = *(const uint2*)&r0[c];
      uint2 bv = *(const uint2*)&r1[c];
      float ox = fmaxf(bflo(av.x) + bflo(bv.x), 0.f);
      float oy = fmaxf(bfhi(av.x) + bfhi(bv.x), 0.f);
      float oz = fmaxf(bflo(av.y) + bflo(bv.y), 0.f);
      float ow = fmaxf(bfhi(av.y) + bfhi(bv.y), 0.f);
      uint2 pv;
      pv.x = packbf2(ox, oy);
      pv.y = packbf2(oz, ow);
      *(uint2*)&sS1[p * 72 + c] = pv;
    }
  }
  __syncthreads();
  const int lane = t & 63;
  const int wave = t >> 6;
  const int quad = lane >> 4, n0 = lane & 15;
  const int edge0 = wave * 16;
  bf16x8 a0 = *(const bf16x8*)&sS1[(edge0 + n0) * 72 + quad * 8];
  bf16x8 a1 = *(const bf16x8*)&sS1[(edge0 + n0) * 72 + 32 + quad * 8];
  const bf16x8* wf = (const bf16x8*)WbF;
  bf16x8 b00 = wf[lane * 4 + 0];
  bf16x8 b01 = wf[lane * 4 + 1];
  bf16x8 b10 = wf[lane * 4 + 2];
  bf16x8 b11 = wf[lane * 4 + 3];
  f32x4 acc0 = {0.f, 0.f, 0.f, 0.f};
  f32x4 acc1 = {0.f, 0.f, 0.f, 0.f};
  acc0 = __builtin_amdgcn_mfma_f32_16x16x32_bf16(a0, b00, acc0, 0, 0, 0);
  acc0 = __builtin_amdgcn_mfma_f32_16x16x32_bf16(a1, b10, acc0, 0, 0, 0);
  acc1 = __builtin_amdgcn_mfma_f32_16x16x32_bf16(a0, b01, acc1, 0, 0, 0);
  acc1 = __builtin_amdgcn_mfma_f32_16x16x32_bf16(a1, b11, acc1, 0, 0, 0);
  const float bb0 = bb[n0], bb1 = bb[n0 + 16];
  const float wc0 = Wc[n0], wc1 = Wc[n0 + 16];
  const float bcv = bc[0];
#pragma unroll
  for (int reg = 0; reg < 4; reg++) {
    float s = fmaf(fmaxf(acc0[reg] + bb0, 0.f), wc0,
                   fmaxf(acc1[reg] + bb1, 0.f) * wc1);
    s += __shfl_xor(s, 1);
    s += __shfl_xor(s, 2);
    s += __shfl_xor(s, 4);
    s += __shfl_xor(s, 8);
    if (n0 == 0) {
      int e = base + edge0 + quad * 4 + reg;
      if (e < ES) logits[e] = s + bcv;
    }
  }
}

// ---------- fused per-graph softmax: one block per graph (eg sorted) ----------
DEVINL int lbound(const int* __restrict__ a, int n, int key) {
  int lo = 0, hi = n;
  while (lo < hi) { int mid = (lo + hi) >> 1; if (a[mid] < key) lo = mid + 1; else hi = mid; }
  return lo;
}
__global__ __launch_bounds__(512) void k_softmax(const float* __restrict__ logits,
                          const int* __restrict__ eg,
                          float* __restrict__ out, int ES) {
  const int g = blockIdx.x;
  const int t = threadIdx.x;
  const int lo = lbound(eg, ES, g);
  const int hi = lbound(eg, ES, g + 1);
  if (lo >= hi) return;
  __shared__ float red[512];
  __shared__ float s_m, s_z;
  float m = -3.4e38f;
  for (int i = lo + t; i < hi; i += 512) m = fmaxf(m, logits[i]);
  red[t] = m; __syncthreads();
#pragma unroll
  for (int off = 256; off >= 1; off >>= 1) {
    if (t < off) red[t] = fmaxf(red[t], red[t + off]);
    __syncthreads();
  }
  if (t == 0) s_m = red[0];
  __syncthreads();
  const float gm = s_m;
  float z = 0.f;
  for (int i = lo + t; i < hi; i += 512) {
    float e = expf(logits[i] - gm);
    out[i] = e;
    z += e;
  }
  red[t] = z; __syncthreads();
#pragma unroll
  for (int off = 256; off >= 1; off >>= 1) {
    if (t < off) red[t] += red[t + off];
    __syncthreads();
  }
  if (t == 0) s_z = red[0];
  __syncthreads();
  const float inv = 1.0f / s_z;
  for (int i = lo + t; i < hi; i += 512) out[i] *= inv;
}

// ---------------------------------------------------------------------------
extern "C" void kernel_launch(void* const* d_in, const int* in_sizes, int n_in,
                              void* d_out, int out_size, void* d_ws, size_t ws_size,
                              hipStream_t stream) {
  const float* x  = (const float*)d_in[0];
  const int* ei   = (const int*)d_in[1];
  const float* ew = (const float*)d_in[2];
  const int* pi   = (const int*)d_in[3];
  const int* eg   = (const int*)d_in[4];
  const float* Wp = (const float*)d_in[6];
  const float* bp = (const float*)d_in[7];
  const float* W1 = (const float*)d_in[8];
  const float* b1 = (const float*)d_in[9];
  const float* W2 = (const float*)d_in[10];
  const float* b2 = (const float*)d_in[11];
  const float* Wa = (const float*)d_in[12];
  const float* ba = (const float*)d_in[13];
  const float* Wb = (const float*)d_in[14];
  const float* bb = (const float*)d_in[15];
  const float* Wc = (const float*)d_in[16];
  const float* bc = (const float*)d_in[17];

  const int N  = in_sizes[0] / 64;
  const int E  = in_sizes[2];
  const int ES = in_sizes[4];
  const int G  = 128;

  float* ws = (float*)d_ws;
  size_t o = 0;
  const size_t Npad = ((size_t)N + 31) & ~(size_t)31;
  ull* cnt64 = (ull*)(ws + o);  o += 2 * Npad;          // packed count|weightsum
  float* dinv = (float*)(ws + o); o += Npad;
  int* start = (int*)(ws + o);  o += Npad + 32;         // exclusive prefix, N+1 entries
  int* bsum = (int*)(ws + o);   o += 512;
  int* boff = (int*)(ws + o);   o += 512;
  int2* pk = (int2*)(ws + o);   o += (size_t)E * 2;
  float* A = ws + o;            o += (size_t)N * 128;   // h1 bf16 -> U bf16
  float* B = ws + o;            o += (size_t)N * 128;   // pos -> hw1 bf16 -> V bf16 -> logits
  unsigned short* WfuseF = (unsigned short*)(ws + o); o += 4096;   // 8192 bf16
  float* bfuse = ws + o;        o += 128;
  unsigned short* McatF = (unsigned short*)(ws + o); o += 8192;    // 16384 bf16
  float* bU = ws + o;           o += 128;
  unsigned short* WbF = (unsigned short*)(ws + o); o += 1024;      // 2048 bf16

  int* pos = (int*)B;                       // dead before gemm1 writes hw1
  unsigned short* hw1 = (unsigned short*)B;
  unsigned short* h1 = (unsigned short*)A;  // bf16 now (MFMA A-operand)
  unsigned short* V = (unsigned short*)B;   // overwrites hw1 (dead after gather1)
  unsigned short* U = (unsigned short*)A;   // overwrites h1 (dead after gemm2)
  float* logits = B;                        // overwrites V (dead after gather2)

  const int* row = ei;
  const int* col = ei + E;
  const int* p0 = pi;
  const int* p1 = pi + ES;
  float* out = (float*)d_out;

  const int gE = (E + 255) / 256;
  const int nb = (N + 255) / 256;

  // ---- weight folding + CSR build ----
  hipMemsetAsync(cnt64, 0, Npad * sizeof(ull), stream);
  k_prep<<<105, 256, 0, stream>>>(Wp, bp, W1, W2, Wa, ba, b2, Wb,
                                  WfuseF, bfuse, McatF, bU, WbF);
  k_hist64<<<gE, 256, 0, stream>>>(col, ew, cnt64, pos, E);
  k_scan1<<<nb, 256, 0, stream>>>(cnt64, start, bsum, N);
  k_scan2<<<1, 512, 0, stream>>>(bsum, boff, nb, &start[N]);
  k_scan3dinv<<<nb, 256, 0, stream>>>(start, boff, cnt64, dinv, N);
  k_fill<<<gE, 256, 0, stream>>>(row, col, ew, dinv, start, pos, pk, E);

  // ---- node pipeline: 2 MFMA GEMMs + 2 gathers ----
  const int gRows = (N + 127) / 128;
  const int gGat = (N + 15) / 16;
  k_gemm_mfma<64, false, true><<<gRows, 256, 0, stream>>>(x, WfuseF, bfuse, hw1, N);
  k_gather<true, true><<<gGat, 256, 0, stream>>>(start, pk, hw1, dinv, b1, (void*)h1, N);
  k_gemm_mfma<128, true, false><<<gRows, 256, 0, stream>>>(h1, McatF, nullptr, V, N);
  k_gather<false, true><<<gGat, 256, 0, stream>>>(start, pk, V, dinv, bU, (void*)U, N);

  // ---- per-edge MLP (MFMA) ----
  k_edge<<<(ES + 63) / 64, 256, 0, stream>>>(U, p0, p1, WbF, bb, Wc, bc, logits, ES);

  // ---- per-graph softmax ----
  k_softmax<<<G, 512, 0, stream>>>(logits, eg, out, ES);
}

// Round 11
// 362.407 us; speedup vs baseline: 8.2732x; 1.0056x over previous
//
#include <hip/hip_runtime.h>
#include <hip/hip_bf16.h>
#include <cstdint>

#define DEVINL __device__ __forceinline__
typedef unsigned long long ull;

// ---------------------------------------------------------------------------
// 2-layer GCN (gcn_norm w/ self-loops) -> per-pair MLP -> per-graph softmax.
// R11: block-range fusion to overlap idle-pipe kernels. R10 evidence:
// k_hist64 48us at 21G atomics/s with VALUBusy 0.6% / HBM 10% — machine idle
// while atomics drain; k_fill similar. Fix: pos gets its own buffer (removes
// false dep on B), then [hist+prep] and [fill+gemm1] each fuse into one
// launch (block-uniform branch; MFMA/VALU co-schedule with atomic/scatter
// waves per m114). All compute bodies byte-identical to R10.
// ---------------------------------------------------------------------------

typedef __attribute__((ext_vector_type(8))) short bf16x8;
typedef __attribute__((ext_vector_type(4))) float f32x4;

DEVINL float bflo(unsigned u) { return __uint_as_float(u << 16); }
DEVINL float bfhi(unsigned u) { return __uint_as_float(u & 0xffff0000u); }
DEVINL unsigned packbf2(float a, float b) {   // RNE pack of 2 fp32 -> 2 bf16
  unsigned ua = __float_as_uint(a); ua = (ua + 0x7fff + ((ua >> 16) & 1)) >> 16;
  unsigned ub = __float_as_uint(b); ub = (ub + 0x7fff + ((ub >> 16) & 1)) >> 16;
  return ua | (ub << 16);
}
DEVINL unsigned short packbf1(float a) {
  unsigned ua = __float_as_uint(a);
  return (unsigned short)((ua + 0x7fff + ((ua >> 16) & 1)) >> 16);
}

// ---------- fused: CSR histogram (atomic-bound) + weight folding (VALU) ----------
// blocks [0, gH): one 64-bit atomic per edge: high 28 bits = count, low 36 =
// sum(w) in 8.28 fixed point; returned old value = in-bucket position.
// blocks [gH, gH+105): weight folding into bf16 MFMA B-fragment layouts.
__global__ void k_histprep(const int* __restrict__ col, const float* __restrict__ w,
                           ull* __restrict__ cnt64, int* __restrict__ pos, int E, int gH,
                           const float* __restrict__ Wp, const float* __restrict__ bp,
                           const float* __restrict__ W1,
                           const float* __restrict__ W2, const float* __restrict__ Wa,
                           const float* __restrict__ ba, const float* __restrict__ b2,
                           const float* __restrict__ Wb,
                           unsigned short* __restrict__ WfuseF, float* __restrict__ bfuse,
                           unsigned short* __restrict__ McatF, float* __restrict__ bU,
                           unsigned short* __restrict__ WbF) {
  const int bid = blockIdx.x;
  if (bid < gH) {
    int e = bid * 256 + threadIdx.x;
    if (e < E) {
      ull inc = (1ULL << 36) | (ull)(unsigned)(w[e] * 268435456.0f + 0.5f);
      ull old = atomicAdd(&cnt64[col[e]], inc);
      pos[e] = (int)(old >> 36);
    }
    return;
  }
  int id = (bid - gH) * 256 + threadIdx.x;
  if (id < 8192) {                      // WfuseF = pack(Wp@W1), B-frag layout
    int j = id & 7, q = id >> 3;
    int l = q & 63, p = q >> 6;
    int nt = p & 7, kci = p >> 3;
    int kr = kci * 32 + ((l >> 4) << 3) + j;
    int nc = nt * 16 + (l & 15);
    float s = 0.f;
    for (int c = 0; c < 128; c++) s = fmaf(Wp[kr * 128 + c], W1[c * 128 + nc], s);
    WfuseF[id] = packbf1(s);
  } else if (id < 8320) {               // bfuse = bp@W1
    int j = id - 8192;
    float s = 0.f;
    for (int c = 0; c < 128; c++) s = fmaf(bp[c], W1[c * 128 + j], s);
    bfuse[j] = s;
  } else if (id < 24704) {              // McatF = pack([W2@Wa0 | W2@Wa1])
    int m = id - 8320;
    int j8 = m & 7, q = m >> 3;
    int l = q & 63, p = q >> 6;
    int nt = p & 7, kci = p >> 3;
    int kr = kci * 32 + ((l >> 4) << 3) + j8;
    int nc = nt * 16 + (l & 15);
    int jj = nc & 63, koff = (nc < 64) ? 0 : 64;
    float s = 0.f;
    for (int k = 0; k < 64; k++) s = fmaf(W2[kr * 64 + k], Wa[(koff + k) * 64 + jj], s);
    McatF[m] = packbf1(s);
  } else if (id < 24832) {              // bU = [b2@Wa0+ba | b2@Wa1]
    int j = id - 24704;
    int jj = j & 63, koff = (j < 64) ? 0 : 64;
    float s = (j < 64) ? ba[j] : 0.f;
    for (int k = 0; k < 64; k++) s = fmaf(b2[k], Wa[(koff + k) * 64 + jj], s);
    bU[j] = s;
  } else if (id < 24832 + 2048) {       // WbF bf16 B-fragment pack (k_edge)
    int m = id - 24832;
    int j = m & 7;
    int idx = m >> 3;
    int nt = idx & 1, kt = (idx >> 1) & 1, l = idx >> 2;
    int kr = kt * 32 + ((l >> 4) << 3) + j;
    int nc = nt * 16 + (l & 15);
    WbF[m] = packbf1(Wb[kr * 32 + nc]);
  }
}

__global__ void k_scan1(const ull* __restrict__ cnt64, int* __restrict__ start,
                        int* __restrict__ bsum, int N) {
  __shared__ int s[256];
  int t = threadIdx.x;
  int i = blockIdx.x * 256 + t;
  int v = (i < N) ? (int)(cnt64[i] >> 36) : 0;
  s[t] = v; __syncthreads();
  int x = v;
#pragma unroll
  for (int off = 1; off < 256; off <<= 1) {
    int y = (t >= off) ? s[t - off] : 0;
    __syncthreads();
    x += y; s[t] = x;
    __syncthreads();
  }
  if (i < N) start[i] = x - v;   // block-local exclusive
  if (t == 255) bsum[blockIdx.x] = x;
}
__global__ void k_scan2(const int* __restrict__ bsum, int* __restrict__ boff,
                        int nb, int* __restrict__ startN) {
  __shared__ int s[512];
  int t = threadIdx.x;
  int v = (t < nb) ? bsum[t] : 0;
  s[t] = v; __syncthreads();
  int x = v;
#pragma unroll
  for (int off = 1; off < 512; off <<= 1) {
    int y = (t >= off) ? s[t - off] : 0;
    __syncthreads();
    x += y; s[t] = x;
    __syncthreads();
  }
  if (t < nb) boff[t] = x - v;
  if (t == nb - 1) *startN = x;  // = E
}
__global__ void k_scan3dinv(int* __restrict__ start, const int* __restrict__ boff,
                            const ull* __restrict__ cnt64, float* __restrict__ dinv, int N) {
  int i = blockIdx.x * 256 + threadIdx.x;
  if (i < N) {
    start[i] += boff[blockIdx.x];
    float sw = (float)(cnt64[i] & 0xFFFFFFFFFULL) * 3.7252903e-09f;  // *2^-28
    dinv[i] = rsqrtf(1.0f + sw);
  }
}

// ---------- fused: atomic-free CSR fill (scatter-bound) + gemm1 (MFMA) ----------
// blocks [0, gF): pk[start[c]+pos[e]] = {row, w*dinv[row]}.
// blocks [gF, ...): hw1 = bf16(x @ WfuseF + bfuse), 128x128 MFMA tile.
__global__ __launch_bounds__(256) void k_fillgemm(
    const int* __restrict__ row, const int* __restrict__ col,
    const float* __restrict__ w, const float* __restrict__ dinv,
    const int* __restrict__ start, const int* __restrict__ pos,
    int2* __restrict__ pk, int E, int gF,
    const float* __restrict__ x, const unsigned short* __restrict__ WF,
    const float* __restrict__ bias, unsigned short* __restrict__ C, int N) {
  __shared__ alignas(16) unsigned short sA[128 * 40];
  const int bid = blockIdx.x;
  if (bid < gF) {
    int e = bid * 256 + threadIdx.x;
    if (e < E) {
      int r = row[e];
      int p = start[col[e]] + pos[e];
      pk[p] = make_int2(r, __float_as_int(w[e] * dinv[r]));
    }
    return;
  }
  // ---- gemm1 body (K=64, A fp32, bias, C bf16) ----
  const int t = threadIdx.x;
  const int lane = t & 63, wave = t >> 6;
  const int quad = lane >> 4, n0 = lane & 15;
  const int r0 = (bid - gF) * 128;
  f32x4 acc[8][2] = {};
  for (int kc = 0; kc < 64; kc += 32) {
    __syncthreads();
#pragma unroll
    for (int i = 0; i < 4; i++) {
      int idx = (t + i * 256) * 4;
      int r = idx >> 5, k = idx & 31;
      int gr = r0 + r;
      float4 v = make_float4(0.f, 0.f, 0.f, 0.f);
      if (gr < N) v = *(const float4*)&x[(size_t)gr * 64 + kc + k];
      uint2 pv;
      pv.x = packbf2(v.x, v.y);
      pv.y = packbf2(v.z, v.w);
      *(uint2*)&sA[r * 40 + k] = pv;
    }
    __syncthreads();
    const int kci = kc >> 5;
    const bf16x8* wf = (const bf16x8*)WF;
    bf16x8 b0 = wf[(kci * 8 + wave * 2 + 0) * 64 + lane];
    bf16x8 b1 = wf[(kci * 8 + wave * 2 + 1) * 64 + lane];
#pragma unroll
    for (int rt = 0; rt < 8; rt++) {
      bf16x8 af = *(const bf16x8*)&sA[(rt * 16 + n0) * 40 + quad * 8];
      acc[rt][0] = __builtin_amdgcn_mfma_f32_16x16x32_bf16(af, b0, acc[rt][0], 0, 0, 0);
      acc[rt][1] = __builtin_amdgcn_mfma_f32_16x16x32_bf16(af, b1, acc[rt][1], 0, 0, 0);
    }
  }
  const int colbase = wave * 32;
  const float bc0 = bias[colbase + n0];
  const float bc1 = bias[colbase + 16 + n0];
#pragma unroll
  for (int rt = 0; rt < 8; rt++) {
#pragma unroll
    for (int reg = 0; reg < 4; reg++) {
      int r = r0 + rt * 16 + quad * 4 + reg;
      if (r < N) {
        unsigned short* cp = C + (size_t)r * 128 + colbase;
        cp[n0] = packbf1(acc[rt][0][reg] + bc0);
        cp[n0 + 16] = packbf1(acc[rt][1][reg] + bc1);
      }
    }
  }
}

// ---------- MFMA bf16 GEMM (gemm2): C[N,128] = A[N,128] @ W (A bf16, no bias) ----
template<int K, bool ABF, bool BIAS>
__global__ __launch_bounds__(256) void k_gemm_mfma(const void* __restrict__ Av,
    const unsigned short* __restrict__ WF, const float* __restrict__ bias,
    unsigned short* __restrict__ C, int N) {
  __shared__ alignas(16) unsigned short sA[128 * 40];
  const int t = threadIdx.x;
  const int lane = t & 63, wave = t >> 6;
  const int quad = lane >> 4, n0 = lane & 15;
  const int r0 = blockIdx.x * 128;
  f32x4 acc[8][2] = {};
  for (int kc = 0; kc < K; kc += 32) {
    __syncthreads();
    if (ABF) {
      const unsigned short* Ab = (const unsigned short*)Av;
#pragma unroll
      for (int i = 0; i < 2; i++) {
        int idx = (t + i * 256) * 8;
        int r = idx >> 5, k = idx & 31;
        int gr = r0 + r;
        uint4 v = make_uint4(0u, 0u, 0u, 0u);
        if (gr < N) v = *(const uint4*)&Ab[(size_t)gr * K + kc + k];
        *(uint4*)&sA[r * 40 + k] = v;
      }
    } else {
      const float* Af = (const float*)Av;
#pragma unroll
      for (int i = 0; i < 4; i++) {
        int idx = (t + i * 256) * 4;
        int r = idx >> 5, k = idx & 31;
        int gr = r0 + r;
        float4 v = make_float4(0.f, 0.f, 0.f, 0.f);
        if (gr < N) v = *(const float4*)&Af[(size_t)gr * K + kc + k];
        uint2 pv;
        pv.x = packbf2(v.x, v.y);
        pv.y = packbf2(v.z, v.w);
        *(uint2*)&sA[r * 40 + k] = pv;
      }
    }
    __syncthreads();
    const int kci = kc >> 5;
    const bf16x8* wf = (const bf16x8*)WF;
    bf16x8 b0 = wf[(kci * 8 + wave * 2 + 0) * 64 + lane];
    bf16x8 b1 = wf[(kci * 8 + wave * 2 + 1) * 64 + lane];
#pragma unroll
    for (int rt = 0; rt < 8; rt++) {
      bf16x8 af = *(const bf16x8*)&sA[(rt * 16 + n0) * 40 + quad * 8];
      acc[rt][0] = __builtin_amdgcn_mfma_f32_16x16x32_bf16(af, b0, acc[rt][0], 0, 0, 0);
      acc[rt][1] = __builtin_amdgcn_mfma_f32_16x16x32_bf16(af, b1, acc[rt][1], 0, 0, 0);
    }
  }
  const int colbase = wave * 32;
  const float bc0 = BIAS ? bias[colbase + n0] : 0.f;
  const float bc1 = BIAS ? bias[colbase + 16 + n0] : 0.f;
#pragma unroll
  for (int rt = 0; rt < 8; rt++) {
#pragma unroll
    for (int reg = 0; reg < 4; reg++) {
      int r = r0 + rt * 16 + quad * 4 + reg;
      if (r < N) {
        unsigned short* cp = C + (size_t)r * 128 + colbase;
        cp[n0] = packbf1(acc[rt][0][reg] + bc0);
        cp[n0 + 16] = packbf1(acc[rt][1][reg] + bc1);
      }
    }
  }
}

// ---------- CSR gather (bf16 table): h[v] = act(dinv*sum + dinv^2*hw[v] + bias) ----
template<bool RELU, bool OUTBF>
__global__ void k_gather(const int* __restrict__ start, const int2* __restrict__ pk,
                         const unsigned short* __restrict__ hw, const float* __restrict__ dinv,
                         const float* __restrict__ bias, void* __restrict__ hout, int N) {
  const int t = threadIdx.x;
  const int v = blockIdx.x * 16 + (t >> 4);
  if (v >= N) return;
  const int j8 = (t & 15) * 8;
  const int b = start[v];
  const int en = start[v + 1];
  float accA[8] = {}, accB[8] = {};
  int i = b;
  for (; i + 1 < en; i += 2) {
    int2 q0 = pk[i], q1 = pk[i + 1];
    float n0 = __int_as_float(q0.y), n1 = __int_as_float(q1.y);
    uint4 w0 = *(const uint4*)&hw[(size_t)q0.x * 128 + j8];
    uint4 w1 = *(const uint4*)&hw[(size_t)q1.x * 128 + j8];
    accA[0] = fmaf(n0, bflo(w0.x), accA[0]); accA[1] = fmaf(n0, bfhi(w0.x), accA[1]);
    accA[2] = fmaf(n0, bflo(w0.y), accA[2]); accA[3] = fmaf(n0, bfhi(w0.y), accA[3]);
    accA[4] = fmaf(n0, bflo(w0.z), accA[4]); accA[5] = fmaf(n0, bfhi(w0.z), accA[5]);
    accA[6] = fmaf(n0, bflo(w0.w), accA[6]); accA[7] = fmaf(n0, bfhi(w0.w), accA[7]);
    accB[0] = fmaf(n1, bflo(w1.x), accB[0]); accB[1] = fmaf(n1, bfhi(w1.x), accB[1]);
    accB[2] = fmaf(n1, bflo(w1.y), accB[2]); accB[3] = fmaf(n1, bfhi(w1.y), accB[3]);
    accB[4] = fmaf(n1, bflo(w1.z), accB[4]); accB[5] = fmaf(n1, bfhi(w1.z), accB[5]);
    accB[6] = fmaf(n1, bflo(w1.w), accB[6]); accB[7] = fmaf(n1, bfhi(w1.w), accB[7]);
  }
  if (i < en) {
    int2 q = pk[i];
    float n = __int_as_float(q.y);
    uint4 w0 = *(const uint4*)&hw[(size_t)q.x * 128 + j8];
    accA[0] = fmaf(n, bflo(w0.x), accA[0]); accA[1] = fmaf(n, bfhi(w0.x), accA[1]);
    accA[2] = fmaf(n, bflo(w0.y), accA[2]); accA[3] = fmaf(n, bfhi(w0.y), accA[3]);
    accA[4] = fmaf(n, bflo(w0.z), accA[4]); accA[5] = fmaf(n, bfhi(w0.z), accA[5]);
    accA[6] = fmaf(n, bflo(w0.w), accA[6]); accA[7] = fmaf(n, bfhi(w0.w), accA[7]);
  }
  const float d = dinv[v];
  const float s = d * d;
  uint4 wv = *(const uint4*)&hw[(size_t)v * 128 + j8];
  float hv[8] = { bflo(wv.x), bfhi(wv.x), bflo(wv.y), bfhi(wv.y),
                  bflo(wv.z), bfhi(wv.z), bflo(wv.w), bfhi(wv.w) };
  float4 bv0 = *(const float4*)&bias[j8];
  float4 bv1 = *(const float4*)&bias[j8 + 4];
  float bvv[8] = { bv0.x, bv0.y, bv0.z, bv0.w, bv1.x, bv1.y, bv1.z, bv1.w };
  float o[8];
#pragma unroll
  for (int k = 0; k < 8; k++) {
    float a = accA[k] + accB[k];
    o[k] = fmaf(d, a, fmaf(s, hv[k], bvv[k]));
    if (RELU) o[k] = fmaxf(o[k], 0.f);
  }
  if (OUTBF) {
    uint4 pv;
    pv.x = packbf2(o[0], o[1]); pv.y = packbf2(o[2], o[3]);
    pv.z = packbf2(o[4], o[5]); pv.w = packbf2(o[6], o[7]);
    *(uint4*)&((unsigned short*)hout)[(size_t)v * 128 + j8] = pv;
  } else {
    float* hf = (float*)hout;
    *(float4*)&hf[(size_t)v * 128 + j8]     = make_float4(o[0], o[1], o[2], o[3]);
    *(float4*)&hf[(size_t)v * 128 + j8 + 4] = make_float4(o[4], o[5], o[6], o[7]);
  }
}

// ---------- per-edge kernel (MFMA layer b) ----------
__global__ __launch_bounds__(256) void k_edge(const unsigned short* __restrict__ U,
    const int* __restrict__ p0, const int* __restrict__ p1,
    const unsigned short* __restrict__ WbF, const float* __restrict__ bb,
    const float* __restrict__ Wc, const float* __restrict__ bc,
    float* __restrict__ logits, int ES) {
  __shared__ alignas(16) unsigned short sS1[64 * 72];   // bf16 [edge][k], stride 72
  const int t = threadIdx.x;
  const int base = blockIdx.x << 6;
  {  // gather + add + relu + bf16-pack -> sS1
    int p = t >> 2, q = t & 3;
    int e = base + p; if (e >= ES) e = ES - 1;
    const unsigned short* r0 = U + (size_t)p0[e] * 128;        // U0: cols 0..63
    const unsigned short* r1 = U + (size_t)p1[e] * 128 + 64;   // U1: cols 64..127
#pragma unroll
    for (int i = 0; i < 4; i++) {
      int c = i * 16 + q * 4;
      uint2 av = *(const uint2*)&r0[c];
      uint2 bv = *(const uint2*)&r1[c];
      float ox = fmaxf(bflo(av.x) + bflo(bv.x), 0.f);
      float oy = fmaxf(bfhi(av.x) + bfhi(bv.x), 0.f);
      float oz = fmaxf(bflo(av.y) + bflo(bv.y), 0.f);
      float ow = fmaxf(bfhi(av.y) + bfhi(bv.y), 0.f);
      uint2 pv;
      pv.x = packbf2(ox, oy);
      pv.y = packbf2(oz, ow);
      *(uint2*)&sS1[p * 72 + c] = pv;
    }
  }
  __syncthreads();
  const int lane = t & 63;
  const int wave = t >> 6;
  const int quad = lane >> 4, n0 = lane & 15;
  const int edge0 = wave * 16;
  bf16x8 a0 = *(const bf16x8*)&sS1[(edge0 + n0) * 72 + quad * 8];
  bf16x8 a1 = *(const bf16x8*)&sS1[(edge0 + n0) * 72 + 32 + quad * 8];
  const bf16x8* wf = (const bf16x8*)WbF;
  bf16x8 b00 = wf[lane * 4 + 0];
  bf16x8 b01 = wf[lane * 4 + 1];
  bf16x8 b10 = wf[lane * 4 + 2];
  bf16x8 b11 = wf[lane * 4 + 3];
  f32x4 acc0 = {0.f, 0.f, 0.f, 0.f};
  f32x4 acc1 = {0.f, 0.f, 0.f, 0.f};
  acc0 = __builtin_amdgcn_mfma_f32_16x16x32_bf16(a0, b00, acc0, 0, 0, 0);
  acc0 = __builtin_amdgcn_mfma_f32_16x16x32_bf16(a1, b10, acc0, 0, 0, 0);
  acc1 = __builtin_amdgcn_mfma_f32_16x16x32_bf16(a0, b01, acc1, 0, 0, 0);
  acc1 = __builtin_amdgcn_mfma_f32_16x16x32_bf16(a1, b11, acc1, 0, 0, 0);
  const float bb0 = bb[n0], bb1 = bb[n0 + 16];
  const float wc0 = Wc[n0], wc1 = Wc[n0 + 16];
  const float bcv = bc[0];
#pragma unroll
  for (int reg = 0; reg < 4; reg++) {
    float s = fmaf(fmaxf(acc0[reg] + bb0, 0.f), wc0,
                   fmaxf(acc1[reg] + bb1, 0.f) * wc1);
    s += __shfl_xor(s, 1);
    s += __shfl_xor(s, 2);
    s += __shfl_xor(s, 4);
    s += __shfl_xor(s, 8);
    if (n0 == 0) {
      int e = base + edge0 + quad * 4 + reg;
      if (e < ES) logits[e] = s + bcv;
    }
  }
}

// ---------- fused per-graph softmax: one block per graph (eg sorted) ----------
DEVINL int lbound(const int* __restrict__ a, int n, int key) {
  int lo = 0, hi = n;
  while (lo < hi) { int mid = (lo + hi) >> 1; if (a[mid] < key) lo = mid + 1; else hi = mid; }
  return lo;
}
__global__ __launch_bounds__(512) void k_softmax(const float* __restrict__ logits,
                          const int* __restrict__ eg,
                          float* __restrict__ out, int ES) {
  const int g = blockIdx.x;
  const int t = threadIdx.x;
  const int lo = lbound(eg, ES, g);
  const int hi = lbound(eg, ES, g + 1);
  if (lo >= hi) return;
  __shared__ float red[512];
  __shared__ float s_m, s_z;
  float m = -3.4e38f;
  for (int i = lo + t; i < hi; i += 512) m = fmaxf(m, logits[i]);
  red[t] = m; __syncthreads();
#pragma unroll
  for (int off = 256; off >= 1; off >>= 1) {
    if (t < off) red[t] = fmaxf(red[t], red[t + off]);
    __syncthreads();
  }
  if (t == 0) s_m = red[0];
  __syncthreads();
  const float gm = s_m;
  float z = 0.f;
  for (int i = lo + t; i < hi; i += 512) {
    float e = expf(logits[i] - gm);
    out[i] = e;
    z += e;
  }
  red[t] = z; __syncthreads();
#pragma unroll
  for (int off = 256; off >= 1; off >>= 1) {
    if (t < off) red[t] += red[t + off];
    __syncthreads();
  }
  if (t == 0) s_z = red[0];
  __syncthreads();
  const float inv = 1.0f / s_z;
  for (int i = lo + t; i < hi; i += 512) out[i] *= inv;
}

// ---------------------------------------------------------------------------
extern "C" void kernel_launch(void* const* d_in, const int* in_sizes, int n_in,
                              void* d_out, int out_size, void* d_ws, size_t ws_size,
                              hipStream_t stream) {
  const float* x  = (const float*)d_in[0];
  const int* ei   = (const int*)d_in[1];
  const float* ew = (const float*)d_in[2];
  const int* pi   = (const int*)d_in[3];
  const int* eg   = (const int*)d_in[4];
  const float* Wp = (const float*)d_in[6];
  const float* bp = (const float*)d_in[7];
  const float* W1 = (const float*)d_in[8];
  const float* b1 = (const float*)d_in[9];
  const float* W2 = (const float*)d_in[10];
  const float* b2 = (const float*)d_in[11];
  const float* Wa = (const float*)d_in[12];
  const float* ba = (const float*)d_in[13];
  const float* Wb = (const float*)d_in[14];
  const float* bb = (const float*)d_in[15];
  const float* Wc = (const float*)d_in[16];
  const float* bc = (const float*)d_in[17];

  const int N  = in_sizes[0] / 64;
  const int E  = in_sizes[2];
  const int ES = in_sizes[4];
  const int G  = 128;

  float* ws = (float*)d_ws;
  size_t o = 0;
  const size_t Npad = ((size_t)N + 31) & ~(size_t)31;
  ull* cnt64 = (ull*)(ws + o);  o += 2 * Npad;          // packed count|weightsum
  float* dinv = (float*)(ws + o); o += Npad;
  int* start = (int*)(ws + o);  o += Npad + 32;         // exclusive prefix, N+1 entries
  int* bsum = (int*)(ws + o);   o += 512;
  int* boff = (int*)(ws + o);   o += 512;
  int* pos = (int*)(ws + o);    o += ((size_t)E + 31) & ~(size_t)31;  // own buffer (R11)
  int2* pk = (int2*)(ws + o);   o += (size_t)E * 2;
  float* A = ws + o;            o += (size_t)N * 128;   // h1 bf16 -> U bf16
  float* B = ws + o;            o += (size_t)N * 128;   // hw1 bf16 -> V bf16 -> logits
  unsigned short* WfuseF = (unsigned short*)(ws + o); o += 4096;   // 8192 bf16
  float* bfuse = ws + o;        o += 128;
  unsigned short* McatF = (unsigned short*)(ws + o); o += 8192;    // 16384 bf16
  float* bU = ws + o;           o += 128;
  unsigned short* WbF = (unsigned short*)(ws + o); o += 1024;      // 2048 bf16

  unsigned short* hw1 = (unsigned short*)B;
  unsigned short* h1 = (unsigned short*)A;  // bf16 (MFMA A-operand)
  unsigned short* V = (unsigned short*)B;   // overwrites hw1 (dead after gather1)
  unsigned short* U = (unsigned short*)A;   // overwrites h1 (dead after gemm2)
  float* logits = B;                        // overwrites V (dead after gather2)

  const int* row = ei;
  const int* col = ei + E;
  const int* p0 = pi;
  const int* p1 = pi + ES;
  float* out = (float*)d_out;

  const int gE = (E + 255) / 256;     // 3907
  const int nb = (N + 255) / 256;
  const int gRows = (N + 127) / 128;  // 782
  const int gGat = (N + 15) / 16;

  // ---- fused [CSR histogram + weight folding] ----
  hipMemsetAsync(cnt64, 0, Npad * sizeof(ull), stream);
  k_histprep<<<gE + 105, 256, 0, stream>>>(col, ew, cnt64, pos, E, gE,
                                           Wp, bp, W1, W2, Wa, ba, b2, Wb,
                                           WfuseF, bfuse, McatF, bU, WbF);
  k_scan1<<<nb, 256, 0, stream>>>(cnt64, start, bsum, N);
  k_scan2<<<1, 512, 0, stream>>>(bsum, boff, nb, &start[N]);
  k_scan3dinv<<<nb, 256, 0, stream>>>(start, boff, cnt64, dinv, N);

  // ---- fused [CSR fill + gemm1] ----
  k_fillgemm<<<gE + gRows, 256, 0, stream>>>(row, col, ew, dinv, start, pos, pk, E, gE,
                                             x, WfuseF, bfuse, hw1, N);

  // ---- rest of node pipeline ----
  k_gather<true, true><<<gGat, 256, 0, stream>>>(start, pk, hw1, dinv, b1, (void*)h1, N);
  k_gemm_mfma<128, true, false><<<gRows, 256, 0, stream>>>(h1, McatF, nullptr, V, N);
  k_gather<false, true><<<gGat, 256, 0, stream>>>(start, pk, V, dinv, bU, (void*)U, N);

  // ---- per-edge MLP (MFMA) ----
  k_edge<<<(ES + 63) / 64, 256, 0, stream>>>(U, p0, p1, WbF, bb, Wc, bc, logits, ES);

  // ---- per-graph softmax ----
  k_softmax<<<G, 512, 0, stream>>>(logits, eg, out, ES);
}

// Round 12
// 352.836 us; speedup vs baseline: 8.4977x; 1.0271x over previous
//
#include <hip/hip_runtime.h>
#include <hip/hip_bf16.h>
#include <cstdint>

#define DEVINL __device__ __forceinline__
typedef unsigned long long ull;

// ---------------------------------------------------------------------------
// 2-layer GCN (gcn_norm w/ self-loops) -> per-pair MLP -> per-graph softmax.
// R12: interleaved block fusion. R11 evidence: appended-block fusion gave
// ZERO overlap (53.4 = 48+5 exactly) because appended blocks dispatch last.
// Fix: k_histgemm interleaves gemm1's 782 MFMA blocks every 5th block among
// hist's 3907 atomic blocks — both resident from t=0, atomic drain hides the
// MFMA work (m114 co-schedule). k_prep moves to its own prior launch (WfuseF
// dependency); k_fill back to standalone. All compute bodies bit-identical.
// ---------------------------------------------------------------------------

typedef __attribute__((ext_vector_type(8))) short bf16x8;
typedef __attribute__((ext_vector_type(4))) float f32x4;

DEVINL float bflo(unsigned u) { return __uint_as_float(u << 16); }
DEVINL float bfhi(unsigned u) { return __uint_as_float(u & 0xffff0000u); }
DEVINL unsigned packbf2(float a, float b) {   // RNE pack of 2 fp32 -> 2 bf16
  unsigned ua = __float_as_uint(a); ua = (ua + 0x7fff + ((ua >> 16) & 1)) >> 16;
  unsigned ub = __float_as_uint(b); ub = (ub + 0x7fff + ((ub >> 16) & 1)) >> 16;
  return ua | (ub << 16);
}
DEVINL unsigned short packbf1(float a) {
  unsigned ua = __float_as_uint(a);
  return (unsigned short)((ua + 0x7fff + ((ua >> 16) & 1)) >> 16);
}

// ---------- weight folding (tiny, separate launch: feeds gemm blocks of
// k_histgemm, so it must complete first) ----------
__global__ void k_prep(const float* __restrict__ Wp, const float* __restrict__ bp,
                       const float* __restrict__ W1,
                       const float* __restrict__ W2, const float* __restrict__ Wa,
                       const float* __restrict__ ba, const float* __restrict__ b2,
                       const float* __restrict__ Wb,
                       unsigned short* __restrict__ WfuseF, float* __restrict__ bfuse,
                       unsigned short* __restrict__ McatF, float* __restrict__ bU,
                       unsigned short* __restrict__ WbF) {
  int id = blockIdx.x * 256 + threadIdx.x;
  if (id < 8192) {                      // WfuseF = pack(Wp@W1), B-frag layout
    int j = id & 7, q = id >> 3;
    int l = q & 63, p = q >> 6;
    int nt = p & 7, kci = p >> 3;
    int kr = kci * 32 + ((l >> 4) << 3) + j;
    int nc = nt * 16 + (l & 15);
    float s = 0.f;
    for (int c = 0; c < 128; c++) s = fmaf(Wp[kr * 128 + c], W1[c * 128 + nc], s);
    WfuseF[id] = packbf1(s);
  } else if (id < 8320) {               // bfuse = bp@W1
    int j = id - 8192;
    float s = 0.f;
    for (int c = 0; c < 128; c++) s = fmaf(bp[c], W1[c * 128 + j], s);
    bfuse[j] = s;
  } else if (id < 24704) {              // McatF = pack([W2@Wa0 | W2@Wa1])
    int m = id - 8320;
    int j8 = m & 7, q = m >> 3;
    int l = q & 63, p = q >> 6;
    int nt = p & 7, kci = p >> 3;
    int kr = kci * 32 + ((l >> 4) << 3) + j8;
    int nc = nt * 16 + (l & 15);
    int jj = nc & 63, koff = (nc < 64) ? 0 : 64;
    float s = 0.f;
    for (int k = 0; k < 64; k++) s = fmaf(W2[kr * 64 + k], Wa[(koff + k) * 64 + jj], s);
    McatF[m] = packbf1(s);
  } else if (id < 24832) {              // bU = [b2@Wa0+ba | b2@Wa1]
    int j = id - 24704;
    int jj = j & 63, koff = (j < 64) ? 0 : 64;
    float s = (j < 64) ? ba[j] : 0.f;
    for (int k = 0; k < 64; k++) s = fmaf(b2[k], Wa[(koff + k) * 64 + jj], s);
    bU[j] = s;
  } else if (id < 24832 + 2048) {       // WbF bf16 B-fragment pack (k_edge)
    int m = id - 24832;
    int j = m & 7;
    int idx = m >> 3;
    int nt = idx & 1, kt = (idx >> 1) & 1, l = idx >> 2;
    int kr = kt * 32 + ((l >> 4) << 3) + j;
    int nc = nt * 16 + (l & 15);
    WbF[m] = packbf1(Wb[kr * 32 + nc]);
  }
}

// ---------- fused: CSR histogram (atomic-bound) ⊕ gemm1 (MFMA), INTERLEAVED ----
// gemm blocks at bid%5==4 within the first 5*gG bids; hist blocks elsewhere.
// hist: one 64-bit atomic per edge (count<<36 | 8.28-fixed w); old>>36 = pos.
// gemm: hw1 = bf16(x @ WfuseF + bfuse), 128x128 MFMA tile (needs prior k_prep).
__global__ __launch_bounds__(256) void k_histgemm(
    const int* __restrict__ col, const float* __restrict__ w,
    ull* __restrict__ cnt64, int* __restrict__ pos, int E, int gG,
    const float* __restrict__ x, const unsigned short* __restrict__ WF,
    const float* __restrict__ bias, unsigned short* __restrict__ C, int N) {
  __shared__ alignas(16) unsigned short sA[128 * 40];
  const int bid = blockIdx.x;
  const int ilv = gG * 5;
  int hb = -1, gb = -1;
  if (bid < ilv) {
    if ((bid % 5) == 4) gb = bid / 5;
    else hb = bid - bid / 5;
  } else {
    hb = bid - gG;
  }
  if (hb >= 0) {   // ---- hist body ----
    int e = hb * 256 + threadIdx.x;
    if (e < E) {
      ull inc = (1ULL << 36) | (ull)(unsigned)(w[e] * 268435456.0f + 0.5f);
      ull old = atomicAdd(&cnt64[col[e]], inc);
      pos[e] = (int)(old >> 36);
    }
    return;
  }
  // ---- gemm1 body (K=64, A fp32, bias, C bf16) ----
  const int t = threadIdx.x;
  const int lane = t & 63, wave = t >> 6;
  const int quad = lane >> 4, n0 = lane & 15;
  const int r0 = gb * 128;
  f32x4 acc[8][2] = {};
  for (int kc = 0; kc < 64; kc += 32) {
    __syncthreads();
#pragma unroll
    for (int i = 0; i < 4; i++) {
      int idx = (t + i * 256) * 4;
      int r = idx >> 5, k = idx & 31;
      int gr = r0 + r;
      float4 v = make_float4(0.f, 0.f, 0.f, 0.f);
      if (gr < N) v = *(const float4*)&x[(size_t)gr * 64 + kc + k];
      uint2 pv;
      pv.x = packbf2(v.x, v.y);
      pv.y = packbf2(v.z, v.w);
      *(uint2*)&sA[r * 40 + k] = pv;
    }
    __syncthreads();
    const int kci = kc >> 5;
    const bf16x8* wf = (const bf16x8*)WF;
    bf16x8 b0 = wf[(kci * 8 + wave * 2 + 0) * 64 + lane];
    bf16x8 b1 = wf[(kci * 8 + wave * 2 + 1) * 64 + lane];
#pragma unroll
    for (int rt = 0; rt < 8; rt++) {
      bf16x8 af = *(const bf16x8*)&sA[(rt * 16 + n0) * 40 + quad * 8];
      acc[rt][0] = __builtin_amdgcn_mfma_f32_16x16x32_bf16(af, b0, acc[rt][0], 0, 0, 0);
      acc[rt][1] = __builtin_amdgcn_mfma_f32_16x16x32_bf16(af, b1, acc[rt][1], 0, 0, 0);
    }
  }
  const int colbase = wave * 32;
  const float bc0 = bias[colbase + n0];
  const float bc1 = bias[colbase + 16 + n0];
#pragma unroll
  for (int rt = 0; rt < 8; rt++) {
#pragma unroll
    for (int reg = 0; reg < 4; reg++) {
      int r = r0 + rt * 16 + quad * 4 + reg;
      if (r < N) {
        unsigned short* cp = C + (size_t)r * 128 + colbase;
        cp[n0] = packbf1(acc[rt][0][reg] + bc0);
        cp[n0 + 16] = packbf1(acc[rt][1][reg] + bc1);
      }
    }
  }
}

__global__ void k_scan1(const ull* __restrict__ cnt64, int* __restrict__ start,
                        int* __restrict__ bsum, int N) {
  __shared__ int s[256];
  int t = threadIdx.x;
  int i = blockIdx.x * 256 + t;
  int v = (i < N) ? (int)(cnt64[i] >> 36) : 0;
  s[t] = v; __syncthreads();
  int x = v;
#pragma unroll
  for (int off = 1; off < 256; off <<= 1) {
    int y = (t >= off) ? s[t - off] : 0;
    __syncthreads();
    x += y; s[t] = x;
    __syncthreads();
  }
  if (i < N) start[i] = x - v;   // block-local exclusive
  if (t == 255) bsum[blockIdx.x] = x;
}
__global__ void k_scan2(const int* __restrict__ bsum, int* __restrict__ boff,
                        int nb, int* __restrict__ startN) {
  __shared__ int s[512];
  int t = threadIdx.x;
  int v = (t < nb) ? bsum[t] : 0;
  s[t] = v; __syncthreads();
  int x = v;
#pragma unroll
  for (int off = 1; off < 512; off <<= 1) {
    int y = (t >= off) ? s[t - off] : 0;
    __syncthreads();
    x += y; s[t] = x;
    __syncthreads();
  }
  if (t < nb) boff[t] = x - v;
  if (t == nb - 1) *startN = x;  // = E
}
__global__ void k_scan3dinv(int* __restrict__ start, const int* __restrict__ boff,
                            const ull* __restrict__ cnt64, float* __restrict__ dinv, int N) {
  int i = blockIdx.x * 256 + threadIdx.x;
  if (i < N) {
    start[i] += boff[blockIdx.x];
    float sw = (float)(cnt64[i] & 0xFFFFFFFFFULL) * 3.7252903e-09f;  // *2^-28
    dinv[i] = rsqrtf(1.0f + sw);
  }
}

// ---------- atomic-free CSR fill ----------
__global__ void k_fill(const int* __restrict__ row, const int* __restrict__ col,
                       const float* __restrict__ w, const float* __restrict__ dinv,
                       const int* __restrict__ start, const int* __restrict__ pos,
                       int2* __restrict__ pk, int E) {
  int e = blockIdx.x * 256 + threadIdx.x;
  if (e >= E) return;
  int r = row[e];
  int p = start[col[e]] + pos[e];
  pk[p] = make_int2(r, __float_as_int(w[e] * dinv[r]));
}

// ---------- MFMA bf16 GEMM (gemm2): C[N,128] = A[N,128] @ W (A bf16) ----------
template<int K, bool ABF, bool BIAS>
__global__ __launch_bounds__(256) void k_gemm_mfma(const void* __restrict__ Av,
    const unsigned short* __restrict__ WF, const float* __restrict__ bias,
    unsigned short* __restrict__ C, int N) {
  __shared__ alignas(16) unsigned short sA[128 * 40];
  const int t = threadIdx.x;
  const int lane = t & 63, wave = t >> 6;
  const int quad = lane >> 4, n0 = lane & 15;
  const int r0 = blockIdx.x * 128;
  f32x4 acc[8][2] = {};
  for (int kc = 0; kc < K; kc += 32) {
    __syncthreads();
    if (ABF) {
      const unsigned short* Ab = (const unsigned short*)Av;
#pragma unroll
      for (int i = 0; i < 2; i++) {
        int idx = (t + i * 256) * 8;
        int r = idx >> 5, k = idx & 31;
        int gr = r0 + r;
        uint4 v = make_uint4(0u, 0u, 0u, 0u);
        if (gr < N) v = *(const uint4*)&Ab[(size_t)gr * K + kc + k];
        *(uint4*)&sA[r * 40 + k] = v;
      }
    } else {
      const float* Af = (const float*)Av;
#pragma unroll
      for (int i = 0; i < 4; i++) {
        int idx = (t + i * 256) * 4;
        int r = idx >> 5, k = idx & 31;
        int gr = r0 + r;
        float4 v = make_float4(0.f, 0.f, 0.f, 0.f);
        if (gr < N) v = *(const float4*)&Af[(size_t)gr * K + kc + k];
        uint2 pv;
        pv.x = packbf2(v.x, v.y);
        pv.y = packbf2(v.z, v.w);
        *(uint2*)&sA[r * 40 + k] = pv;
      }
    }
    __syncthreads();
    const int kci = kc >> 5;
    const bf16x8* wf = (const bf16x8*)WF;
    bf16x8 b0 = wf[(kci * 8 + wave * 2 + 0) * 64 + lane];
    bf16x8 b1 = wf[(kci * 8 + wave * 2 + 1) * 64 + lane];
#pragma unroll
    for (int rt = 0; rt < 8; rt++) {
      bf16x8 af = *(const bf16x8*)&sA[(rt * 16 + n0) * 40 + quad * 8];
      acc[rt][0] = __builtin_amdgcn_mfma_f32_16x16x32_bf16(af, b0, acc[rt][0], 0, 0, 0);
      acc[rt][1] = __builtin_amdgcn_mfma_f32_16x16x32_bf16(af, b1, acc[rt][1], 0, 0, 0);
    }
  }
  const int colbase = wave * 32;
  const float bc0 = BIAS ? bias[colbase + n0] : 0.f;
  const float bc1 = BIAS ? bias[colbase + 16 + n0] : 0.f;
#pragma unroll
  for (int rt = 0; rt < 8; rt++) {
#pragma unroll
    for (int reg = 0; reg < 4; reg++) {
      int r = r0 + rt * 16 + quad * 4 + reg;
      if (r < N) {
        unsigned short* cp = C + (size_t)r * 128 + colbase;
        cp[n0] = packbf1(acc[rt][0][reg] + bc0);
        cp[n0 + 16] = packbf1(acc[rt][1][reg] + bc1);
      }
    }
  }
}

// ---------- CSR gather (bf16 table): h[v] = act(dinv*sum + dinv^2*hw[v] + bias) ----
template<bool RELU, bool OUTBF>
__global__ void k_gather(const int* __restrict__ start, const int2* __restrict__ pk,
                         const unsigned short* __restrict__ hw, const float* __restrict__ dinv,
                         const float* __restrict__ bias, void* __restrict__ hout, int N) {
  const int t = threadIdx.x;
  const int v = blockIdx.x * 16 + (t >> 4);
  if (v >= N) return;
  const int j8 = (t & 15) * 8;
  const int b = start[v];
  const int en = start[v + 1];
  float accA[8] = {}, accB[8] = {};
  int i = b;
  for (; i + 1 < en; i += 2) {
    int2 q0 = pk[i], q1 = pk[i + 1];
    float n0 = __int_as_float(q0.y), n1 = __int_as_float(q1.y);
    uint4 w0 = *(const uint4*)&hw[(size_t)q0.x * 128 + j8];
    uint4 w1 = *(const uint4*)&hw[(size_t)q1.x * 128 + j8];
    accA[0] = fmaf(n0, bflo(w0.x), accA[0]); accA[1] = fmaf(n0, bfhi(w0.x), accA[1]);
    accA[2] = fmaf(n0, bflo(w0.y), accA[2]); accA[3] = fmaf(n0, bfhi(w0.y), accA[3]);
    accA[4] = fmaf(n0, bflo(w0.z), accA[4]); accA[5] = fmaf(n0, bfhi(w0.z), accA[5]);
    accA[6] = fmaf(n0, bflo(w0.w), accA[6]); accA[7] = fmaf(n0, bfhi(w0.w), accA[7]);
    accB[0] = fmaf(n1, bflo(w1.x), accB[0]); accB[1] = fmaf(n1, bfhi(w1.x), accB[1]);
    accB[2] = fmaf(n1, bflo(w1.y), accB[2]); accB[3] = fmaf(n1, bfhi(w1.y), accB[3]);
    accB[4] = fmaf(n1, bflo(w1.z), accB[4]); accB[5] = fmaf(n1, bfhi(w1.z), accB[5]);
    accB[6] = fmaf(n1, bflo(w1.w), accB[6]); accB[7] = fmaf(n1, bfhi(w1.w), accB[7]);
  }
  if (i < en) {
    int2 q = pk[i];
    float n = __int_as_float(q.y);
    uint4 w0 = *(const uint4*)&hw[(size_t)q.x * 128 + j8];
    accA[0] = fmaf(n, bflo(w0.x), accA[0]); accA[1] = fmaf(n, bfhi(w0.x), accA[1]);
    accA[2] = fmaf(n, bflo(w0.y), accA[2]); accA[3] = fmaf(n, bfhi(w0.y), accA[3]);
    accA[4] = fmaf(n, bflo(w0.z), accA[4]); accA[5] = fmaf(n, bfhi(w0.z), accA[5]);
    accA[6] = fmaf(n, bflo(w0.w), accA[6]); accA[7] = fmaf(n, bfhi(w0.w), accA[7]);
  }
  const float d = dinv[v];
  const float s = d * d;
  uint4 wv = *(const uint4*)&hw[(size_t)v * 128 + j8];
  float hv[8] = { bflo(wv.x), bfhi(wv.x), bflo(wv.y), bfhi(wv.y),
                  bflo(wv.z), bfhi(wv.z), bflo(wv.w), bfhi(wv.w) };
  float4 bv0 = *(const float4*)&bias[j8];
  float4 bv1 = *(const float4*)&bias[j8 + 4];
  float bvv[8] = { bv0.x, bv0.y, bv0.z, bv0.w, bv1.x, bv1.y, bv1.z, bv1.w };
  float o[8];
#pragma unroll
  for (int k = 0; k < 8; k++) {
    float a = accA[k] + accB[k];
    o[k] = fmaf(d, a, fmaf(s, hv[k], bvv[k]));
    if (RELU) o[k] = fmaxf(o[k], 0.f);
  }
  if (OUTBF) {
    uint4 pv;
    pv.x = packbf2(o[0], o[1]); pv.y = packbf2(o[2], o[3]);
    pv.z = packbf2(o[4], o[5]); pv.w = packbf2(o[6], o[7]);
    *(uint4*)&((unsigned short*)hout)[(size_t)v * 128 + j8] = pv;
  } else {
    float* hf = (float*)hout;
    *(float4*)&hf[(size_t)v * 128 + j8]     = make_float4(o[0], o[1], o[2], o[3]);
    *(float4*)&hf[(size_t)v * 128 + j8 + 4] = make_float4(o[4], o[5], o[6], o[7]);
  }
}

// ---------- per-edge kernel (MFMA layer b) ----------
__global__ __launch_bounds__(256) void k_edge(const unsigned short* __restrict__ U,
    const int* __restrict__ p0, const int* __restrict__ p1,
    const unsigned short* __restrict__ WbF, const float* __restrict__ bb,
    const float* __restrict__ Wc, const float* __restrict__ bc,
    float* __restrict__ logits, int ES) {
  __shared__ alignas(16) unsigned short sS1[64 * 72];   // bf16 [edge][k], stride 72
  const int t = threadIdx.x;
  const int base = blockIdx.x << 6;
  {  // gather + add + relu + bf16-pack -> sS1
    int p = t >> 2, q = t & 3;
    int e = base + p; if (e >= ES) e = ES - 1;
    const unsigned short* r0 = U + (size_t)p0[e] * 128;        // U0: cols 0..63
    const unsigned short* r1 = U + (size_t)p1[e] * 128 + 64;   // U1: cols 64..127
#pragma unroll
    for (int i = 0; i < 4; i++) {
      int c = i * 16 + q * 4;
      uint2 av = *(const uint2*)&r0[c];
      uint2 bv = *(const uint2*)&r1[c];
      float ox = fmaxf(bflo(av.x) + bflo(bv.x), 0.f);
      float oy = fmaxf(bfhi(av.x) + bfhi(bv.x), 0.f);
      float oz = fmaxf(bflo(av.y) + bflo(bv.y), 0.f);
      float ow = fmaxf(bfhi(av.y) + bfhi(bv.y), 0.f);
      uint2 pv;
      pv.x = packbf2(ox, oy);
      pv.y = packbf2(oz, ow);
      *(uint2*)&sS1[p * 72 + c] = pv;
    }
  }
  __syncthreads();
  const int lane = t & 63;
  const int wave = t >> 6;
  const int quad = lane >> 4, n0 = lane & 15;
  const int edge0 = wave * 16;
  bf16x8 a0 = *(const bf16x8*)&sS1[(edge0 + n0) * 72 + quad * 8];
  bf16x8 a1 = *(const bf16x8*)&sS1[(edge0 + n0) * 72 + 32 + quad * 8];
  const bf16x8* wf = (const bf16x8*)WbF;
  bf16x8 b00 = wf[lane * 4 + 0];
  bf16x8 b01 = wf[lane * 4 + 1];
  bf16x8 b10 = wf[lane * 4 + 2];
  bf16x8 b11 = wf[lane * 4 + 3];
  f32x4 acc0 = {0.f, 0.f, 0.f, 0.f};
  f32x4 acc1 = {0.f, 0.f, 0.f, 0.f};
  acc0 = __builtin_amdgcn_mfma_f32_16x16x32_bf16(a0, b00, acc0, 0, 0, 0);
  acc0 = __builtin_amdgcn_mfma_f32_16x16x32_bf16(a1, b10, acc0, 0, 0, 0);
  acc1 = __builtin_amdgcn_mfma_f32_16x16x32_bf16(a0, b01, acc1, 0, 0, 0);
  acc1 = __builtin_amdgcn_mfma_f32_16x16x32_bf16(a1, b11, acc1, 0, 0, 0);
  const float bb0 = bb[n0], bb1 = bb[n0 + 16];
  const float wc0 = Wc[n0], wc1 = Wc[n0 + 16];
  const float bcv = bc[0];
#pragma unroll
  for (int reg = 0; reg < 4; reg++) {
    float s = fmaf(fmaxf(acc0[reg] + bb0, 0.f), wc0,
                   fmaxf(acc1[reg] + bb1, 0.f) * wc1);
    s += __shfl_xor(s, 1);
    s += __shfl_xor(s, 2);
    s += __shfl_xor(s, 4);
    s += __shfl_xor(s, 8);
    if (n0 == 0) {
      int e = base + edge0 + quad * 4 + reg;
      if (e < ES) logits[e] = s + bcv;
    }
  }
}

// ---------- fused per-graph softmax: one block per graph (eg sorted) ----------
DEVINL int lbound(const int* __restrict__ a, int n, int key) {
  int lo = 0, hi = n;
  while (lo < hi) { int mid = (lo + hi) >> 1; if (a[mid] < key) lo = mid + 1; else hi = mid; }
  return lo;
}
__global__ __launch_bounds__(512) void k_softmax(const float* __restrict__ logits,
                          const int* __restrict__ eg,
                          float* __restrict__ out, int ES) {
  const int g = blockIdx.x;
  const int t = threadIdx.x;
  const int lo = lbound(eg, ES, g);
  const int hi = lbound(eg, ES, g + 1);
  if (lo >= hi) return;
  __shared__ float red[512];
  __shared__ float s_m, s_z;
  float m = -3.4e38f;
  for (int i = lo + t; i < hi; i += 512) m = fmaxf(m, logits[i]);
  red[t] = m; __syncthreads();
#pragma unroll
  for (int off = 256; off >= 1; off >>= 1) {
    if (t < off) red[t] = fmaxf(red[t], red[t + off]);
    __syncthreads();
  }
  if (t == 0) s_m = red[0];
  __syncthreads();
  const float gm = s_m;
  float z = 0.f;
  for (int i = lo + t; i < hi; i += 512) {
    float e = expf(logits[i] - gm);
    out[i] = e;
    z += e;
  }
  red[t] = z; __syncthreads();
#pragma unroll
  for (int off = 256; off >= 1; off >>= 1) {
    if (t < off) red[t] += red[t + off];
    __syncthreads();
  }
  if (t == 0) s_z = red[0];
  __syncthreads();
  const float inv = 1.0f / s_z;
  for (int i = lo + t; i < hi; i += 512) out[i] *= inv;
}

// ---------------------------------------------------------------------------
extern "C" void kernel_launch(void* const* d_in, const int* in_sizes, int n_in,
                              void* d_out, int out_size, void* d_ws, size_t ws_size,
                              hipStream_t stream) {
  const float* x  = (const float*)d_in[0];
  const int* ei   = (const int*)d_in[1];
  const float* ew = (const float*)d_in[2];
  const int* pi   = (const int*)d_in[3];
  const int* eg   = (const int*)d_in[4];
  const float* Wp = (const float*)d_in[6];
  const float* bp = (const float*)d_in[7];
  const float* W1 = (const float*)d_in[8];
  const float* b1 = (const float*)d_in[9];
  const float* W2 = (const float*)d_in[10];
  const float* b2 = (const float*)d_in[11];
  const float* Wa = (const float*)d_in[12];
  const float* ba = (const float*)d_in[13];
  const float* Wb = (const float*)d_in[14];
  const float* bb = (const float*)d_in[15];
  const float* Wc = (const float*)d_in[16];
  const float* bc = (const float*)d_in[17];

  const int N  = in_sizes[0] / 64;
  const int E  = in_sizes[2];
  const int ES = in_sizes[4];
  const int G  = 128;

  float* ws = (float*)d_ws;
  size_t o = 0;
  const size_t Npad = ((size_t)N + 31) & ~(size_t)31;
  ull* cnt64 = (ull*)(ws + o);  o += 2 * Npad;          // packed count|weightsum
  float* dinv = (float*)(ws + o); o += Npad;
  int* start = (int*)(ws + o);  o += Npad + 32;         // exclusive prefix, N+1 entries
  int* bsum = (int*)(ws + o);   o += 512;
  int* boff = (int*)(ws + o);   o += 512;
  int* pos = (int*)(ws + o);    o += ((size_t)E + 31) & ~(size_t)31;  // own buffer
  int2* pk = (int2*)(ws + o);   o += (size_t)E * 2;
  float* A = ws + o;            o += (size_t)N * 128;   // h1 bf16 -> U bf16
  float* B = ws + o;            o += (size_t)N * 128;   // hw1 bf16 -> V bf16 -> logits
  unsigned short* WfuseF = (unsigned short*)(ws + o); o += 4096;   // 8192 bf16
  float* bfuse = ws + o;        o += 128;
  unsigned short* McatF = (unsigned short*)(ws + o); o += 8192;    // 16384 bf16
  float* bU = ws + o;           o += 128;
  unsigned short* WbF = (unsigned short*)(ws + o); o += 1024;      // 2048 bf16

  unsigned short* hw1 = (unsigned short*)B;
  unsigned short* h1 = (unsigned short*)A;  // bf16 (MFMA A-operand)
  unsigned short* V = (unsigned short*)B;   // overwrites hw1 (dead after gather1)
  unsigned short* U = (unsigned short*)A;   // overwrites h1 (dead after gemm2)
  float* logits = B;                        // overwrites V (dead after gather2)

  const int* row = ei;
  const int* col = ei + E;
  const int* p0 = pi;
  const int* p1 = pi + ES;
  float* out = (float*)d_out;

  const int gE = (E + 255) / 256;     // 3907 hist/fill blocks
  const int nb = (N + 255) / 256;
  const int gRows = (N + 127) / 128;  // 782 gemm blocks
  const int gGat = (N + 15) / 16;

  // ---- weight folding (feeds gemm blocks of k_histgemm) ----
  hipMemsetAsync(cnt64, 0, Npad * sizeof(ull), stream);
  k_prep<<<105, 256, 0, stream>>>(Wp, bp, W1, W2, Wa, ba, b2, Wb,
                                  WfuseF, bfuse, McatF, bU, WbF);

  // ---- interleaved [CSR histogram ⊕ gemm1] ----
  k_histgemm<<<gE + gRows, 256, 0, stream>>>(col, ew, cnt64, pos, E, gRows,
                                             x, WfuseF, bfuse, hw1, N);

  // ---- scans ----
  k_scan1<<<nb, 256, 0, stream>>>(cnt64, start, bsum, N);
  k_scan2<<<1, 512, 0, stream>>>(bsum, boff, nb, &start[N]);
  k_scan3dinv<<<nb, 256, 0, stream>>>(start, boff, cnt64, dinv, N);

  // ---- CSR fill ----
  k_fill<<<gE, 256, 0, stream>>>(row, col, ew, dinv, start, pos, pk, E);

  // ---- rest of node pipeline ----
  k_gather<true, true><<<gGat, 256, 0, stream>>>(start, pk, hw1, dinv, b1, (void*)h1, N);
  k_gemm_mfma<128, true, false><<<gRows, 256, 0, stream>>>(h1, McatF, nullptr, V, N);
  k_gather<false, true><<<gGat, 256, 0, stream>>>(start, pk, V, dinv, bU, (void*)U, N);

  // ---- per-edge MLP (MFMA) ----
  k_edge<<<(ES + 63) / 64, 256, 0, stream>>>(U, p0, p1, WbF, bb, Wc, bc, logits, ES);

  // ---- per-graph softmax ----
  k_softmax<<<G, 512, 0, stream>>>(logits, eg, out, ES);
}